// Round 8
// baseline (788.242 us; speedup 1.0000x reference)
//
#include <hip/hip_runtime.h>
#include <hip/hip_bf16.h>

#define T_SEQ 200
#define HDIM  256
#define EDIM  256
#define G3    768   // 3*H
#define TOUT  199   // T-1

typedef _Float16 h2_t __attribute__((ext_vector_type(2)));
typedef unsigned int u4_t __attribute__((ext_vector_type(4)));
typedef float f4_t __attribute__((ext_vector_type(4)));

static __device__ __forceinline__ float dot2acc(unsigned int w, unsigned int h, float c) {
  return __builtin_amdgcn_fdot2(__builtin_bit_cast(h2_t, w),
                                __builtin_bit_cast(h2_t, h), c, false);
}

static __device__ __forceinline__ unsigned int pk(float x, float y) {
  h2_t p; p[0] = (_Float16)x; p[1] = (_Float16)y;
  return __builtin_bit_cast(unsigned int, p);
}

// async global->LDS, 4 bytes per lane; lds base must be wave-uniform
static __device__ __forceinline__ void gload_lds4(const float* g, float* l) {
  __builtin_amdgcn_global_load_lds(
      (const __attribute__((address_space(1))) void*)g,
      (__attribute__((address_space(3))) void*)l, 4, 0, 0);
}

// ---------------------------------------------------------------------------
// Kernel A: gi[m][n] = sum_e (q_emb[q[m]][e]+a_emb[a[m]][e]) * w_ih[n][e]
//                      + b_ih[n] + (n<512 ? b_hh[n] : 0)
// 4x4 microtile, 64x64 tile, grid (200,12), 256 thr.
// Demand ~66 regs -> fits ANY budget tier (rounds 2-7: big microtiles spill;
// attribute knobs are dead, so fit the granted budget instead).
// ---------------------------------------------------------------------------
__global__ __attribute__((amdgpu_flat_work_group_size(256, 256)))
void gi_gemm_kernel(
    const int* __restrict__ questions,
    const int* __restrict__ answers,
    const float* __restrict__ q_emb,
    const float* __restrict__ a_emb,
    const float* __restrict__ w_ih,
    const float* __restrict__ b_ih,
    const float* __restrict__ b_hh,
    float* __restrict__ gi)
{
  const int tx = threadIdx.x & 15;
  const int ty = threadIdx.x >> 4;
  const int m0 = blockIdx.x * 64 + ty * 4;
  const int n0 = blockIdx.y * 64 + tx * 4;

#define QAOFF(i) \
  int qo##i, ao##i; \
  { int q_ = questions[m0 + i]; q_ = q_ < 0 ? 0 : q_; qo##i = q_ * EDIM; \
    int a_ = answers[m0 + i];   a_ = a_ < 0 ? 0 : a_; ao##i = a_ * EDIM; }
  QAOFF(0) QAOFF(1) QAOFF(2) QAOFF(3)

  const float* wb = w_ih + (size_t)n0 * EDIM;

#define DECL_ACC(i) float c##i##_0=0.f, c##i##_1=0.f, c##i##_2=0.f, c##i##_3=0.f;
  DECL_ACC(0) DECL_ACC(1) DECL_ACC(2) DECL_ACC(3)

  for (int k = 0; k < EDIM; k += 4) {
#define LOADX(i) f4_t x##i; { \
    f4_t q_ = *(const f4_t*)(q_emb + qo##i + k); \
    f4_t e_ = *(const f4_t*)(a_emb + ao##i + k); x##i = q_ + e_; }
    LOADX(0) LOADX(1) LOADX(2) LOADX(3)
#define LOADY(j) f4_t y##j = *(const f4_t*)(wb + (j) * EDIM + k);
    LOADY(0) LOADY(1) LOADY(2) LOADY(3)
#define FMA1(i,j) c##i##_##j = fmaf(x##i[3], y##j[3], fmaf(x##i[2], y##j[2], \
                    fmaf(x##i[1], y##j[1], fmaf(x##i[0], y##j[0], c##i##_##j))));
#define FMAR(i) FMA1(i,0) FMA1(i,1) FMA1(i,2) FMA1(i,3)
    FMAR(0) FMAR(1) FMAR(2) FMAR(3)
  }

#define BB(j) float bb##j; { int n_ = n0 + (j); \
    bb##j = b_ih[n_] + (n_ < 2 * HDIM ? b_hh[n_] : 0.f); }
  BB(0) BB(1) BB(2) BB(3)

#define STORER(i) { float* d_ = gi + (size_t)(m0 + i) * G3 + n0; \
    f4_t o_ = { c##i##_0+bb0, c##i##_1+bb1, c##i##_2+bb2, c##i##_3+bb3 }; \
    *(f4_t*)d_ = o_; }
  STORER(0) STORER(1) STORER(2) STORER(3)
}

// ---------------------------------------------------------------------------
// Kernel B: sequential GRU scan. 64 blocks x 512 thr (8 waves, proven 128-VGPR
// tier). Thread (g=tid>>1, sub=tid&1): unit g, column half [128*sub, +128).
// W_r + W_n: 32 named u4 = 128 VGPRs fp16-packed (fits granted tier).
// W_z: LDS-resident (128 KB), layout [sub][k4][g] -> lane-consecutive 16B
//   ds_read_b128, zero bank conflicts; staged once at prologue.
// h: fp16 in LDS, reads are wave-broadcast (2 addrs); h_prev fp32 in reg.
// gi rows / pred_w rows via global_load_lds (0 VGPR); pb in wave-0 regs.
// ---------------------------------------------------------------------------
__global__ __attribute__((amdgpu_flat_work_group_size(512, 512)))
__attribute__((amdgpu_waves_per_eu(2, 2)))
void gru_scan_kernel(
    const int* __restrict__ questions,
    const float* __restrict__ w_hh,    // [768][256]
    const float* __restrict__ b_hh,    // [768]
    const float* __restrict__ pred_w,  // [Q+1][256]
    const float* __restrict__ pred_b,  // [Q+1]
    const float* __restrict__ gi,      // [B*T][768] (b_ih + b_hh_{r,z} folded)
    float* __restrict__ out)           // [B][199]
{
  const int b    = blockIdx.x;
  const int tid  = threadIdx.x;
  const int lane = tid & 63;
  const int wave = tid >> 6;
  const int g    = tid >> 1;   // hidden unit 0..255
  const int sub  = tid & 1;    // column half
  const bool is_gate = (sub == 0);

  __shared__ __align__(16) u4_t zbuf[2][16][HDIM];  // 128 KB: W_z [sub][k4][g]
  __shared__ __align__(16) _Float16 hh[HDIM];       // fp16 h (512 B, linear)
  __shared__ float gi_buf[2][G3];
  __shared__ float pw_lds[2][HDIM];
  __shared__ float partial_lds[8];

  // ---- W_r, W_n -> 32 NAMED u4 (128 VGPRs, packed fp16) ----
  const float* wr_p = w_hh + (size_t)g * HDIM + 128 * sub;
  const float* wn_p = w_hh + (size_t)(2 * HDIM + g) * HDIM + 128 * sub;

#define WLOAD(name, p_, r_) u4_t name; { \
    f4_t f0_ = *(const f4_t*)((p_) + 8 * (r_)); \
    f4_t f1_ = *(const f4_t*)((p_) + 8 * (r_) + 4); \
    name[0] = pk(f0_[0], f0_[1]); name[1] = pk(f0_[2], f0_[3]); \
    name[2] = pk(f1_[0], f1_[1]); name[3] = pk(f1_[2], f1_[3]); }

  WLOAD(WR0,wr_p,0)  WLOAD(WR1,wr_p,1)  WLOAD(WR2,wr_p,2)  WLOAD(WR3,wr_p,3)
  WLOAD(WR4,wr_p,4)  WLOAD(WR5,wr_p,5)  WLOAD(WR6,wr_p,6)  WLOAD(WR7,wr_p,7)
  WLOAD(WR8,wr_p,8)  WLOAD(WR9,wr_p,9)  WLOAD(WR10,wr_p,10) WLOAD(WR11,wr_p,11)
  WLOAD(WR12,wr_p,12) WLOAD(WR13,wr_p,13) WLOAD(WR14,wr_p,14) WLOAD(WR15,wr_p,15)
  WLOAD(WN0,wn_p,0)  WLOAD(WN1,wn_p,1)  WLOAD(WN2,wn_p,2)  WLOAD(WN3,wn_p,3)
  WLOAD(WN4,wn_p,4)  WLOAD(WN5,wn_p,5)  WLOAD(WN6,wn_p,6)  WLOAD(WN7,wn_p,7)
  WLOAD(WN8,wn_p,8)  WLOAD(WN9,wn_p,9)  WLOAD(WN10,wn_p,10) WLOAD(WN11,wn_p,11)
  WLOAD(WN12,wn_p,12) WLOAD(WN13,wn_p,13) WLOAD(WN14,wn_p,14) WLOAD(WN15,wn_p,15)

  // ---- stage W_z -> LDS, layout [sub][k4][g] (one-time) ----
  {
    const float* wz_p = w_hh + (size_t)(HDIM + g) * HDIM + 128 * sub;
    for (int k4 = 0; k4 < 16; ++k4) {
      f4_t f0 = *(const f4_t*)(wz_p + 8 * k4);
      f4_t f1 = *(const f4_t*)(wz_p + 8 * k4 + 4);
      u4_t z;
      z[0] = pk(f0[0], f0[1]); z[1] = pk(f0[2], f0[3]);
      z[2] = pk(f1[0], f1[1]); z[3] = pk(f1[2], f1[3]);
      zbuf[sub][k4][g] = z;
    }
  }

  float bhn = 0.f, h_prev = 0.f;
  if (is_gate) bhn = b_hh[2 * HDIM + g];

  if (tid < 32) { u4_t z_ = {0u,0u,0u,0u}; *(u4_t*)((char*)hh + tid * 16) = z_; }

  const int*   q_b  = questions + b * T_SEQ;
  const float* gi_b = gi + (size_t)b * T_SEQ * G3;

  // prologue staging for t=0
  if (wave < 6) {
    gload_lds4(gi_b + (2*wave)   * 64 + lane, &gi_buf[0][(2*wave)   * 64]);
    gload_lds4(gi_b + (2*wave+1) * 64 + lane, &gi_buf[0][(2*wave+1) * 64]);
  }
  if (wave == 6) {
    int q0 = q_b[0]; if (q0 < 0) q0 = 0;
    const float* pr = pred_w + (size_t)q0 * HDIM;
#pragma unroll
    for (int kk = 0; kk < 4; ++kk) gload_lds4(pr + 64*kk + lane, &pw_lds[0][64*kk]);
  }
  float pbA = 0.f, pbB = 0.f;
  if (tid == 0) { int q0 = q_b[0]; if (q0 < 0) q0 = 0; pbA = pred_b[q0]; }
  __syncthreads();   // full drain (prologue only)

  const char* hbase = (const char*)hh + 256 * sub;

#define KSTEP(k_) { \
    u4_t hv_ = *(const u4_t*)(hbase + 16 * (k_)); \
    u4_t zv_ = zbuf[sub][k_][g]; \
    sr = dot2acc(WR##k_[0], hv_[0], sr); sr = dot2acc(WR##k_[1], hv_[1], sr); \
    sr = dot2acc(WR##k_[2], hv_[2], sr); sr = dot2acc(WR##k_[3], hv_[3], sr); \
    sz = dot2acc(zv_[0],    hv_[0], sz); sz = dot2acc(zv_[1],    hv_[1], sz); \
    sz = dot2acc(zv_[2],    hv_[2], sz); sz = dot2acc(zv_[3],    hv_[3], sz); \
    sn = dot2acc(WN##k_[0], hv_[0], sn); sn = dot2acc(WN##k_[1], hv_[1], sn); \
    sn = dot2acc(WN##k_[2], hv_[2], sn); sn = dot2acc(WN##k_[3], hv_[3], sn); }

#define STEP(T, C, N) do { \
    const int cur_ = (T) & 1; \
    /* phase 0: async prefetch of step (T)+1 */ \
    if (wave < 6) { \
      gload_lds4(gi_b + (size_t)((T)+1) * G3 + (2*wave)   * 64 + lane, \
                 &gi_buf[cur_ ^ 1][(2*wave)   * 64]); \
      gload_lds4(gi_b + (size_t)((T)+1) * G3 + (2*wave+1) * 64 + lane, \
                 &gi_buf[cur_ ^ 1][(2*wave+1) * 64]); \
    } \
    if (wave == 6) { \
      int tq_ = (T) + 1; tq_ = tq_ > 199 ? 199 : tq_; \
      int qn_ = q_b[tq_]; if (qn_ < 0) qn_ = 0; \
      const float* pr_ = pred_w + (size_t)qn_ * HDIM; \
      gload_lds4(pr_ + lane,       &pw_lds[cur_ ^ 1][0]); \
      gload_lds4(pr_ + 64 + lane,  &pw_lds[cur_ ^ 1][64]); \
      gload_lds4(pr_ + 128 + lane, &pw_lds[cur_ ^ 1][128]); \
      gload_lds4(pr_ + 192 + lane, &pw_lds[cur_ ^ 1][192]); \
    } \
    if (tid == 0) { \
      int tq_ = (T) + 1; tq_ = tq_ > 199 ? 199 : tq_; \
      int qn_ = q_b[tq_]; if (qn_ < 0) qn_ = 0; \
      pb##N = pred_b[qn_]; \
    } \
    /* phase 1: matvec — 192 v_dot2, broadcast h reads, coalesced W_z reads */ \
    float sr = 0.f, sz = 0.f, sn = 0.f; \
    KSTEP(0)  KSTEP(1)  KSTEP(2)  KSTEP(3) \
    KSTEP(4)  KSTEP(5)  KSTEP(6)  KSTEP(7) \
    KSTEP(8)  KSTEP(9)  KSTEP(10) KSTEP(11) \
    KSTEP(12) KSTEP(13) KSTEP(14) KSTEP(15) \
    sr += __shfl_xor(sr, 1); sz += __shfl_xor(sz, 1); sn += __shfl_xor(sn, 1); \
    __builtin_amdgcn_sched_barrier(0); \
    __builtin_amdgcn_s_barrier();   /* B1: all h_t reads done */ \
    __builtin_amdgcn_sched_barrier(0); \
    /* phase 2: gates on sub==0; h update + pred partial */ \
    if (is_gate) { \
      float r_ = __fdividef(1.f, 1.f + __expf(-(gi_buf[cur_][g] + sr))); \
      float z_ = __fdividef(1.f, 1.f + __expf(-(gi_buf[cur_][HDIM + g] + sz))); \
      float e2_ = __expf(2.f * (gi_buf[cur_][2 * HDIM + g] + r_ * (sn + bhn))); \
      float n_ = 1.f - __fdividef(2.f, e2_ + 1.f); \
      h_prev = (1.f - z_) * n_ + z_ * h_prev; \
      hh[g] = (_Float16)h_prev; \
      float pp_ = h_prev * pw_lds[cur_][g]; \
      pp_ += __shfl_xor(pp_, 2);  pp_ += __shfl_xor(pp_, 4); \
      pp_ += __shfl_xor(pp_, 8);  pp_ += __shfl_xor(pp_, 16); \
      pp_ += __shfl_xor(pp_, 32); \
      if (lane == 0) partial_lds[wave] = pp_; \
    } \
    __builtin_amdgcn_sched_barrier(0); \
    asm volatile("s_waitcnt vmcnt(0) lgkmcnt(0)" ::: "memory"); \
    __builtin_amdgcn_s_barrier();   /* B2: h_{t+1}, partials, prefetch visible */ \
    __builtin_amdgcn_sched_barrier(0); \
    /* phase 3: finish prediction for step (T) */ \
    if (tid < 8) { \
      float v_ = partial_lds[tid]; \
      v_ += __shfl_xor(v_, 1); v_ += __shfl_xor(v_, 2); v_ += __shfl_xor(v_, 4); \
      if (tid == 0) \
        out[b * TOUT + (T)] = __fdividef(1.f, 1.f + __expf(-(v_ + pb##C))); \
    } \
  } while (0)

  for (int T = 0; T < 198; T += 2) {
    STEP(T, A, B);
    STEP(T + 1, B, A);
  }
  STEP(198, A, B);
}

// ---------------------------------------------------------------------------
extern "C" void kernel_launch(void* const* d_in, const int* in_sizes, int n_in,
                              void* d_out, int out_size, void* d_ws, size_t ws_size,
                              hipStream_t stream) {
  const int*   questions = (const int*)d_in[1];
  const int*   answers   = (const int*)d_in[2];
  const float* q_emb     = (const float*)d_in[3];
  const float* a_emb     = (const float*)d_in[4];
  const float* w_ih      = (const float*)d_in[5];
  const float* w_hh      = (const float*)d_in[6];
  const float* b_ih      = (const float*)d_in[7];
  const float* b_hh      = (const float*)d_in[8];
  const float* pred_w    = (const float*)d_in[9];
  const float* pred_b    = (const float*)d_in[10];
  float* out = (float*)d_out;

  float* gi = (float*)d_ws;  // [64*200][768] fp32 = 39.3 MB

  gi_gemm_kernel<<<dim3(200, 12), 256, 0, stream>>>(
      questions, answers, q_emb, a_emb, w_ih, b_ih, b_hh, gi);

  gru_scan_kernel<<<64, 512, 0, stream>>>(
      questions, w_hh, b_hh, pred_w, pred_b, gi, out);
}

// Round 9
// 665.765 us; speedup vs baseline: 1.1840x; 1.1840x over previous
//
#include <hip/hip_runtime.h>
#include <hip/hip_bf16.h>

#define T_SEQ 200
#define HDIM  256
#define EDIM  256
#define G3    768   // 3*H
#define TOUT  199   // T-1

typedef _Float16 h2_t __attribute__((ext_vector_type(2)));
typedef _Float16 f16x8_t __attribute__((ext_vector_type(8)));
typedef unsigned int u4_t __attribute__((ext_vector_type(4)));
typedef float f4_t __attribute__((ext_vector_type(4)));

static __device__ __forceinline__ float dot2acc(unsigned int w, unsigned int h, float c) {
  return __builtin_amdgcn_fdot2(__builtin_bit_cast(h2_t, w),
                                __builtin_bit_cast(h2_t, h), c, false);
}

static __device__ __forceinline__ unsigned int pk(float x, float y) {
  h2_t p; p[0] = (_Float16)x; p[1] = (_Float16)y;
  return __builtin_bit_cast(unsigned int, p);
}

// 4 floats -> 4 e5m2 bytes (top byte of f16, round-half-up on bit 7)
static __device__ __forceinline__ unsigned int pk_e5m2x4(const float* p) {
  unsigned int r = 0;
#pragma unroll
  for (int j = 0; j < 4; ++j) {
    unsigned short b = __builtin_bit_cast(unsigned short, (_Float16)p[j]);
    r |= ((unsigned int)((unsigned short)(b + 0x80) >> 8)) << (8 * j);
  }
  return r;
}

// async global->LDS, 4 bytes per lane; lds base must be wave-uniform
static __device__ __forceinline__ void gload_lds4(const float* g, float* l) {
  __builtin_amdgcn_global_load_lds(
      (const __attribute__((address_space(1))) void*)g,
      (__attribute__((address_space(3))) void*)l, 4, 0, 0);
}

// ---------------------------------------------------------------------------
// Kernel A (MFMA f16): gi[m][n] = sum_e x[m][e]*w_ih[n][e] + bias(n),
// x = q_emb[q[m]] + a_emb[a[m]].  M=12800, N=768, K=256.
// Block 512 thr = 8 waves -> tile 64(M)x128(N); wave (wm=w&3, wn=w>>2):
// rows wm*16, col-half wn*64, 4 n-subtiles x 8 K-slices = 32 MFMA/wave.
// A/B frags loaded directly per lane (k = 32i + 8*(lane>>4) + j on BOTH
// operands -> any HW k-permutation cancels); C/D: col=lane&15 (N),
// row=(lane>>4)*4+reg (M)  [m89-verified, dtype-independent].
// ~70 VGPR demand vs 128 budget at 512 thr -> no spill, matrix pipe does K.
// ---------------------------------------------------------------------------
__global__ __attribute__((amdgpu_flat_work_group_size(512, 512)))
__attribute__((amdgpu_waves_per_eu(2, 2)))
void gi_gemm_kernel(
    const int* __restrict__ questions,
    const int* __restrict__ answers,
    const float* __restrict__ q_emb,
    const float* __restrict__ a_emb,
    const float* __restrict__ w_ih,
    const float* __restrict__ b_ih,
    const float* __restrict__ b_hh,
    float* __restrict__ gi)
{
  const int lane = threadIdx.x & 63;
  const int wv   = threadIdx.x >> 6;   // 0..7
  const int lr   = lane & 15;
  const int kg   = lane >> 4;          // 0..3
  const int wm   = wv & 3;
  const int wn   = wv >> 2;

  const int m  = blockIdx.x * 64 + wm * 16 + lr;     // A row this lane loads
  const int nb = blockIdx.y * 128 + wn * 64;         // wave's N base

  int q = questions[m]; q = q < 0 ? 0 : q;
  int a = answers[m];   a = a < 0 ? 0 : a;
  const float* qrow = q_emb + (size_t)q * EDIM + 8 * kg;
  const float* arow = a_emb + (size_t)a * EDIM + 8 * kg;
  const float* wrow = w_ih + (size_t)(nb + lr) * EDIM + 8 * kg;

  f4_t zero4 = {0.f, 0.f, 0.f, 0.f};
  f4_t acc0 = zero4, acc1 = zero4, acc2 = zero4, acc3 = zero4;

#pragma unroll
  for (int i = 0; i < 8; ++i) {        // K slice [32i, 32i+32)
    f4_t q0 = *(const f4_t*)(qrow + 32 * i);
    f4_t q1 = *(const f4_t*)(qrow + 32 * i + 4);
    f4_t a0 = *(const f4_t*)(arow + 32 * i);
    f4_t a1 = *(const f4_t*)(arow + 32 * i + 4);
    f16x8_t af;
    af[0] = (_Float16)(q0[0] + a0[0]); af[1] = (_Float16)(q0[1] + a0[1]);
    af[2] = (_Float16)(q0[2] + a0[2]); af[3] = (_Float16)(q0[3] + a0[3]);
    af[4] = (_Float16)(q1[0] + a1[0]); af[5] = (_Float16)(q1[1] + a1[1]);
    af[6] = (_Float16)(q1[2] + a1[2]); af[7] = (_Float16)(q1[3] + a1[3]);
#define BT(nt) { \
    f4_t b0 = *(const f4_t*)(wrow + (nt) * 16 * EDIM + 32 * i); \
    f4_t b1 = *(const f4_t*)(wrow + (nt) * 16 * EDIM + 32 * i + 4); \
    f16x8_t bf; \
    bf[0] = (_Float16)b0[0]; bf[1] = (_Float16)b0[1]; \
    bf[2] = (_Float16)b0[2]; bf[3] = (_Float16)b0[3]; \
    bf[4] = (_Float16)b1[0]; bf[5] = (_Float16)b1[1]; \
    bf[6] = (_Float16)b1[2]; bf[7] = (_Float16)b1[3]; \
    acc##nt = __builtin_amdgcn_mfma_f32_16x16x32_f16(af, bf, acc##nt, 0, 0, 0); }
    BT(0) BT(1) BT(2) BT(3)
  }

  const int mrow0 = blockIdx.x * 64 + wm * 16 + kg * 4;  // D rows this lane owns
#define ST(nt) { \
    const int c_ = nb + (nt) * 16 + lr; \
    const float bias_ = b_ih[c_] + (c_ < 2 * HDIM ? b_hh[c_] : 0.f); \
    float* d_ = gi + (size_t)mrow0 * G3 + c_; \
    d_[0]          = acc##nt[0] + bias_; \
    d_[G3]         = acc##nt[1] + bias_; \
    d_[2 * G3]     = acc##nt[2] + bias_; \
    d_[3 * G3]     = acc##nt[3] + bias_; }
  ST(0) ST(1) ST(2) ST(3)
}

// ---------------------------------------------------------------------------
// Kernel B: sequential GRU scan. 64 blocks x 512 thr.
// Thread (g=tid>>1, sub=tid&1): unit g, column half [128*sub, +128).
// W_n: 16 NAMED u4 fp16 (64 VGPRs) -> with ~35 overhead, NO SPILL (vs r8's
// 128 named + overhead > 128 budget -> ~25-reg spill, the step-time killer).
// W_r + W_z: e5m2 bytes in LDS (128 KB), unpack = byte<<8 (exact f16).
// n-gate (error-dominant through (1-z)*dn) keeps full fp16 precision.
// h fp16 in LDS (broadcast reads); gi/pred_w via global_load_lds.
// ---------------------------------------------------------------------------
__global__ __attribute__((amdgpu_flat_work_group_size(512, 512)))
__attribute__((amdgpu_waves_per_eu(2, 2)))
void gru_scan_kernel(
    const int* __restrict__ questions,
    const float* __restrict__ w_hh,    // [768][256]
    const float* __restrict__ b_hh,    // [768]
    const float* __restrict__ pred_w,  // [Q+1][256]
    const float* __restrict__ pred_b,  // [Q+1]
    const float* __restrict__ gi,      // [B*T][768] (b_ih + b_hh_{r,z} folded)
    float* __restrict__ out)           // [B][199]
{
  const int b    = blockIdx.x;
  const int tid  = threadIdx.x;
  const int lane = tid & 63;
  const int wave = tid >> 6;
  const int g    = tid >> 1;   // hidden unit 0..255
  const int sub  = tid & 1;    // column half
  const bool is_gate = (sub == 0);

  __shared__ __align__(16) u4_t rz_lds[16][512];   // 128 KB: e5m2 W_r|W_z
  __shared__ __align__(16) _Float16 hh[HDIM];      // fp16 h (512 B, linear)
  __shared__ float gi_buf[2][G3];
  __shared__ float pw_lds[2][HDIM];
  __shared__ float partial_lds[8];

  // ---- W_n -> 16 NAMED u4 (64 VGPRs, packed fp16) ----
  const float* wn_p = w_hh + (size_t)(2 * HDIM + g) * HDIM + 128 * sub;
#define WLOAD(name, p_, r_) u4_t name; { \
    f4_t f0_ = *(const f4_t*)((p_) + 8 * (r_)); \
    f4_t f1_ = *(const f4_t*)((p_) + 8 * (r_) + 4); \
    name[0] = pk(f0_[0], f0_[1]); name[1] = pk(f0_[2], f0_[3]); \
    name[2] = pk(f1_[0], f1_[1]); name[3] = pk(f1_[2], f1_[3]); }
  WLOAD(WN0,wn_p,0)  WLOAD(WN1,wn_p,1)  WLOAD(WN2,wn_p,2)  WLOAD(WN3,wn_p,3)
  WLOAD(WN4,wn_p,4)  WLOAD(WN5,wn_p,5)  WLOAD(WN6,wn_p,6)  WLOAD(WN7,wn_p,7)
  WLOAD(WN8,wn_p,8)  WLOAD(WN9,wn_p,9)  WLOAD(WN10,wn_p,10) WLOAD(WN11,wn_p,11)
  WLOAD(WN12,wn_p,12) WLOAD(WN13,wn_p,13) WLOAD(WN14,wn_p,14) WLOAD(WN15,wn_p,15)

  // ---- W_r, W_z -> LDS as packed e5m2: rz_lds[k][tid] = {r0,r1,z0,z1} ----
  {
    const float* wr_p = w_hh + (size_t)g * HDIM + 128 * sub;
    const float* wz_p = w_hh + (size_t)(HDIM + g) * HDIM + 128 * sub;
    for (int k = 0; k < 16; ++k) {
      u4_t v;
      v[0] = pk_e5m2x4(wr_p + 8 * k);
      v[1] = pk_e5m2x4(wr_p + 8 * k + 4);
      v[2] = pk_e5m2x4(wz_p + 8 * k);
      v[3] = pk_e5m2x4(wz_p + 8 * k + 4);
      rz_lds[k][tid] = v;
    }
  }

  float bhn = 0.f, h_prev = 0.f;
  if (is_gate) bhn = b_hh[2 * HDIM + g];

  if (tid < 32) { u4_t z_ = {0u,0u,0u,0u}; *(u4_t*)((char*)hh + tid * 16) = z_; }

  const int*   q_b  = questions + b * T_SEQ;
  const float* gi_b = gi + (size_t)b * T_SEQ * G3;

  // prologue staging for t=0
  if (wave < 6) {
    gload_lds4(gi_b + (2*wave)   * 64 + lane, &gi_buf[0][(2*wave)   * 64]);
    gload_lds4(gi_b + (2*wave+1) * 64 + lane, &gi_buf[0][(2*wave+1) * 64]);
  }
  if (wave == 6) {
    int q0 = q_b[0]; if (q0 < 0) q0 = 0;
    const float* pr = pred_w + (size_t)q0 * HDIM;
#pragma unroll
    for (int kk = 0; kk < 4; ++kk) gload_lds4(pr + 64*kk + lane, &pw_lds[0][64*kk]);
  }
  float pbA = 0.f, pbB = 0.f;
  if (tid == 0) { int q0 = q_b[0]; if (q0 < 0) q0 = 0; pbA = pred_b[q0]; }
  __syncthreads();   // full drain (prologue only)

  const char* hbase = (const char*)hh + 256 * sub;

#define KSTEP(k_) { \
    u4_t hv_ = *(const u4_t*)(hbase + 16 * (k_)); \
    u4_t rz_ = rz_lds[k_][tid]; \
    unsigned int r0_ = ((rz_[0] & 0xFFu) << 8) | ((rz_[0] & 0xFF00u) << 16); \
    unsigned int r1_ = ((rz_[0] >> 8) & 0xFF00u) | (rz_[0] & 0xFF000000u); \
    unsigned int r2_ = ((rz_[1] & 0xFFu) << 8) | ((rz_[1] & 0xFF00u) << 16); \
    unsigned int r3_ = ((rz_[1] >> 8) & 0xFF00u) | (rz_[1] & 0xFF000000u); \
    unsigned int z0_ = ((rz_[2] & 0xFFu) << 8) | ((rz_[2] & 0xFF00u) << 16); \
    unsigned int z1_ = ((rz_[2] >> 8) & 0xFF00u) | (rz_[2] & 0xFF000000u); \
    unsigned int z2_ = ((rz_[3] & 0xFFu) << 8) | ((rz_[3] & 0xFF00u) << 16); \
    unsigned int z3_ = ((rz_[3] >> 8) & 0xFF00u) | (rz_[3] & 0xFF000000u); \
    sr = dot2acc(r0_, hv_[0], sr); sr = dot2acc(r1_, hv_[1], sr); \
    sr = dot2acc(r2_, hv_[2], sr); sr = dot2acc(r3_, hv_[3], sr); \
    sz = dot2acc(z0_, hv_[0], sz); sz = dot2acc(z1_, hv_[1], sz); \
    sz = dot2acc(z2_, hv_[2], sz); sz = dot2acc(z3_, hv_[3], sz); \
    sn = dot2acc(WN##k_[0], hv_[0], sn); sn = dot2acc(WN##k_[1], hv_[1], sn); \
    sn = dot2acc(WN##k_[2], hv_[2], sn); sn = dot2acc(WN##k_[3], hv_[3], sn); }

#define STEP(T, C, N) do { \
    const int cur_ = (T) & 1; \
    /* phase 0: async prefetch of step (T)+1 */ \
    if (wave < 6) { \
      gload_lds4(gi_b + (size_t)((T)+1) * G3 + (2*wave)   * 64 + lane, \
                 &gi_buf[cur_ ^ 1][(2*wave)   * 64]); \
      gload_lds4(gi_b + (size_t)((T)+1) * G3 + (2*wave+1) * 64 + lane, \
                 &gi_buf[cur_ ^ 1][(2*wave+1) * 64]); \
    } \
    if (wave == 6) { \
      int tq_ = (T) + 1; tq_ = tq_ > 199 ? 199 : tq_; \
      int qn_ = q_b[tq_]; if (qn_ < 0) qn_ = 0; \
      const float* pr_ = pred_w + (size_t)qn_ * HDIM; \
      gload_lds4(pr_ + lane,       &pw_lds[cur_ ^ 1][0]); \
      gload_lds4(pr_ + 64 + lane,  &pw_lds[cur_ ^ 1][64]); \
      gload_lds4(pr_ + 128 + lane, &pw_lds[cur_ ^ 1][128]); \
      gload_lds4(pr_ + 192 + lane, &pw_lds[cur_ ^ 1][192]); \
    } \
    if (tid == 0) { \
      int tq_ = (T) + 1; tq_ = tq_ > 199 ? 199 : tq_; \
      int qn_ = q_b[tq_]; if (qn_ < 0) qn_ = 0; \
      pb##N = pred_b[qn_]; \
    } \
    /* phase 1: matvec — 192 dot2 + e5m2 unpack, broadcast h reads */ \
    float sr = 0.f, sz = 0.f, sn = 0.f; \
    KSTEP(0)  KSTEP(1)  KSTEP(2)  KSTEP(3) \
    KSTEP(4)  KSTEP(5)  KSTEP(6)  KSTEP(7) \
    KSTEP(8)  KSTEP(9)  KSTEP(10) KSTEP(11) \
    KSTEP(12) KSTEP(13) KSTEP(14) KSTEP(15) \
    sr += __shfl_xor(sr, 1); sz += __shfl_xor(sz, 1); sn += __shfl_xor(sn, 1); \
    __builtin_amdgcn_sched_barrier(0); \
    __builtin_amdgcn_s_barrier();   /* B1: all h_t reads done */ \
    __builtin_amdgcn_sched_barrier(0); \
    /* phase 2: gates on sub==0; h update + pred partial */ \
    if (is_gate) { \
      float r_ = __fdividef(1.f, 1.f + __expf(-(gi_buf[cur_][g] + sr))); \
      float z_ = __fdividef(1.f, 1.f + __expf(-(gi_buf[cur_][HDIM + g] + sz))); \
      float e2_ = __expf(2.f * (gi_buf[cur_][2 * HDIM + g] + r_ * (sn + bhn))); \
      float n_ = 1.f - __fdividef(2.f, e2_ + 1.f); \
      h_prev = (1.f - z_) * n_ + z_ * h_prev; \
      hh[g] = (_Float16)h_prev; \
      float pp_ = h_prev * pw_lds[cur_][g]; \
      pp_ += __shfl_xor(pp_, 2);  pp_ += __shfl_xor(pp_, 4); \
      pp_ += __shfl_xor(pp_, 8);  pp_ += __shfl_xor(pp_, 16); \
      pp_ += __shfl_xor(pp_, 32); \
      if (lane == 0) partial_lds[wave] = pp_; \
    } \
    __builtin_amdgcn_sched_barrier(0); \
    asm volatile("s_waitcnt vmcnt(0) lgkmcnt(0)" ::: "memory"); \
    __builtin_amdgcn_s_barrier();   /* B2: h_{t+1}, partials, prefetch visible */ \
    __builtin_amdgcn_sched_barrier(0); \
    /* phase 3: finish prediction for step (T) */ \
    if (tid < 8) { \
      float v_ = partial_lds[tid]; \
      v_ += __shfl_xor(v_, 1); v_ += __shfl_xor(v_, 2); v_ += __shfl_xor(v_, 4); \
      if (tid == 0) \
        out[b * TOUT + (T)] = __fdividef(1.f, 1.f + __expf(-(v_ + pb##C))); \
    } \
  } while (0)

  for (int T = 0; T < 198; T += 2) {
    STEP(T, A, B);
    STEP(T + 1, B, A);
  }
  STEP(198, A, B);
}

// ---------------------------------------------------------------------------
extern "C" void kernel_launch(void* const* d_in, const int* in_sizes, int n_in,
                              void* d_out, int out_size, void* d_ws, size_t ws_size,
                              hipStream_t stream) {
  const int*   questions = (const int*)d_in[1];
  const int*   answers   = (const int*)d_in[2];
  const float* q_emb     = (const float*)d_in[3];
  const float* a_emb     = (const float*)d_in[4];
  const float* w_ih      = (const float*)d_in[5];
  const float* w_hh      = (const float*)d_in[6];
  const float* b_ih      = (const float*)d_in[7];
  const float* b_hh      = (const float*)d_in[8];
  const float* pred_w    = (const float*)d_in[9];
  const float* pred_b    = (const float*)d_in[10];
  float* out = (float*)d_out;

  float* gi = (float*)d_ws;  // [64*200][768] fp32 = 39.3 MB

  gi_gemm_kernel<<<dim3(200, 6), 512, 0, stream>>>(
      questions, answers, q_emb, a_emb, w_ih, b_ih, b_hh, gi);

  gru_scan_kernel<<<64, 512, 0, stream>>>(
      questions, w_hh, b_hh, pred_w, pred_b, gi, out);
}

// Round 10
// 473.762 us; speedup vs baseline: 1.6638x; 1.4053x over previous
//
#include <hip/hip_runtime.h>
#include <hip/hip_bf16.h>

#define T_SEQ 200
#define HDIM  256
#define EDIM  256
#define G3    768   // 3*H
#define TOUT  199   // T-1

typedef _Float16 h2_t __attribute__((ext_vector_type(2)));
typedef _Float16 f16x8_t __attribute__((ext_vector_type(8)));
typedef unsigned int u4_t __attribute__((ext_vector_type(4)));
typedef unsigned int u2_t __attribute__((ext_vector_type(2)));
typedef float f4_t __attribute__((ext_vector_type(4)));

static __device__ __forceinline__ float dot2acc(unsigned int w, unsigned int h, float c) {
  return __builtin_amdgcn_fdot2(__builtin_bit_cast(h2_t, w),
                                __builtin_bit_cast(h2_t, h), c, false);
}

static __device__ __forceinline__ unsigned int pk(float x, float y) {
  h2_t p; p[0] = (_Float16)x; p[1] = (_Float16)y;
  return __builtin_bit_cast(unsigned int, p);
}

// 4 floats -> 4 e5m2 bytes (top byte of f16, round-half-up; weights <=0.0625 so
// no overflow). Validated numerically in round 9 (absmax identical to fp16).
static __device__ __forceinline__ unsigned int pk_e5m2x4(const float* p) {
  unsigned int r = 0;
#pragma unroll
  for (int j = 0; j < 4; ++j) {
    unsigned short b = __builtin_bit_cast(unsigned short, (_Float16)p[j]);
    r |= ((unsigned int)((unsigned short)(b + 0x80) >> 8)) << (8 * j);
  }
  return r;
}

// e5m2 bytes {b0,b1} of u -> h2 {b0<<8, b1<<8}: single v_perm_b32
static __device__ __forceinline__ unsigned int up_lo(unsigned int u) {
#if __has_builtin(__builtin_amdgcn_perm)
  return __builtin_amdgcn_perm(0u, u, 0x010C000Cu);
#else
  return ((u & 0xFFu) << 8) | ((u & 0xFF00u) << 16);
#endif
}
static __device__ __forceinline__ unsigned int up_hi(unsigned int u) {
#if __has_builtin(__builtin_amdgcn_perm)
  return __builtin_amdgcn_perm(0u, u, 0x030C020Cu);
#else
  return ((u >> 8) & 0xFF00u) | (u & 0xFF000000u);
#endif
}

// async global->LDS, 4 bytes per lane; lds base must be wave-uniform
static __device__ __forceinline__ void gload_lds4(const float* g, float* l) {
  __builtin_amdgcn_global_load_lds(
      (const __attribute__((address_space(1))) void*)g,
      (__attribute__((address_space(3))) void*)l, 4, 0, 0);
}

// ---------------------------------------------------------------------------
// xbuild: xh[m][e] = (f16)(q_emb[q[m]][e] + a_emb[a[m]][e]).  12800 x 256.
// ---------------------------------------------------------------------------
__global__ __attribute__((amdgpu_flat_work_group_size(256, 256)))
void xbuild_kernel(const int* __restrict__ questions,
                   const int* __restrict__ answers,
                   const float* __restrict__ q_emb,
                   const float* __restrict__ a_emb,
                   _Float16* __restrict__ xh)
{
  const int tid = threadIdx.x;
  const int m0  = blockIdx.x * 128;
  for (int i = 0; i < 128; ++i) {
    int m = m0 + i;
    int q = questions[m]; q = q < 0 ? 0 : q;
    int a = answers[m];   a = a < 0 ? 0 : a;
    xh[(size_t)m * EDIM + tid] =
        (_Float16)(q_emb[(size_t)q * EDIM + tid] + a_emb[(size_t)a * EDIM + tid]);
  }
}

// ---------------------------------------------------------------------------
// wcvt: wih_h = (f16)w_ih.  768*256 elems, 8/thread.
// ---------------------------------------------------------------------------
__global__ __attribute__((amdgpu_flat_work_group_size(256, 256)))
void wcvt_kernel(const float* __restrict__ w_ih, _Float16* __restrict__ wih_h)
{
  const int i = (blockIdx.x * 256 + threadIdx.x) * 8;
  f4_t a = *(const f4_t*)(w_ih + i);
  f4_t b = *(const f4_t*)(w_ih + i + 4);
  f16x8_t o;
  o[0]=(_Float16)a[0]; o[1]=(_Float16)a[1]; o[2]=(_Float16)a[2]; o[3]=(_Float16)a[3];
  o[4]=(_Float16)b[0]; o[5]=(_Float16)b[1]; o[6]=(_Float16)b[2]; o[7]=(_Float16)b[3];
  *(f16x8_t*)(wih_h + i) = o;
}

// ---------------------------------------------------------------------------
// Kernel A fast (MFMA f16, preconverted operands): gi = xh @ wih_h^T + bias.
// Same fragment pattern as round 9 (passed): k = 32i + 8*(lane>>4) + j on both
// operands; C/D col=lane&15, row=(lane>>4)*4+reg.
// ---------------------------------------------------------------------------
__global__ __attribute__((amdgpu_flat_work_group_size(512, 512)))
void gi_gemm_fast_kernel(const _Float16* __restrict__ xh,
                         const _Float16* __restrict__ wih_h,
                         const float* __restrict__ b_ih,
                         const float* __restrict__ b_hh,
                         float* __restrict__ gi)
{
  const int lane = threadIdx.x & 63;
  const int wv   = threadIdx.x >> 6;
  const int lr   = lane & 15;
  const int kg   = lane >> 4;
  const int wm   = wv & 3;
  const int wn   = wv >> 2;

  const int m  = blockIdx.x * 64 + wm * 16 + lr;
  const int nb = blockIdx.y * 128 + wn * 64;

  const _Float16* arow = xh + (size_t)m * EDIM + 8 * kg;
  const _Float16* wrow = wih_h + (size_t)(nb + lr) * EDIM + 8 * kg;

  f4_t zero4 = {0.f, 0.f, 0.f, 0.f};
  f4_t acc0 = zero4, acc1 = zero4, acc2 = zero4, acc3 = zero4;

#pragma unroll
  for (int i = 0; i < 8; ++i) {
    f16x8_t af = *(const f16x8_t*)(arow + 32 * i);
#define BTF(nt) { \
    f16x8_t bf = *(const f16x8_t*)(wrow + (size_t)(nt) * 16 * EDIM + 32 * i); \
    acc##nt = __builtin_amdgcn_mfma_f32_16x16x32_f16(af, bf, acc##nt, 0, 0, 0); }
    BTF(0) BTF(1) BTF(2) BTF(3)
  }

  const int mrow0 = blockIdx.x * 64 + wm * 16 + kg * 4;
#define STF(nt) { \
    const int c_ = nb + (nt) * 16 + lr; \
    const float bias_ = b_ih[c_] + (c_ < 2 * HDIM ? b_hh[c_] : 0.f); \
    float* d_ = gi + (size_t)mrow0 * G3 + c_; \
    d_[0]      = acc##nt[0] + bias_; \
    d_[G3]     = acc##nt[1] + bias_; \
    d_[2 * G3] = acc##nt[2] + bias_; \
    d_[3 * G3] = acc##nt[3] + bias_; }
  STF(0) STF(1) STF(2) STF(3)
}

// ---------------------------------------------------------------------------
// Kernel A fallback (round-9 version, proven): gather + cvt inline.
// ---------------------------------------------------------------------------
__global__ __attribute__((amdgpu_flat_work_group_size(512, 512)))
__attribute__((amdgpu_waves_per_eu(2, 2)))
void gi_gemm_kernel(
    const int* __restrict__ questions,
    const int* __restrict__ answers,
    const float* __restrict__ q_emb,
    const float* __restrict__ a_emb,
    const float* __restrict__ w_ih,
    const float* __restrict__ b_ih,
    const float* __restrict__ b_hh,
    float* __restrict__ gi)
{
  const int lane = threadIdx.x & 63;
  const int wv   = threadIdx.x >> 6;
  const int lr   = lane & 15;
  const int kg   = lane >> 4;
  const int wm   = wv & 3;
  const int wn   = wv >> 2;

  const int m  = blockIdx.x * 64 + wm * 16 + lr;
  const int nb = blockIdx.y * 128 + wn * 64;

  int q = questions[m]; q = q < 0 ? 0 : q;
  int a = answers[m];   a = a < 0 ? 0 : a;
  const float* qrow = q_emb + (size_t)q * EDIM + 8 * kg;
  const float* arow = a_emb + (size_t)a * EDIM + 8 * kg;
  const float* wrow = w_ih + (size_t)(nb + lr) * EDIM + 8 * kg;

  f4_t zero4 = {0.f, 0.f, 0.f, 0.f};
  f4_t acc0 = zero4, acc1 = zero4, acc2 = zero4, acc3 = zero4;

#pragma unroll
  for (int i = 0; i < 8; ++i) {
    f4_t q0 = *(const f4_t*)(qrow + 32 * i);
    f4_t q1 = *(const f4_t*)(qrow + 32 * i + 4);
    f4_t a0 = *(const f4_t*)(arow + 32 * i);
    f4_t a1 = *(const f4_t*)(arow + 32 * i + 4);
    f16x8_t af;
    af[0] = (_Float16)(q0[0] + a0[0]); af[1] = (_Float16)(q0[1] + a0[1]);
    af[2] = (_Float16)(q0[2] + a0[2]); af[3] = (_Float16)(q0[3] + a0[3]);
    af[4] = (_Float16)(q1[0] + a1[0]); af[5] = (_Float16)(q1[1] + a1[1]);
    af[6] = (_Float16)(q1[2] + a1[2]); af[7] = (_Float16)(q1[3] + a1[3]);
#define BT(nt) { \
    f4_t b0 = *(const f4_t*)(wrow + (nt) * 16 * EDIM + 32 * i); \
    f4_t b1 = *(const f4_t*)(wrow + (nt) * 16 * EDIM + 32 * i + 4); \
    f16x8_t bf; \
    bf[0] = (_Float16)b0[0]; bf[1] = (_Float16)b0[1]; \
    bf[2] = (_Float16)b0[2]; bf[3] = (_Float16)b0[3]; \
    bf[4] = (_Float16)b1[0]; bf[5] = (_Float16)b1[1]; \
    bf[6] = (_Float16)b1[2]; bf[7] = (_Float16)b1[3]; \
    acc##nt = __builtin_amdgcn_mfma_f32_16x16x32_f16(af, bf, acc##nt, 0, 0, 0); }
    BT(0) BT(1) BT(2) BT(3)
  }

  const int mrow0 = blockIdx.x * 64 + wm * 16 + kg * 4;
#define ST(nt) { \
    const int c_ = nb + (nt) * 16 + lr; \
    const float bias_ = b_ih[c_] + (c_ < 2 * HDIM ? b_hh[c_] : 0.f); \
    float* d_ = gi + (size_t)mrow0 * G3 + c_; \
    d_[0]      = acc##nt[0] + bias_; \
    d_[G3]     = acc##nt[1] + bias_; \
    d_[2 * G3] = acc##nt[2] + bias_; \
    d_[3 * G3] = acc##nt[3] + bias_; }
  ST(0) ST(1) ST(2) ST(3)
}

// ---------------------------------------------------------------------------
// Kernel B: GRU scan, 64 blocks x 512 thr. ONE barrier per step.
// Thread (g=tid>>1, sub=tid&1): unit g, col half [128*sub,+128).
// W_n fp16 in 16 named u4 (64 regs); W_r e5m2 in 16 named u2 (32 regs);
// W_z e5m2 in LDS (64 KB). Total named weight regs = 96 -> no spill.
// hh double-buffered (no read/write hazard); pred deferred one step through
// pbuf (finisher for t-1 runs inside step t) -> single __syncthreads()/step.
// ---------------------------------------------------------------------------
__global__ __attribute__((amdgpu_flat_work_group_size(512, 512)))
__attribute__((amdgpu_waves_per_eu(2, 2)))
void gru_scan_kernel(
    const int* __restrict__ questions,
    const float* __restrict__ w_hh,    // [768][256]
    const float* __restrict__ b_hh,    // [768]
    const float* __restrict__ pred_w,  // [Q+1][256]
    const float* __restrict__ pred_b,  // [Q+1]
    const float* __restrict__ gi,      // [B*T][768] (b_ih + b_hh_{r,z} folded)
    float* __restrict__ out)           // [B][199]
{
  const int b    = blockIdx.x;
  const int tid  = threadIdx.x;
  const int lane = tid & 63;
  const int wave = tid >> 6;
  const int g    = tid >> 1;   // hidden unit 0..255
  const int sub  = tid & 1;    // column half

  __shared__ __align__(16) u2_t zE[16][512];        // 64 KB: e5m2 W_z
  __shared__ __align__(16) _Float16 hh[2][HDIM];    // fp16 h double-buffer
  __shared__ float gi_buf[2][G3];
  __shared__ float pw_lds[2][HDIM];
  __shared__ float pbuf[2][16];                     // [0..7] wave partials, [8] pred_b

  // ---- W_n -> 16 named u4 fp16 (64 VGPRs) ----
  const float* wn_p = w_hh + (size_t)(2 * HDIM + g) * HDIM + 128 * sub;
#define WLOAD(name, p_, r_) u4_t name; { \
    f4_t f0_ = *(const f4_t*)((p_) + 8 * (r_)); \
    f4_t f1_ = *(const f4_t*)((p_) + 8 * (r_) + 4); \
    name[0] = pk(f0_[0], f0_[1]); name[1] = pk(f0_[2], f0_[3]); \
    name[2] = pk(f1_[0], f1_[1]); name[3] = pk(f1_[2], f1_[3]); }
  WLOAD(WN0,wn_p,0)  WLOAD(WN1,wn_p,1)  WLOAD(WN2,wn_p,2)  WLOAD(WN3,wn_p,3)
  WLOAD(WN4,wn_p,4)  WLOAD(WN5,wn_p,5)  WLOAD(WN6,wn_p,6)  WLOAD(WN7,wn_p,7)
  WLOAD(WN8,wn_p,8)  WLOAD(WN9,wn_p,9)  WLOAD(WN10,wn_p,10) WLOAD(WN11,wn_p,11)
  WLOAD(WN12,wn_p,12) WLOAD(WN13,wn_p,13) WLOAD(WN14,wn_p,14) WLOAD(WN15,wn_p,15)

  // ---- W_r -> 16 named u2 e5m2 (32 VGPRs) ----
  const float* wr_p = w_hh + (size_t)g * HDIM + 128 * sub;
#define RLOAD(name, r_) u2_t name; { \
    name[0] = pk_e5m2x4(wr_p + 8 * (r_)); \
    name[1] = pk_e5m2x4(wr_p + 8 * (r_) + 4); }
  RLOAD(RU0,0)  RLOAD(RU1,1)  RLOAD(RU2,2)  RLOAD(RU3,3)
  RLOAD(RU4,4)  RLOAD(RU5,5)  RLOAD(RU6,6)  RLOAD(RU7,7)
  RLOAD(RU8,8)  RLOAD(RU9,9)  RLOAD(RU10,10) RLOAD(RU11,11)
  RLOAD(RU12,12) RLOAD(RU13,13) RLOAD(RU14,14) RLOAD(RU15,15)

  // ---- W_z -> LDS e5m2 ----
  {
    const float* wz_p = w_hh + (size_t)(HDIM + g) * HDIM + 128 * sub;
    for (int k = 0; k < 16; ++k) {
      u2_t v;
      v[0] = pk_e5m2x4(wz_p + 8 * k);
      v[1] = pk_e5m2x4(wz_p + 8 * k + 4);
      zE[k][tid] = v;
    }
  }

  const float bhn = b_hh[2 * HDIM + g];
  float h_prev = 0.f;

  if (tid < 32) { u4_t z_ = {0u,0u,0u,0u}; *(u4_t*)((char*)&hh[0][0] + tid * 16) = z_; }

  const int*   q_b  = questions + b * T_SEQ;
  const float* gi_b = gi + (size_t)b * T_SEQ * G3;

  // prologue: stage gi[0], pw[0]
  if (wave < 6) {
    gload_lds4(gi_b + (2*wave)   * 64 + lane, &gi_buf[0][(2*wave)   * 64]);
    gload_lds4(gi_b + (2*wave+1) * 64 + lane, &gi_buf[0][(2*wave+1) * 64]);
  }
  if (wave == 6) {
    int q0 = q_b[0]; if (q0 < 0) q0 = 0;
    const float* pr = pred_w + (size_t)q0 * HDIM;
#pragma unroll
    for (int kk = 0; kk < 4; ++kk) gload_lds4(pr + 64*kk + lane, &pw_lds[0][64*kk]);
  }
  __syncthreads();

#define KSTEP(k_) { \
    u4_t hv_ = *(const u4_t*)(hcur + 16 * (k_)); \
    u2_t zu_ = zE[k_][tid]; \
    sn = dot2acc(WN##k_[0], hv_[0], sn); sn = dot2acc(WN##k_[1], hv_[1], sn); \
    sn = dot2acc(WN##k_[2], hv_[2], sn); sn = dot2acc(WN##k_[3], hv_[3], sn); \
    sr = dot2acc(up_lo(RU##k_[0]), hv_[0], sr); \
    sr = dot2acc(up_hi(RU##k_[0]), hv_[1], sr); \
    sr = dot2acc(up_lo(RU##k_[1]), hv_[2], sr); \
    sr = dot2acc(up_hi(RU##k_[1]), hv_[3], sr); \
    sz = dot2acc(up_lo(zu_[0]), hv_[0], sz); \
    sz = dot2acc(up_hi(zu_[0]), hv_[1], sz); \
    sz = dot2acc(up_lo(zu_[1]), hv_[2], sz); \
    sz = dot2acc(up_hi(zu_[1]), hv_[3], sz); }

  for (int t = 0; t < TOUT; ++t) {
    const int cur = t & 1, nxt = cur ^ 1;

    // prefetch step t+1 inputs (t+1 <= 199, valid row)
    if (wave < 6) {
      gload_lds4(gi_b + (size_t)(t+1) * G3 + (2*wave)   * 64 + lane,
                 &gi_buf[nxt][(2*wave)   * 64]);
      gload_lds4(gi_b + (size_t)(t+1) * G3 + (2*wave+1) * 64 + lane,
                 &gi_buf[nxt][(2*wave+1) * 64]);
    }
    if (wave == 6) {
      int qn = q_b[t+1]; if (qn < 0) qn = 0;
      const float* pr = pred_w + (size_t)qn * HDIM;
      gload_lds4(pr + lane,       &pw_lds[nxt][0]);
      gload_lds4(pr + 64 + lane,  &pw_lds[nxt][64]);
      gload_lds4(pr + 128 + lane, &pw_lds[nxt][128]);
      gload_lds4(pr + 192 + lane, &pw_lds[nxt][192]);
    }
    float pbv = 0.f;
    if (tid == 8) { int qt = q_b[t]; if (qt < 0) qt = 0; pbv = pred_b[qt]; }

    // matvec on h_t (hh[cur]); h reads are 2-address broadcasts
    const char* hcur = (const char*)&hh[cur][0] + 256 * sub;
    float sr = 0.f, sz = 0.f, sn = 0.f;
    KSTEP(0)  KSTEP(1)  KSTEP(2)  KSTEP(3)
    KSTEP(4)  KSTEP(5)  KSTEP(6)  KSTEP(7)
    KSTEP(8)  KSTEP(9)  KSTEP(10) KSTEP(11)
    KSTEP(12) KSTEP(13) KSTEP(14) KSTEP(15)
    sr += __shfl_xor(sr, 1); sz += __shfl_xor(sz, 1); sn += __shfl_xor(sn, 1);

    // finisher for step t-1 (partials published by last barrier)
    if (t > 0 && tid < 8) {
      float v = pbuf[nxt][tid];
      v += __shfl_xor(v, 1); v += __shfl_xor(v, 2); v += __shfl_xor(v, 4);
      if (tid == 0)
        out[b * TOUT + t - 1] = __fdividef(1.f, 1.f + __expf(-(v + pbuf[nxt][8])));
    }

    // gates (both lanes of the pair compute redundantly)
    float r_ = __fdividef(1.f, 1.f + __expf(-(gi_buf[cur][g] + sr)));
    float z_ = __fdividef(1.f, 1.f + __expf(-(gi_buf[cur][HDIM + g] + sz)));
    float e2 = __expf(2.f * (gi_buf[cur][2 * HDIM + g] + r_ * (sn + bhn)));
    float n_ = 1.f - __fdividef(2.f, e2 + 1.f);
    h_prev = (1.f - z_) * n_ + z_ * h_prev;

    float pp = 0.f;
    if (sub == 0) {
      hh[nxt][g] = (_Float16)h_prev;
      pp = h_prev * pw_lds[cur][g];
    }
    pp += __shfl_xor(pp, 1);  pp += __shfl_xor(pp, 2);
    pp += __shfl_xor(pp, 4);  pp += __shfl_xor(pp, 8);
    pp += __shfl_xor(pp, 16); pp += __shfl_xor(pp, 32);
    if (lane == 0) pbuf[cur][wave] = pp;
    if (tid == 8)  pbuf[cur][8] = pbv;

    __syncthreads();   // the ONLY barrier: publishes hh[nxt], pbuf[cur], prefetches
  }

  // epilogue: finish step 198 (parity 0)
  if (tid < 8) {
    float v = pbuf[0][tid];
    v += __shfl_xor(v, 1); v += __shfl_xor(v, 2); v += __shfl_xor(v, 4);
    if (tid == 0)
      out[b * TOUT + 198] = __fdividef(1.f, 1.f + __expf(-(v + pbuf[0][8])));
  }
}

// ---------------------------------------------------------------------------
extern "C" void kernel_launch(void* const* d_in, const int* in_sizes, int n_in,
                              void* d_out, int out_size, void* d_ws, size_t ws_size,
                              hipStream_t stream) {
  const int*   questions = (const int*)d_in[1];
  const int*   answers   = (const int*)d_in[2];
  const float* q_emb     = (const float*)d_in[3];
  const float* a_emb     = (const float*)d_in[4];
  const float* w_ih      = (const float*)d_in[5];
  const float* w_hh      = (const float*)d_in[6];
  const float* b_ih      = (const float*)d_in[7];
  const float* b_hh      = (const float*)d_in[8];
  const float* pred_w    = (const float*)d_in[9];
  const float* pred_b    = (const float*)d_in[10];
  float* out = (float*)d_out;

  const size_t gi_bytes = (size_t)64 * T_SEQ * G3 * 4;     // 39.3 MB
  const size_t xh_bytes = (size_t)64 * T_SEQ * EDIM * 2;   // 6.55 MB
  const size_t wh_bytes = (size_t)G3 * EDIM * 2;           // 0.39 MB
  float* gi = (float*)d_ws;

  if (ws_size >= gi_bytes + xh_bytes + wh_bytes) {
    _Float16* xh    = (_Float16*)((char*)d_ws + gi_bytes);
    _Float16* wih_h = (_Float16*)((char*)d_ws + gi_bytes + xh_bytes);
    xbuild_kernel<<<100, 256, 0, stream>>>(questions, answers, q_emb, a_emb, xh);
    wcvt_kernel<<<96, 256, 0, stream>>>(w_ih, wih_h);
    gi_gemm_fast_kernel<<<dim3(200, 6), 512, 0, stream>>>(xh, wih_h, b_ih, b_hh, gi);
  } else {
    gi_gemm_kernel<<<dim3(200, 6), 512, 0, stream>>>(
        questions, answers, q_emb, a_emb, w_ih, b_ih, b_hh, gi);
  }

  gru_scan_kernel<<<64, 512, 0, stream>>>(
      questions, w_hh, b_hh, pred_w, pred_b, gi, out);
}

// Round 11
// 458.728 us; speedup vs baseline: 1.7183x; 1.0328x over previous
//
#include <hip/hip_runtime.h>
#include <hip/hip_bf16.h>

#define T_SEQ 200
#define HDIM  256
#define EDIM  256
#define G3    768   // 3*H
#define TOUT  199   // T-1

typedef _Float16 h2_t __attribute__((ext_vector_type(2)));
typedef _Float16 f16x8_t __attribute__((ext_vector_type(8)));
typedef unsigned int u4_t __attribute__((ext_vector_type(4)));
typedef unsigned int u2_t __attribute__((ext_vector_type(2)));
typedef float f4_t __attribute__((ext_vector_type(4)));

static __device__ __forceinline__ float dot2acc(unsigned int w, unsigned int h, float c) {
  return __builtin_amdgcn_fdot2(__builtin_bit_cast(h2_t, w),
                                __builtin_bit_cast(h2_t, h), c, false);
}

static __device__ __forceinline__ unsigned int pk(float x, float y) {
  h2_t p; p[0] = (_Float16)x; p[1] = (_Float16)y;
  return __builtin_bit_cast(unsigned int, p);
}

// 4 floats -> 4 e5m2 bytes (top byte of f16, round-half-up; weights <=0.0625
// so no overflow). Numerics validated rounds 9/10 (absmax identical to fp16).
static __device__ __forceinline__ unsigned int pk_e5m2x4(const float* p) {
  unsigned int r = 0;
#pragma unroll
  for (int j = 0; j < 4; ++j) {
    unsigned short b = __builtin_bit_cast(unsigned short, (_Float16)p[j]);
    r |= ((unsigned int)((unsigned short)(b + 0x80) >> 8)) << (8 * j);
  }
  return r;
}

// e5m2 bytes {b0,b1} of u -> h2 {b0<<8, b1<<8}: single v_perm_b32
static __device__ __forceinline__ unsigned int up_lo(unsigned int u) {
  return __builtin_amdgcn_perm(0u, u, 0x010C000Cu);
}
static __device__ __forceinline__ unsigned int up_hi(unsigned int u) {
  return __builtin_amdgcn_perm(0u, u, 0x030C020Cu);
}

// async global->LDS, 4 bytes per lane; lds base must be wave-uniform
static __device__ __forceinline__ void gload_lds4(const float* g, float* l) {
  __builtin_amdgcn_global_load_lds(
      (const __attribute__((address_space(1))) void*)g,
      (__attribute__((address_space(3))) void*)l, 4, 0, 0);
}

// ---------------------------------------------------------------------------
// xbuild (+wcvt fused): xh[m][e] = (f16)(q_emb[q[m]][e] + a_emb[a[m]][e]);
// also converts w_ih -> fp16 (8 elems/thread across the grid).
// ---------------------------------------------------------------------------
__global__ __attribute__((amdgpu_flat_work_group_size(256, 256)))
void xbuild_kernel(const int* __restrict__ questions,
                   const int* __restrict__ answers,
                   const float* __restrict__ q_emb,
                   const float* __restrict__ a_emb,
                   const float* __restrict__ w_ih,
                   _Float16* __restrict__ xh,
                   _Float16* __restrict__ wih_h)
{
  const int tid = threadIdx.x;
  // fused w_ih conversion: 100 blocks x 256 thr x 8 = 204800 >= 196608
  {
    int wi = (blockIdx.x * 256 + tid) * 8;
    if (wi < G3 * EDIM) {
      f4_t a = *(const f4_t*)(w_ih + wi);
      f4_t b = *(const f4_t*)(w_ih + wi + 4);
      f16x8_t o;
      o[0]=(_Float16)a[0]; o[1]=(_Float16)a[1]; o[2]=(_Float16)a[2]; o[3]=(_Float16)a[3];
      o[4]=(_Float16)b[0]; o[5]=(_Float16)b[1]; o[6]=(_Float16)b[2]; o[7]=(_Float16)b[3];
      *(f16x8_t*)(wih_h + wi) = o;
    }
  }
  const int m0 = blockIdx.x * 128;
  for (int i = 0; i < 128; ++i) {
    int m = m0 + i;
    int q = questions[m]; q = q < 0 ? 0 : q;
    int a = answers[m];   a = a < 0 ? 0 : a;
    xh[(size_t)m * EDIM + tid] =
        (_Float16)(q_emb[(size_t)q * EDIM + tid] + a_emb[(size_t)a * EDIM + tid]);
  }
}

// ---------------------------------------------------------------------------
// Kernel A fast (MFMA f16, preconverted operands): gi = xh @ wih_h^T + bias.
// Fragment pattern proven rounds 9/10.
// ---------------------------------------------------------------------------
__global__ __attribute__((amdgpu_flat_work_group_size(512, 512)))
void gi_gemm_fast_kernel(const _Float16* __restrict__ xh,
                         const _Float16* __restrict__ wih_h,
                         const float* __restrict__ b_ih,
                         const float* __restrict__ b_hh,
                         float* __restrict__ gi)
{
  const int lane = threadIdx.x & 63;
  const int wv   = threadIdx.x >> 6;
  const int lr   = lane & 15;
  const int kg   = lane >> 4;
  const int wm   = wv & 3;
  const int wn   = wv >> 2;

  const int m  = blockIdx.x * 64 + wm * 16 + lr;
  const int nb = blockIdx.y * 128 + wn * 64;

  const _Float16* arow = xh + (size_t)m * EDIM + 8 * kg;
  const _Float16* wrow = wih_h + (size_t)(nb + lr) * EDIM + 8 * kg;

  f4_t zero4 = {0.f, 0.f, 0.f, 0.f};
  f4_t acc0 = zero4, acc1 = zero4, acc2 = zero4, acc3 = zero4;

#pragma unroll
  for (int i = 0; i < 8; ++i) {
    f16x8_t af = *(const f16x8_t*)(arow + 32 * i);
#define BTF(nt) { \
    f16x8_t bf = *(const f16x8_t*)(wrow + (size_t)(nt) * 16 * EDIM + 32 * i); \
    acc##nt = __builtin_amdgcn_mfma_f32_16x16x32_f16(af, bf, acc##nt, 0, 0, 0); }
    BTF(0) BTF(1) BTF(2) BTF(3)
  }

  const int mrow0 = blockIdx.x * 64 + wm * 16 + kg * 4;
#define STF(nt) { \
    const int c_ = nb + (nt) * 16 + lr; \
    const float bias_ = b_ih[c_] + (c_ < 2 * HDIM ? b_hh[c_] : 0.f); \
    float* d_ = gi + (size_t)mrow0 * G3 + c_; \
    d_[0]      = acc##nt[0] + bias_; \
    d_[G3]     = acc##nt[1] + bias_; \
    d_[2 * G3] = acc##nt[2] + bias_; \
    d_[3 * G3] = acc##nt[3] + bias_; }
  STF(0) STF(1) STF(2) STF(3)
}

// ---------------------------------------------------------------------------
// Kernel A fallback (round-9 version, proven): gather + cvt inline.
// ---------------------------------------------------------------------------
__global__ __attribute__((amdgpu_flat_work_group_size(512, 512)))
__attribute__((amdgpu_waves_per_eu(2, 2)))
void gi_gemm_kernel(
    const int* __restrict__ questions,
    const int* __restrict__ answers,
    const float* __restrict__ q_emb,
    const float* __restrict__ a_emb,
    const float* __restrict__ w_ih,
    const float* __restrict__ b_ih,
    const float* __restrict__ b_hh,
    float* __restrict__ gi)
{
  const int lane = threadIdx.x & 63;
  const int wv   = threadIdx.x >> 6;
  const int lr   = lane & 15;
  const int kg   = lane >> 4;
  const int wm   = wv & 3;
  const int wn   = wv >> 2;

  const int m  = blockIdx.x * 64 + wm * 16 + lr;
  const int nb = blockIdx.y * 128 + wn * 64;

  int q = questions[m]; q = q < 0 ? 0 : q;
  int a = answers[m];   a = a < 0 ? 0 : a;
  const float* qrow = q_emb + (size_t)q * EDIM + 8 * kg;
  const float* arow = a_emb + (size_t)a * EDIM + 8 * kg;
  const float* wrow = w_ih + (size_t)(nb + lr) * EDIM + 8 * kg;

  f4_t zero4 = {0.f, 0.f, 0.f, 0.f};
  f4_t acc0 = zero4, acc1 = zero4, acc2 = zero4, acc3 = zero4;

#pragma unroll
  for (int i = 0; i < 8; ++i) {
    f4_t q0 = *(const f4_t*)(qrow + 32 * i);
    f4_t q1 = *(const f4_t*)(qrow + 32 * i + 4);
    f4_t a0 = *(const f4_t*)(arow + 32 * i);
    f4_t a1 = *(const f4_t*)(arow + 32 * i + 4);
    f16x8_t af;
    af[0] = (_Float16)(q0[0] + a0[0]); af[1] = (_Float16)(q0[1] + a0[1]);
    af[2] = (_Float16)(q0[2] + a0[2]); af[3] = (_Float16)(q0[3] + a0[3]);
    af[4] = (_Float16)(q1[0] + a1[0]); af[5] = (_Float16)(q1[1] + a1[1]);
    af[6] = (_Float16)(q1[2] + a1[2]); af[7] = (_Float16)(q1[3] + a1[3]);
#define BT(nt) { \
    f4_t b0 = *(const f4_t*)(wrow + (nt) * 16 * EDIM + 32 * i); \
    f4_t b1 = *(const f4_t*)(wrow + (nt) * 16 * EDIM + 32 * i + 4); \
    f16x8_t bf; \
    bf[0] = (_Float16)b0[0]; bf[1] = (_Float16)b0[1]; \
    bf[2] = (_Float16)b0[2]; bf[3] = (_Float16)b0[3]; \
    bf[4] = (_Float16)b1[0]; bf[5] = (_Float16)b1[1]; \
    bf[6] = (_Float16)b1[2]; bf[7] = (_Float16)b1[3]; \
    acc##nt = __builtin_amdgcn_mfma_f32_16x16x32_f16(af, bf, acc##nt, 0, 0, 0); }
    BT(0) BT(1) BT(2) BT(3)
  }

  const int mrow0 = blockIdx.x * 64 + wm * 16 + kg * 4;
#define ST(nt) { \
    const int c_ = nb + (nt) * 16 + lr; \
    const float bias_ = b_ih[c_] + (c_ < 2 * HDIM ? b_hh[c_] : 0.f); \
    float* d_ = gi + (size_t)mrow0 * G3 + c_; \
    d_[0]      = acc##nt[0] + bias_; \
    d_[G3]     = acc##nt[1] + bias_; \
    d_[2 * G3] = acc##nt[2] + bias_; \
    d_[3 * G3] = acc##nt[3] + bias_; }
  ST(0) ST(1) ST(2) ST(3)
}

// ---------------------------------------------------------------------------
// Kernel B: GRU scan, 64 blocks x 512 thr, ONE barrier per step (r10 base).
// Round-11 change: software-pipelined LDS reads. h chunks double-buffered
// (hvA/hvB, chunk k+1 issued before chunk k's dot2s); chunk-0 read + all
// gate/pred inputs (gir/giz/gin/pwv) issued right after the barrier so their
// ~120-cyc LDS latency hides under the prefetch-address block and matvec.
// (r2/r8/r10 all sat at 1.7-2.0us/step regardless of weight placement ->
//  the floor is dependent-LDS-read latency, not bandwidth or residency.)
// ---------------------------------------------------------------------------
__global__ __attribute__((amdgpu_flat_work_group_size(512, 512)))
__attribute__((amdgpu_waves_per_eu(2, 2)))
void gru_scan_kernel(
    const int* __restrict__ questions,
    const float* __restrict__ w_hh,    // [768][256]
    const float* __restrict__ b_hh,    // [768]
    const float* __restrict__ pred_w,  // [Q+1][256]
    const float* __restrict__ pred_b,  // [Q+1]
    const float* __restrict__ gi,      // [B*T][768] (b_ih + b_hh_{r,z} folded)
    float* __restrict__ out)           // [B][199]
{
  const int b    = blockIdx.x;
  const int tid  = threadIdx.x;
  const int lane = tid & 63;
  const int wave = tid >> 6;
  const int g    = tid >> 1;   // hidden unit 0..255
  const int sub  = tid & 1;    // column half

  __shared__ __align__(16) u2_t zE[16][512];        // 64 KB: e5m2 W_z
  __shared__ __align__(16) _Float16 hh[2][HDIM];    // fp16 h double-buffer
  __shared__ float gi_buf[2][G3];
  __shared__ float pw_lds[2][HDIM];
  __shared__ float pbuf[2][16];                     // [0..7] partials, [8] pred_b

  // ---- W_n -> 16 named u4 fp16 (64 VGPRs) ----
  const float* wn_p = w_hh + (size_t)(2 * HDIM + g) * HDIM + 128 * sub;
#define WLOAD(name, p_, r_) u4_t name; { \
    f4_t f0_ = *(const f4_t*)((p_) + 8 * (r_)); \
    f4_t f1_ = *(const f4_t*)((p_) + 8 * (r_) + 4); \
    name[0] = pk(f0_[0], f0_[1]); name[1] = pk(f0_[2], f0_[3]); \
    name[2] = pk(f1_[0], f1_[1]); name[3] = pk(f1_[2], f1_[3]); }
  WLOAD(WN0,wn_p,0)  WLOAD(WN1,wn_p,1)  WLOAD(WN2,wn_p,2)  WLOAD(WN3,wn_p,3)
  WLOAD(WN4,wn_p,4)  WLOAD(WN5,wn_p,5)  WLOAD(WN6,wn_p,6)  WLOAD(WN7,wn_p,7)
  WLOAD(WN8,wn_p,8)  WLOAD(WN9,wn_p,9)  WLOAD(WN10,wn_p,10) WLOAD(WN11,wn_p,11)
  WLOAD(WN12,wn_p,12) WLOAD(WN13,wn_p,13) WLOAD(WN14,wn_p,14) WLOAD(WN15,wn_p,15)

  // ---- W_r -> 16 named u2 e5m2 (32 VGPRs) ----
  const float* wr_p = w_hh + (size_t)g * HDIM + 128 * sub;
#define RLOAD(name, r_) u2_t name; { \
    name[0] = pk_e5m2x4(wr_p + 8 * (r_)); \
    name[1] = pk_e5m2x4(wr_p + 8 * (r_) + 4); }
  RLOAD(RU0,0)  RLOAD(RU1,1)  RLOAD(RU2,2)  RLOAD(RU3,3)
  RLOAD(RU4,4)  RLOAD(RU5,5)  RLOAD(RU6,6)  RLOAD(RU7,7)
  RLOAD(RU8,8)  RLOAD(RU9,9)  RLOAD(RU10,10) RLOAD(RU11,11)
  RLOAD(RU12,12) RLOAD(RU13,13) RLOAD(RU14,14) RLOAD(RU15,15)

  // ---- W_z -> LDS e5m2 ----
  {
    const float* wz_p = w_hh + (size_t)(HDIM + g) * HDIM + 128 * sub;
    for (int k = 0; k < 16; ++k) {
      u2_t v;
      v[0] = pk_e5m2x4(wz_p + 8 * k);
      v[1] = pk_e5m2x4(wz_p + 8 * k + 4);
      zE[k][tid] = v;
    }
  }

  const float bhn = b_hh[2 * HDIM + g];
  float h_prev = 0.f;

  if (tid < 32) { u4_t z_ = {0u,0u,0u,0u}; *(u4_t*)((char*)&hh[0][0] + tid * 16) = z_; }

  const int*   q_b  = questions + b * T_SEQ;
  const float* gi_b = gi + (size_t)b * T_SEQ * G3;

  // prologue: stage gi[0], pw[0]
  if (wave < 6) {
    gload_lds4(gi_b + (2*wave)   * 64 + lane, &gi_buf[0][(2*wave)   * 64]);
    gload_lds4(gi_b + (2*wave+1) * 64 + lane, &gi_buf[0][(2*wave+1) * 64]);
  }
  if (wave == 6) {
    int q0 = q_b[0]; if (q0 < 0) q0 = 0;
    const float* pr = pred_w + (size_t)q0 * HDIM;
#pragma unroll
    for (int kk = 0; kk < 4; ++kk) gload_lds4(pr + 64*kk + lane, &pw_lds[0][64*kk]);
  }
  __syncthreads();

#define CHUNK(k_, C_, N_) { \
    if ((k_) < 15) hv##N_ = *(const u4_t*)(hcur + 16 * ((k_) + 1)); \
    u2_t zu_ = zE[k_][tid]; \
    sn = dot2acc(WN##k_[0], hv##C_[0], sn); sn = dot2acc(WN##k_[1], hv##C_[1], sn); \
    sn = dot2acc(WN##k_[2], hv##C_[2], sn); sn = dot2acc(WN##k_[3], hv##C_[3], sn); \
    sr = dot2acc(up_lo(RU##k_[0]), hv##C_[0], sr); \
    sr = dot2acc(up_hi(RU##k_[0]), hv##C_[1], sr); \
    sr = dot2acc(up_lo(RU##k_[1]), hv##C_[2], sr); \
    sr = dot2acc(up_hi(RU##k_[1]), hv##C_[3], sr); \
    sz = dot2acc(up_lo(zu_[0]), hv##C_[0], sz); \
    sz = dot2acc(up_hi(zu_[0]), hv##C_[1], sz); \
    sz = dot2acc(up_lo(zu_[1]), hv##C_[2], sz); \
    sz = dot2acc(up_hi(zu_[1]), hv##C_[3], sz); }

  for (int t = 0; t < TOUT; ++t) {
    const int cur = t & 1, nxt = cur ^ 1;

    // issue chunk-0 h read + gate/pred inputs FIRST (latency hides under
    // the prefetch-address block below)
    const char* hcur = (const char*)&hh[cur][0] + 256 * sub;
    u4_t hvA = *(const u4_t*)(hcur);
    u4_t hvB;
    float gir = gi_buf[cur][g];
    float giz = gi_buf[cur][HDIM + g];
    float gin = gi_buf[cur][2 * HDIM + g];
    float pwv = pw_lds[cur][g];

    // prefetch step t+1 inputs (async, drains at this step's barrier)
    if (wave < 6) {
      gload_lds4(gi_b + (size_t)(t+1) * G3 + (2*wave)   * 64 + lane,
                 &gi_buf[nxt][(2*wave)   * 64]);
      gload_lds4(gi_b + (size_t)(t+1) * G3 + (2*wave+1) * 64 + lane,
                 &gi_buf[nxt][(2*wave+1) * 64]);
    }
    if (wave == 6) {
      int qn = q_b[t+1]; if (qn < 0) qn = 0;
      const float* pr = pred_w + (size_t)qn * HDIM;
      gload_lds4(pr + lane,       &pw_lds[nxt][0]);
      gload_lds4(pr + 64 + lane,  &pw_lds[nxt][64]);
      gload_lds4(pr + 128 + lane, &pw_lds[nxt][128]);
      gload_lds4(pr + 192 + lane, &pw_lds[nxt][192]);
    }
    float pbv = 0.f;
    if (tid == 8) { int qt = q_b[t]; if (qt < 0) qt = 0; pbv = pred_b[qt]; }

    // software-pipelined matvec: h chunk k+1 in flight while dotting chunk k
    float sr = 0.f, sz = 0.f, sn = 0.f;
    CHUNK(0,A,B)  CHUNK(1,B,A)  CHUNK(2,A,B)  CHUNK(3,B,A)
    CHUNK(4,A,B)  CHUNK(5,B,A)  CHUNK(6,A,B)  CHUNK(7,B,A)
    CHUNK(8,A,B)  CHUNK(9,B,A)  CHUNK(10,A,B) CHUNK(11,B,A)
    CHUNK(12,A,B) CHUNK(13,B,A) CHUNK(14,A,B) CHUNK(15,B,A)
    sr += __shfl_xor(sr, 1); sz += __shfl_xor(sz, 1); sn += __shfl_xor(sn, 1);

    // finisher for step t-1 (partials published by last barrier)
    if (t > 0 && tid < 8) {
      float v = pbuf[nxt][tid];
      v += __shfl_xor(v, 1); v += __shfl_xor(v, 2); v += __shfl_xor(v, 4);
      if (tid == 0)
        out[b * TOUT + t - 1] = __fdividef(1.f, 1.f + __expf(-(v + pbuf[nxt][8])));
    }

    // gates (both lanes of the pair compute redundantly)
    float r_ = __fdividef(1.f, 1.f + __expf(-(gir + sr)));
    float z_ = __fdividef(1.f, 1.f + __expf(-(giz + sz)));
    float e2 = __expf(2.f * (gin + r_ * (sn + bhn)));
    float n_ = 1.f - __fdividef(2.f, e2 + 1.f);
    h_prev = (1.f - z_) * n_ + z_ * h_prev;

    float pp = 0.f;
    if (sub == 0) {
      hh[nxt][g] = (_Float16)h_prev;
      pp = h_prev * pwv;
    }
    pp += __shfl_xor(pp, 1);  pp += __shfl_xor(pp, 2);
    pp += __shfl_xor(pp, 4);  pp += __shfl_xor(pp, 8);
    pp += __shfl_xor(pp, 16); pp += __shfl_xor(pp, 32);
    if (lane == 0) pbuf[cur][wave] = pp;
    if (tid == 8)  pbuf[cur][8] = pbv;

    __syncthreads();   // the ONLY barrier: publishes hh[nxt], pbuf[cur], prefetches
  }

  // epilogue: finish step 198 (parity 0)
  if (tid < 8) {
    float v = pbuf[0][tid];
    v += __shfl_xor(v, 1); v += __shfl_xor(v, 2); v += __shfl_xor(v, 4);
    if (tid == 0)
      out[b * TOUT + 198] = __fdividef(1.f, 1.f + __expf(-(v + pbuf[0][8])));
  }
}

// ---------------------------------------------------------------------------
extern "C" void kernel_launch(void* const* d_in, const int* in_sizes, int n_in,
                              void* d_out, int out_size, void* d_ws, size_t ws_size,
                              hipStream_t stream) {
  const int*   questions = (const int*)d_in[1];
  const int*   answers   = (const int*)d_in[2];
  const float* q_emb     = (const float*)d_in[3];
  const float* a_emb     = (const float*)d_in[4];
  const float* w_ih      = (const float*)d_in[5];
  const float* w_hh      = (const float*)d_in[6];
  const float* b_ih      = (const float*)d_in[7];
  const float* b_hh      = (const float*)d_in[8];
  const float* pred_w    = (const float*)d_in[9];
  const float* pred_b    = (const float*)d_in[10];
  float* out = (float*)d_out;

  const size_t gi_bytes = (size_t)64 * T_SEQ * G3 * 4;     // 39.3 MB
  const size_t xh_bytes = (size_t)64 * T_SEQ * EDIM * 2;   // 6.55 MB
  const size_t wh_bytes = (size_t)G3 * EDIM * 2;           // 0.39 MB
  float* gi = (float*)d_ws;

  if (ws_size >= gi_bytes + xh_bytes + wh_bytes) {
    _Float16* xh    = (_Float16*)((char*)d_ws + gi_bytes);
    _Float16* wih_h = (_Float16*)((char*)d_ws + gi_bytes + xh_bytes);
    xbuild_kernel<<<100, 256, 0, stream>>>(questions, answers, q_emb, a_emb,
                                           w_ih, xh, wih_h);
    gi_gemm_fast_kernel<<<dim3(200, 6), 512, 0, stream>>>(xh, wih_h, b_ih, b_hh, gi);
  } else {
    gi_gemm_kernel<<<dim3(200, 6), 512, 0, stream>>>(
        questions, answers, q_emb, a_emb, w_ih, b_ih, b_hh, gi);
  }

  gru_scan_kernel<<<64, 512, 0, stream>>>(
      questions, w_hh, b_hh, pred_w, pred_b, gi, out);
}

// Round 12
// 444.237 us; speedup vs baseline: 1.7744x; 1.0326x over previous
//
#include <hip/hip_runtime.h>
#include <hip/hip_bf16.h>

#define T_SEQ 200
#define HDIM  256
#define EDIM  256
#define G3    768   // 3*H
#define TOUT  199   // T-1

typedef _Float16 h2_t __attribute__((ext_vector_type(2)));
typedef _Float16 f16x8_t __attribute__((ext_vector_type(8)));
typedef unsigned int u4_t __attribute__((ext_vector_type(4)));
typedef unsigned int u2_t __attribute__((ext_vector_type(2)));
typedef float f4_t __attribute__((ext_vector_type(4)));

static __device__ __forceinline__ float dot2acc(unsigned int w, unsigned int h, float c) {
  return __builtin_amdgcn_fdot2(__builtin_bit_cast(h2_t, w),
                                __builtin_bit_cast(h2_t, h), c, false);
}

static __device__ __forceinline__ unsigned int pk(float x, float y) {
  h2_t p; p[0] = (_Float16)x; p[1] = (_Float16)y;
  return __builtin_bit_cast(unsigned int, p);
}

// 4 floats -> 4 e5m2 bytes (top byte of f16, round-half-up; weights <=0.0625
// so no overflow). Numerics validated rounds 9-11 (absmax identical to fp16).
static __device__ __forceinline__ unsigned int pk_e5m2x4(const float* p) {
  unsigned int r = 0;
#pragma unroll
  for (int j = 0; j < 4; ++j) {
    unsigned short b = __builtin_bit_cast(unsigned short, (_Float16)p[j]);
    r |= ((unsigned int)((unsigned short)(b + 0x80) >> 8)) << (8 * j);
  }
  return r;
}

// e5m2 bytes {b0,b1} of u -> h2 {b0<<8, b1<<8}: single v_perm_b32
static __device__ __forceinline__ unsigned int up_lo(unsigned int u) {
  return __builtin_amdgcn_perm(0u, u, 0x010C000Cu);
}
static __device__ __forceinline__ unsigned int up_hi(unsigned int u) {
  return __builtin_amdgcn_perm(0u, u, 0x030C020Cu);
}

// async global->LDS, 4 bytes per lane; lds base must be wave-uniform
static __device__ __forceinline__ void gload_lds4(const float* g, float* l) {
  __builtin_amdgcn_global_load_lds(
      (const __attribute__((address_space(1))) void*)g,
      (__attribute__((address_space(3))) void*)l, 4, 0, 0);
}

// ---------------------------------------------------------------------------
// xbuild (+wcvt fused): xh[m][e] = (f16)(q_emb[q[m]][e] + a_emb[a[m]][e]);
// also converts w_ih -> fp16.
// ---------------------------------------------------------------------------
__global__ __attribute__((amdgpu_flat_work_group_size(256, 256)))
void xbuild_kernel(const int* __restrict__ questions,
                   const int* __restrict__ answers,
                   const float* __restrict__ q_emb,
                   const float* __restrict__ a_emb,
                   const float* __restrict__ w_ih,
                   _Float16* __restrict__ xh,
                   _Float16* __restrict__ wih_h)
{
  const int tid = threadIdx.x;
  {
    int wi = (blockIdx.x * 256 + tid) * 8;
    if (wi < G3 * EDIM) {
      f4_t a = *(const f4_t*)(w_ih + wi);
      f4_t b = *(const f4_t*)(w_ih + wi + 4);
      f16x8_t o;
      o[0]=(_Float16)a[0]; o[1]=(_Float16)a[1]; o[2]=(_Float16)a[2]; o[3]=(_Float16)a[3];
      o[4]=(_Float16)b[0]; o[5]=(_Float16)b[1]; o[6]=(_Float16)b[2]; o[7]=(_Float16)b[3];
      *(f16x8_t*)(wih_h + wi) = o;
    }
  }
  const int m0 = blockIdx.x * 128;
  for (int i = 0; i < 128; ++i) {
    int m = m0 + i;
    int q = questions[m]; q = q < 0 ? 0 : q;
    int a = answers[m];   a = a < 0 ? 0 : a;
    xh[(size_t)m * EDIM + tid] =
        (_Float16)(q_emb[(size_t)q * EDIM + tid] + a_emb[(size_t)a * EDIM + tid]);
  }
}

// ---------------------------------------------------------------------------
// Kernel A fast (MFMA f16, preconverted operands): gi = xh @ wih_h^T + bias.
// Fragment pattern proven rounds 9-11.
// ---------------------------------------------------------------------------
__global__ __attribute__((amdgpu_flat_work_group_size(512, 512)))
void gi_gemm_fast_kernel(const _Float16* __restrict__ xh,
                         const _Float16* __restrict__ wih_h,
                         const float* __restrict__ b_ih,
                         const float* __restrict__ b_hh,
                         float* __restrict__ gi)
{
  const int lane = threadIdx.x & 63;
  const int wv   = threadIdx.x >> 6;
  const int lr   = lane & 15;
  const int kg   = lane >> 4;
  const int wm   = wv & 3;
  const int wn   = wv >> 2;

  const int m  = blockIdx.x * 64 + wm * 16 + lr;
  const int nb = blockIdx.y * 128 + wn * 64;

  const _Float16* arow = xh + (size_t)m * EDIM + 8 * kg;
  const _Float16* wrow = wih_h + (size_t)(nb + lr) * EDIM + 8 * kg;

  f4_t zero4 = {0.f, 0.f, 0.f, 0.f};
  f4_t acc0 = zero4, acc1 = zero4, acc2 = zero4, acc3 = zero4;

#pragma unroll
  for (int i = 0; i < 8; ++i) {
    f16x8_t af = *(const f16x8_t*)(arow + 32 * i);
#define BTF(nt) { \
    f16x8_t bf = *(const f16x8_t*)(wrow + (size_t)(nt) * 16 * EDIM + 32 * i); \
    acc##nt = __builtin_amdgcn_mfma_f32_16x16x32_f16(af, bf, acc##nt, 0, 0, 0); }
    BTF(0) BTF(1) BTF(2) BTF(3)
  }

  const int mrow0 = blockIdx.x * 64 + wm * 16 + kg * 4;
#define STF(nt) { \
    const int c_ = nb + (nt) * 16 + lr; \
    const float bias_ = b_ih[c_] + (c_ < 2 * HDIM ? b_hh[c_] : 0.f); \
    float* d_ = gi + (size_t)mrow0 * G3 + c_; \
    d_[0]      = acc##nt[0] + bias_; \
    d_[G3]     = acc##nt[1] + bias_; \
    d_[2 * G3] = acc##nt[2] + bias_; \
    d_[3 * G3] = acc##nt[3] + bias_; }
  STF(0) STF(1) STF(2) STF(3)
}

// ---------------------------------------------------------------------------
// Kernel A fallback (round-9 version, proven): gather + cvt inline.
// ---------------------------------------------------------------------------
__global__ __attribute__((amdgpu_flat_work_group_size(512, 512)))
__attribute__((amdgpu_waves_per_eu(2, 2)))
void gi_gemm_kernel(
    const int* __restrict__ questions,
    const int* __restrict__ answers,
    const float* __restrict__ q_emb,
    const float* __restrict__ a_emb,
    const float* __restrict__ w_ih,
    const float* __restrict__ b_ih,
    const float* __restrict__ b_hh,
    float* __restrict__ gi)
{
  const int lane = threadIdx.x & 63;
  const int wv   = threadIdx.x >> 6;
  const int lr   = lane & 15;
  const int kg   = lane >> 4;
  const int wm   = wv & 3;
  const int wn   = wv >> 2;

  const int m  = blockIdx.x * 64 + wm * 16 + lr;
  const int nb = blockIdx.y * 128 + wn * 64;

  int q = questions[m]; q = q < 0 ? 0 : q;
  int a = answers[m];   a = a < 0 ? 0 : a;
  const float* qrow = q_emb + (size_t)q * EDIM + 8 * kg;
  const float* arow = a_emb + (size_t)a * EDIM + 8 * kg;
  const float* wrow = w_ih + (size_t)(nb + lr) * EDIM + 8 * kg;

  f4_t zero4 = {0.f, 0.f, 0.f, 0.f};
  f4_t acc0 = zero4, acc1 = zero4, acc2 = zero4, acc3 = zero4;

#pragma unroll
  for (int i = 0; i < 8; ++i) {
    f4_t q0 = *(const f4_t*)(qrow + 32 * i);
    f4_t q1 = *(const f4_t*)(qrow + 32 * i + 4);
    f4_t a0 = *(const f4_t*)(arow + 32 * i);
    f4_t a1 = *(const f4_t*)(arow + 32 * i + 4);
    f16x8_t af;
    af[0] = (_Float16)(q0[0] + a0[0]); af[1] = (_Float16)(q0[1] + a0[1]);
    af[2] = (_Float16)(q0[2] + a0[2]); af[3] = (_Float16)(q0[3] + a0[3]);
    af[4] = (_Float16)(q1[0] + a1[0]); af[5] = (_Float16)(q1[1] + a1[1]);
    af[6] = (_Float16)(q1[2] + a1[2]); af[7] = (_Float16)(q1[3] + a1[3]);
#define BT(nt) { \
    f4_t b0 = *(const f4_t*)(wrow + (nt) * 16 * EDIM + 32 * i); \
    f4_t b1 = *(const f4_t*)(wrow + (nt) * 16 * EDIM + 32 * i + 4); \
    f16x8_t bf; \
    bf[0] = (_Float16)b0[0]; bf[1] = (_Float16)b0[1]; \
    bf[2] = (_Float16)b0[2]; bf[3] = (_Float16)b0[3]; \
    bf[4] = (_Float16)b1[0]; bf[5] = (_Float16)b1[1]; \
    bf[6] = (_Float16)b1[2]; bf[7] = (_Float16)b1[3]; \
    acc##nt = __builtin_amdgcn_mfma_f32_16x16x32_f16(af, bf, acc##nt, 0, 0, 0); }
    BT(0) BT(1) BT(2) BT(3)
  }

  const int mrow0 = blockIdx.x * 64 + wm * 16 + kg * 4;
#define ST(nt) { \
    const int c_ = nb + (nt) * 16 + lr; \
    const float bias_ = b_ih[c_] + (c_ < 2 * HDIM ? b_hh[c_] : 0.f); \
    float* d_ = gi + (size_t)mrow0 * G3 + c_; \
    d_[0]      = acc##nt[0] + bias_; \
    d_[G3]     = acc##nt[1] + bias_; \
    d_[2 * G3] = acc##nt[2] + bias_; \
    d_[3 * G3] = acc##nt[3] + bias_; }
  ST(0) ST(1) ST(2) ST(3)
}

// ---------------------------------------------------------------------------
// Kernel B: GRU scan, 64 blocks x 512 thr, ONE barrier per step (r10 base).
// Round-12 change: 4-deep register ring for the zE stream (zuA..zuD).
// r11 pipelined only hh and gained ~3% -> the exposed latency was the zE
// read issued and consumed INSIDE each chunk (~80 cyc x 16 chunks). Depth 4
// divides 16, so chunk k always consumes slot k%4 and loads zE[(k+4)&15] --
// the ring phase is stable across steps, and chunks 13..15 legally prefetch
// next step's zE[0..2] (zE is step-invariant; the barrier's lgkmcnt drain
// only waits for them to land, values stay correct).
// ---------------------------------------------------------------------------
__global__ __attribute__((amdgpu_flat_work_group_size(512, 512)))
__attribute__((amdgpu_waves_per_eu(2, 2)))
void gru_scan_kernel(
    const int* __restrict__ questions,
    const float* __restrict__ w_hh,    // [768][256]
    const float* __restrict__ b_hh,    // [768]
    const float* __restrict__ pred_w,  // [Q+1][256]
    const float* __restrict__ pred_b,  // [Q+1]
    const float* __restrict__ gi,      // [B*T][768] (b_ih + b_hh_{r,z} folded)
    float* __restrict__ out)           // [B][199]
{
  const int b    = blockIdx.x;
  const int tid  = threadIdx.x;
  const int lane = tid & 63;
  const int wave = tid >> 6;
  const int g    = tid >> 1;   // hidden unit 0..255
  const int sub  = tid & 1;    // column half

  __shared__ __align__(16) u2_t zE[16][512];        // 64 KB: e5m2 W_z
  __shared__ __align__(16) _Float16 hh[2][HDIM];    // fp16 h double-buffer
  __shared__ float gi_buf[2][G3];
  __shared__ float pw_lds[2][HDIM];
  __shared__ float pbuf[2][16];                     // [0..7] partials, [8] pred_b

  // ---- W_n -> 16 named u4 fp16 (64 VGPRs) ----
  const float* wn_p = w_hh + (size_t)(2 * HDIM + g) * HDIM + 128 * sub;
#define WLOAD(name, p_, r_) u4_t name; { \
    f4_t f0_ = *(const f4_t*)((p_) + 8 * (r_)); \
    f4_t f1_ = *(const f4_t*)((p_) + 8 * (r_) + 4); \
    name[0] = pk(f0_[0], f0_[1]); name[1] = pk(f0_[2], f0_[3]); \
    name[2] = pk(f1_[0], f1_[1]); name[3] = pk(f1_[2], f1_[3]); }
  WLOAD(WN0,wn_p,0)  WLOAD(WN1,wn_p,1)  WLOAD(WN2,wn_p,2)  WLOAD(WN3,wn_p,3)
  WLOAD(WN4,wn_p,4)  WLOAD(WN5,wn_p,5)  WLOAD(WN6,wn_p,6)  WLOAD(WN7,wn_p,7)
  WLOAD(WN8,wn_p,8)  WLOAD(WN9,wn_p,9)  WLOAD(WN10,wn_p,10) WLOAD(WN11,wn_p,11)
  WLOAD(WN12,wn_p,12) WLOAD(WN13,wn_p,13) WLOAD(WN14,wn_p,14) WLOAD(WN15,wn_p,15)

  // ---- W_r -> 16 named u2 e5m2 (32 VGPRs) ----
  const float* wr_p = w_hh + (size_t)g * HDIM + 128 * sub;
#define RLOAD(name, r_) u2_t name; { \
    name[0] = pk_e5m2x4(wr_p + 8 * (r_)); \
    name[1] = pk_e5m2x4(wr_p + 8 * (r_) + 4); }
  RLOAD(RU0,0)  RLOAD(RU1,1)  RLOAD(RU2,2)  RLOAD(RU3,3)
  RLOAD(RU4,4)  RLOAD(RU5,5)  RLOAD(RU6,6)  RLOAD(RU7,7)
  RLOAD(RU8,8)  RLOAD(RU9,9)  RLOAD(RU10,10) RLOAD(RU11,11)
  RLOAD(RU12,12) RLOAD(RU13,13) RLOAD(RU14,14) RLOAD(RU15,15)

  // ---- W_z -> LDS e5m2 ----
  {
    const float* wz_p = w_hh + (size_t)(HDIM + g) * HDIM + 128 * sub;
    for (int k = 0; k < 16; ++k) {
      u2_t v;
      v[0] = pk_e5m2x4(wz_p + 8 * k);
      v[1] = pk_e5m2x4(wz_p + 8 * k + 4);
      zE[k][tid] = v;
    }
  }

  const float bhn = b_hh[2 * HDIM + g];
  float h_prev = 0.f;

  if (tid < 32) { u4_t z_ = {0u,0u,0u,0u}; *(u4_t*)((char*)&hh[0][0] + tid * 16) = z_; }

  const int*   q_b  = questions + b * T_SEQ;
  const float* gi_b = gi + (size_t)b * T_SEQ * G3;

  // prologue: stage gi[0], pw[0]
  if (wave < 6) {
    gload_lds4(gi_b + (2*wave)   * 64 + lane, &gi_buf[0][(2*wave)   * 64]);
    gload_lds4(gi_b + (2*wave+1) * 64 + lane, &gi_buf[0][(2*wave+1) * 64]);
  }
  if (wave == 6) {
    int q0 = q_b[0]; if (q0 < 0) q0 = 0;
    const float* pr = pred_w + (size_t)q0 * HDIM;
#pragma unroll
    for (int kk = 0; kk < 4; ++kk) gload_lds4(pr + 64*kk + lane, &pw_lds[0][64*kk]);
  }
  __syncthreads();

  // 4-deep zE ring (steady-state across steps since 16 % 4 == 0)
  u2_t zuA = zE[0][tid], zuB = zE[1][tid], zuC = zE[2][tid], zuD = zE[3][tid];
  u4_t hvA, hvB;

#define CHUNK(k_, HC_, HN_, ZS_) { \
    if ((k_) < 15) hv##HN_ = *(const u4_t*)(hcur + 16 * ((k_) + 1)); \
    u2_t zc_ = zu##ZS_; \
    zu##ZS_ = zE[((k_) + 4) & 15][tid]; \
    sn = dot2acc(WN##k_[0], hv##HC_[0], sn); sn = dot2acc(WN##k_[1], hv##HC_[1], sn); \
    sn = dot2acc(WN##k_[2], hv##HC_[2], sn); sn = dot2acc(WN##k_[3], hv##HC_[3], sn); \
    sr = dot2acc(up_lo(RU##k_[0]), hv##HC_[0], sr); \
    sr = dot2acc(up_hi(RU##k_[0]), hv##HC_[1], sr); \
    sr = dot2acc(up_lo(RU##k_[1]), hv##HC_[2], sr); \
    sr = dot2acc(up_hi(RU##k_[1]), hv##HC_[3], sr); \
    sz = dot2acc(up_lo(zc_[0]), hv##HC_[0], sz); \
    sz = dot2acc(up_hi(zc_[0]), hv##HC_[1], sz); \
    sz = dot2acc(up_lo(zc_[1]), hv##HC_[2], sz); \
    sz = dot2acc(up_hi(zc_[1]), hv##HC_[3], sz); }

  for (int t = 0; t < TOUT; ++t) {
    const int cur = t & 1, nxt = cur ^ 1;

    // issue chunk-0 h read + gate/pred inputs FIRST (latency hides under
    // the prefetch-address block below)
    const char* hcur = (const char*)&hh[cur][0] + 256 * sub;
    hvA = *(const u4_t*)(hcur);
    float gir = gi_buf[cur][g];
    float giz = gi_buf[cur][HDIM + g];
    float gin = gi_buf[cur][2 * HDIM + g];
    float pwv = pw_lds[cur][g];

    // prefetch step t+1 inputs (async, drains at this step's barrier)
    if (wave < 6) {
      gload_lds4(gi_b + (size_t)(t+1) * G3 + (2*wave)   * 64 + lane,
                 &gi_buf[nxt][(2*wave)   * 64]);
      gload_lds4(gi_b + (size_t)(t+1) * G3 + (2*wave+1) * 64 + lane,
                 &gi_buf[nxt][(2*wave+1) * 64]);
    }
    if (wave == 6) {
      int qn = q_b[t+1]; if (qn < 0) qn = 0;
      const float* pr = pred_w + (size_t)qn * HDIM;
      gload_lds4(pr + lane,       &pw_lds[nxt][0]);
      gload_lds4(pr + 64 + lane,  &pw_lds[nxt][64]);
      gload_lds4(pr + 128 + lane, &pw_lds[nxt][128]);
      gload_lds4(pr + 192 + lane, &pw_lds[nxt][192]);
    }
    float pbv = 0.f;
    if (tid == 8) { int qt = q_b[t]; if (qt < 0) qt = 0; pbv = pred_b[qt]; }

    // software-pipelined matvec: hh 2-deep, zE 4-deep ring
    float sr = 0.f, sz = 0.f, sn = 0.f;
    CHUNK(0,A,B,A)  CHUNK(1,B,A,B)  CHUNK(2,A,B,C)  CHUNK(3,B,A,D)
    CHUNK(4,A,B,A)  CHUNK(5,B,A,B)  CHUNK(6,A,B,C)  CHUNK(7,B,A,D)
    CHUNK(8,A,B,A)  CHUNK(9,B,A,B)  CHUNK(10,A,B,C) CHUNK(11,B,A,D)
    CHUNK(12,A,B,A) CHUNK(13,B,A,B) CHUNK(14,A,B,C) CHUNK(15,B,A,D)
    sr += __shfl_xor(sr, 1); sz += __shfl_xor(sz, 1); sn += __shfl_xor(sn, 1);

    // finisher for step t-1 (partials published by last barrier)
    if (t > 0 && tid < 8) {
      float v = pbuf[nxt][tid];
      v += __shfl_xor(v, 1); v += __shfl_xor(v, 2); v += __shfl_xor(v, 4);
      if (tid == 0)
        out[b * TOUT + t - 1] = __fdividef(1.f, 1.f + __expf(-(v + pbuf[nxt][8])));
    }

    // gates (both lanes of the pair compute redundantly)
    float r_ = __fdividef(1.f, 1.f + __expf(-(gir + sr)));
    float z_ = __fdividef(1.f, 1.f + __expf(-(giz + sz)));
    float e2 = __expf(2.f * (gin + r_ * (sn + bhn)));
    float n_ = 1.f - __fdividef(2.f, e2 + 1.f);
    h_prev = (1.f - z_) * n_ + z_ * h_prev;

    float pp = 0.f;
    if (sub == 0) {
      hh[nxt][g] = (_Float16)h_prev;
      pp = h_prev * pwv;
    }
    pp += __shfl_xor(pp, 1);  pp += __shfl_xor(pp, 2);
    pp += __shfl_xor(pp, 4);  pp += __shfl_xor(pp, 8);
    pp += __shfl_xor(pp, 16); pp += __shfl_xor(pp, 32);
    if (lane == 0) pbuf[cur][wave] = pp;
    if (tid == 8)  pbuf[cur][8] = pbv;

    __syncthreads();   // the ONLY barrier: publishes hh[nxt], pbuf[cur], prefetches
  }

  // epilogue: finish step 198 (parity 0)
  if (tid < 8) {
    float v = pbuf[0][tid];
    v += __shfl_xor(v, 1); v += __shfl_xor(v, 2); v += __shfl_xor(v, 4);
    if (tid == 0)
      out[b * TOUT + 198] = __fdividef(1.f, 1.f + __expf(-(v + pbuf[0][8])));
  }
}

// ---------------------------------------------------------------------------
extern "C" void kernel_launch(void* const* d_in, const int* in_sizes, int n_in,
                              void* d_out, int out_size, void* d_ws, size_t ws_size,
                              hipStream_t stream) {
  const int*   questions = (const int*)d_in[1];
  const int*   answers   = (const int*)d_in[2];
  const float* q_emb     = (const float*)d_in[3];
  const float* a_emb     = (const float*)d_in[4];
  const float* w_ih      = (const float*)d_in[5];
  const float* w_hh      = (const float*)d_in[6];
  const float* b_ih      = (const float*)d_in[7];
  const float* b_hh      = (const float*)d_in[8];
  const float* pred_w    = (const float*)d_in[9];
  const float* pred_b    = (const float*)d_in[10];
  float* out = (float*)d_out;

  const size_t gi_bytes = (size_t)64 * T_SEQ * G3 * 4;     // 39.3 MB
  const size_t xh_bytes = (size_t)64 * T_SEQ * EDIM * 2;   // 6.55 MB
  const size_t wh_bytes = (size_t)G3 * EDIM * 2;           // 0.39 MB
  float* gi = (float*)d_ws;

  if (ws_size >= gi_bytes + xh_bytes + wh_bytes) {
    _Float16* xh    = (_Float16*)((char*)d_ws + gi_bytes);
    _Float16* wih_h = (_Float16*)((char*)d_ws + gi_bytes + xh_bytes);
    xbuild_kernel<<<100, 256, 0, stream>>>(questions, answers, q_emb, a_emb,
                                           w_ih, xh, wih_h);
    gi_gemm_fast_kernel<<<dim3(200, 6), 512, 0, stream>>>(xh, wih_h, b_ih, b_hh, gi);
  } else {
    gi_gemm_kernel<<<dim3(200, 6), 512, 0, stream>>>(
        questions, answers, q_emb, a_emb, w_ih, b_ih, b_hh, gi);
  }

  gru_scan_kernel<<<64, 512, 0, stream>>>(
      questions, w_hh, b_hh, pred_w, pred_b, gi, out);
}

// Round 13
// 412.288 us; speedup vs baseline: 1.9119x; 1.0775x over previous
//
#include <hip/hip_runtime.h>
#include <hip/hip_bf16.h>

#define T_SEQ 200
#define HDIM  256
#define EDIM  256
#define G3    768   // 3*H
#define TOUT  199   // T-1

typedef _Float16 h2_t __attribute__((ext_vector_type(2)));
typedef _Float16 f16x8_t __attribute__((ext_vector_type(8)));
typedef unsigned int u4_t __attribute__((ext_vector_type(4)));
typedef unsigned int u2_t __attribute__((ext_vector_type(2)));
typedef float f4_t __attribute__((ext_vector_type(4)));

static __device__ __forceinline__ float dot2acc(unsigned int w, unsigned int h, float c) {
  return __builtin_amdgcn_fdot2(__builtin_bit_cast(h2_t, w),
                                __builtin_bit_cast(h2_t, h), c, false);
}

static __device__ __forceinline__ unsigned int pk(float x, float y) {
  h2_t p; p[0] = (_Float16)x; p[1] = (_Float16)y;
  return __builtin_bit_cast(unsigned int, p);
}

// 4 floats -> 4 e5m2 bytes (top byte of f16, round-half-up; weights <=0.0625
// so no overflow). Numerics validated rounds 9-12 (absmax identical to fp16).
static __device__ __forceinline__ unsigned int pk_e5m2x4(const float* p) {
  unsigned int r = 0;
#pragma unroll
  for (int j = 0; j < 4; ++j) {
    unsigned short b = __builtin_bit_cast(unsigned short, (_Float16)p[j]);
    r |= ((unsigned int)((unsigned short)(b + 0x80) >> 8)) << (8 * j);
  }
  return r;
}

// e5m2 bytes {b0,b1} of u -> h2 {b0<<8, b1<<8}: single v_perm_b32
static __device__ __forceinline__ unsigned int up_lo(unsigned int u) {
  return __builtin_amdgcn_perm(0u, u, 0x010C000Cu);
}
static __device__ __forceinline__ unsigned int up_hi(unsigned int u) {
  return __builtin_amdgcn_perm(0u, u, 0x030C020Cu);
}

// async global->LDS, 4 bytes per lane; lds base must be wave-uniform
static __device__ __forceinline__ void gload_lds4(const float* g, float* l) {
  __builtin_amdgcn_global_load_lds(
      (const __attribute__((address_space(1))) void*)g,
      (__attribute__((address_space(3))) void*)l, 4, 0, 0);
}

// ---------------------------------------------------------------------------
// xbuild (+wcvt fused): xh[m][e] = (f16)(q_emb[q[m]][e] + a_emb[a[m]][e]);
// also converts w_ih -> fp16.
// ---------------------------------------------------------------------------
__global__ __attribute__((amdgpu_flat_work_group_size(256, 256)))
void xbuild_kernel(const int* __restrict__ questions,
                   const int* __restrict__ answers,
                   const float* __restrict__ q_emb,
                   const float* __restrict__ a_emb,
                   const float* __restrict__ w_ih,
                   _Float16* __restrict__ xh,
                   _Float16* __restrict__ wih_h)
{
  const int tid = threadIdx.x;
  {
    int wi = (blockIdx.x * 256 + tid) * 8;
    if (wi < G3 * EDIM) {
      f4_t a = *(const f4_t*)(w_ih + wi);
      f4_t b = *(const f4_t*)(w_ih + wi + 4);
      f16x8_t o;
      o[0]=(_Float16)a[0]; o[1]=(_Float16)a[1]; o[2]=(_Float16)a[2]; o[3]=(_Float16)a[3];
      o[4]=(_Float16)b[0]; o[5]=(_Float16)b[1]; o[6]=(_Float16)b[2]; o[7]=(_Float16)b[3];
      *(f16x8_t*)(wih_h + wi) = o;
    }
  }
  const int m0 = blockIdx.x * 128;
  for (int i = 0; i < 128; ++i) {
    int m = m0 + i;
    int q = questions[m]; q = q < 0 ? 0 : q;
    int a = answers[m];   a = a < 0 ? 0 : a;
    xh[(size_t)m * EDIM + tid] =
        (_Float16)(q_emb[(size_t)q * EDIM + tid] + a_emb[(size_t)a * EDIM + tid]);
  }
}

// ---------------------------------------------------------------------------
// Kernel A fast (MFMA f16, preconverted operands): gi = xh @ wih_h^T + bias.
// Fragment pattern proven rounds 9-12.
// ---------------------------------------------------------------------------
__global__ __attribute__((amdgpu_flat_work_group_size(512, 512)))
void gi_gemm_fast_kernel(const _Float16* __restrict__ xh,
                         const _Float16* __restrict__ wih_h,
                         const float* __restrict__ b_ih,
                         const float* __restrict__ b_hh,
                         float* __restrict__ gi)
{
  const int lane = threadIdx.x & 63;
  const int wv   = threadIdx.x >> 6;
  const int lr   = lane & 15;
  const int kg   = lane >> 4;
  const int wm   = wv & 3;
  const int wn   = wv >> 2;

  const int m  = blockIdx.x * 64 + wm * 16 + lr;
  const int nb = blockIdx.y * 128 + wn * 64;

  const _Float16* arow = xh + (size_t)m * EDIM + 8 * kg;
  const _Float16* wrow = wih_h + (size_t)(nb + lr) * EDIM + 8 * kg;

  f4_t zero4 = {0.f, 0.f, 0.f, 0.f};
  f4_t acc0 = zero4, acc1 = zero4, acc2 = zero4, acc3 = zero4;

#pragma unroll
  for (int i = 0; i < 8; ++i) {
    f16x8_t af = *(const f16x8_t*)(arow + 32 * i);
#define BTF(nt) { \
    f16x8_t bf = *(const f16x8_t*)(wrow + (size_t)(nt) * 16 * EDIM + 32 * i); \
    acc##nt = __builtin_amdgcn_mfma_f32_16x16x32_f16(af, bf, acc##nt, 0, 0, 0); }
    BTF(0) BTF(1) BTF(2) BTF(3)
  }

  const int mrow0 = blockIdx.x * 64 + wm * 16 + kg * 4;
#define STF(nt) { \
    const int c_ = nb + (nt) * 16 + lr; \
    const float bias_ = b_ih[c_] + (c_ < 2 * HDIM ? b_hh[c_] : 0.f); \
    float* d_ = gi + (size_t)mrow0 * G3 + c_; \
    d_[0]      = acc##nt[0] + bias_; \
    d_[G3]     = acc##nt[1] + bias_; \
    d_[2 * G3] = acc##nt[2] + bias_; \
    d_[3 * G3] = acc##nt[3] + bias_; }
  STF(0) STF(1) STF(2) STF(3)
}

// ---------------------------------------------------------------------------
// Kernel A fallback (round-9 version, proven): gather + cvt inline.
// ---------------------------------------------------------------------------
__global__ __attribute__((amdgpu_flat_work_group_size(512, 512)))
__attribute__((amdgpu_waves_per_eu(2, 2)))
void gi_gemm_kernel(
    const int* __restrict__ questions,
    const int* __restrict__ answers,
    const float* __restrict__ q_emb,
    const float* __restrict__ a_emb,
    const float* __restrict__ w_ih,
    const float* __restrict__ b_ih,
    const float* __restrict__ b_hh,
    float* __restrict__ gi)
{
  const int lane = threadIdx.x & 63;
  const int wv   = threadIdx.x >> 6;
  const int lr   = lane & 15;
  const int kg   = lane >> 4;
  const int wm   = wv & 3;
  const int wn   = wv >> 2;

  const int m  = blockIdx.x * 64 + wm * 16 + lr;
  const int nb = blockIdx.y * 128 + wn * 64;

  int q = questions[m]; q = q < 0 ? 0 : q;
  int a = answers[m];   a = a < 0 ? 0 : a;
  const float* qrow = q_emb + (size_t)q * EDIM + 8 * kg;
  const float* arow = a_emb + (size_t)a * EDIM + 8 * kg;
  const float* wrow = w_ih + (size_t)(nb + lr) * EDIM + 8 * kg;

  f4_t zero4 = {0.f, 0.f, 0.f, 0.f};
  f4_t acc0 = zero4, acc1 = zero4, acc2 = zero4, acc3 = zero4;

#pragma unroll
  for (int i = 0; i < 8; ++i) {
    f4_t q0 = *(const f4_t*)(qrow + 32 * i);
    f4_t q1 = *(const f4_t*)(qrow + 32 * i + 4);
    f4_t a0 = *(const f4_t*)(arow + 32 * i);
    f4_t a1 = *(const f4_t*)(arow + 32 * i + 4);
    f16x8_t af;
    af[0] = (_Float16)(q0[0] + a0[0]); af[1] = (_Float16)(q0[1] + a0[1]);
    af[2] = (_Float16)(q0[2] + a0[2]); af[3] = (_Float16)(q0[3] + a0[3]);
    af[4] = (_Float16)(q1[0] + a1[0]); af[5] = (_Float16)(q1[1] + a1[1]);
    af[6] = (_Float16)(q1[2] + a1[2]); af[7] = (_Float16)(q1[3] + a1[3]);
#define BT(nt) { \
    f4_t b0 = *(const f4_t*)(wrow + (nt) * 16 * EDIM + 32 * i); \
    f4_t b1 = *(const f4_t*)(wrow + (nt) * 16 * EDIM + 32 * i + 4); \
    f16x8_t bf; \
    bf[0] = (_Float16)b0[0]; bf[1] = (_Float16)b0[1]; \
    bf[2] = (_Float16)b0[2]; bf[3] = (_Float16)b0[3]; \
    bf[4] = (_Float16)b1[0]; bf[5] = (_Float16)b1[1]; \
    bf[6] = (_Float16)b1[2]; bf[7] = (_Float16)b1[3]; \
    acc##nt = __builtin_amdgcn_mfma_f32_16x16x32_f16(af, bf, acc##nt, 0, 0, 0); }
    BT(0) BT(1) BT(2) BT(3)
  }

  const int mrow0 = blockIdx.x * 64 + wm * 16 + kg * 4;
#define ST(nt) { \
    const int c_ = nb + (nt) * 16 + lr; \
    const float bias_ = b_ih[c_] + (c_ < 2 * HDIM ? b_hh[c_] : 0.f); \
    float* d_ = gi + (size_t)mrow0 * G3 + c_; \
    d_[0]      = acc##nt[0] + bias_; \
    d_[G3]     = acc##nt[1] + bias_; \
    d_[2 * G3] = acc##nt[2] + bias_; \
    d_[3 * G3] = acc##nt[3] + bias_; }
  ST(0) ST(1) ST(2) ST(3)
}

// ---------------------------------------------------------------------------
// Kernel B: GRU scan, 64 blocks x 512 thr, ONE barrier per step.
// Round-13: DS-pipe diet (step was ~43 DS wave-instrs/thread):
//  (1) zE repacked as u4[8][512]: 8 ds_read_b128 instead of 16 ds_read_b64
//      (same bytes, half the DS instructions). 2-deep copy-reload ring,
//      phase-stable across steps (8 pairs, reload (j+2)&7).
//  (2) pred partial: drop the 6-shfl reduce on ALL waves; sub==0 writes
//      h*pw to ppbuf[cur][g] (1 ds_write); next step's finisher (wave 0)
//      reads 4 floats/lane (1 b128) + 6 shfl. Saves ~13 DS + ~12 VALU per
//      thread-step.
// ---------------------------------------------------------------------------
__global__ __attribute__((amdgpu_flat_work_group_size(512, 512)))
__attribute__((amdgpu_waves_per_eu(2, 2)))
void gru_scan_kernel(
    const int* __restrict__ questions,
    const float* __restrict__ w_hh,    // [768][256]
    const float* __restrict__ b_hh,    // [768]
    const float* __restrict__ pred_w,  // [Q+1][256]
    const float* __restrict__ pred_b,  // [Q+1]
    const float* __restrict__ gi,      // [B*T][768] (b_ih + b_hh_{r,z} folded)
    float* __restrict__ out)           // [B][199]
{
  const int b    = blockIdx.x;
  const int tid  = threadIdx.x;
  const int lane = tid & 63;
  const int wave = tid >> 6;
  const int g    = tid >> 1;   // hidden unit 0..255
  const int sub  = tid & 1;    // column half

  __shared__ __align__(16) u4_t zE4[8][512];        // 64 KB: e5m2 W_z (u4 rows)
  __shared__ __align__(16) _Float16 hh[2][HDIM];    // fp16 h double-buffer
  __shared__ __align__(16) float ppbuf[2][HDIM];    // per-unit pred products
  __shared__ float gi_buf[2][G3];
  __shared__ float pw_lds[2][HDIM];
  __shared__ float pb2[2];                          // pred_b, per parity

  // ---- W_n -> 16 named u4 fp16 (64 VGPRs) ----
  const float* wn_p = w_hh + (size_t)(2 * HDIM + g) * HDIM + 128 * sub;
#define WLOAD(name, p_, r_) u4_t name; { \
    f4_t f0_ = *(const f4_t*)((p_) + 8 * (r_)); \
    f4_t f1_ = *(const f4_t*)((p_) + 8 * (r_) + 4); \
    name[0] = pk(f0_[0], f0_[1]); name[1] = pk(f0_[2], f0_[3]); \
    name[2] = pk(f1_[0], f1_[1]); name[3] = pk(f1_[2], f1_[3]); }
  WLOAD(WN0,wn_p,0)  WLOAD(WN1,wn_p,1)  WLOAD(WN2,wn_p,2)  WLOAD(WN3,wn_p,3)
  WLOAD(WN4,wn_p,4)  WLOAD(WN5,wn_p,5)  WLOAD(WN6,wn_p,6)  WLOAD(WN7,wn_p,7)
  WLOAD(WN8,wn_p,8)  WLOAD(WN9,wn_p,9)  WLOAD(WN10,wn_p,10) WLOAD(WN11,wn_p,11)
  WLOAD(WN12,wn_p,12) WLOAD(WN13,wn_p,13) WLOAD(WN14,wn_p,14) WLOAD(WN15,wn_p,15)

  // ---- W_r -> 16 named u2 e5m2 (32 VGPRs) ----
  const float* wr_p = w_hh + (size_t)g * HDIM + 128 * sub;
#define RLOAD(name, r_) u2_t name; { \
    name[0] = pk_e5m2x4(wr_p + 8 * (r_)); \
    name[1] = pk_e5m2x4(wr_p + 8 * (r_) + 4); }
  RLOAD(RU0,0)  RLOAD(RU1,1)  RLOAD(RU2,2)  RLOAD(RU3,3)
  RLOAD(RU4,4)  RLOAD(RU5,5)  RLOAD(RU6,6)  RLOAD(RU7,7)
  RLOAD(RU8,8)  RLOAD(RU9,9)  RLOAD(RU10,10) RLOAD(RU11,11)
  RLOAD(RU12,12) RLOAD(RU13,13) RLOAD(RU14,14) RLOAD(RU15,15)

  // ---- W_z -> LDS e5m2, u4 rows (j covers chunks 2j, 2j+1) ----
  {
    const float* wz_p = w_hh + (size_t)(HDIM + g) * HDIM + 128 * sub;
    for (int j = 0; j < 8; ++j) {
      u4_t v;
      v[0] = pk_e5m2x4(wz_p + 16 * j);
      v[1] = pk_e5m2x4(wz_p + 16 * j + 4);
      v[2] = pk_e5m2x4(wz_p + 16 * j + 8);
      v[3] = pk_e5m2x4(wz_p + 16 * j + 12);
      zE4[j][tid] = v;
    }
  }

  const float bhn = b_hh[2 * HDIM + g];
  float h_prev = 0.f;

  if (tid < 32) { u4_t z_ = {0u,0u,0u,0u}; *(u4_t*)((char*)&hh[0][0] + tid * 16) = z_; }

  const int*   q_b  = questions + b * T_SEQ;
  const float* gi_b = gi + (size_t)b * T_SEQ * G3;

  // prologue: stage gi[0], pw[0]
  if (wave < 6) {
    gload_lds4(gi_b + (2*wave)   * 64 + lane, &gi_buf[0][(2*wave)   * 64]);
    gload_lds4(gi_b + (2*wave+1) * 64 + lane, &gi_buf[0][(2*wave+1) * 64]);
  }
  if (wave == 6) {
    int q0 = q_b[0]; if (q0 < 0) q0 = 0;
    const float* pr = pred_w + (size_t)q0 * HDIM;
#pragma unroll
    for (int kk = 0; kk < 4; ++kk) gload_lds4(pr + 64*kk + lane, &pw_lds[0][64*kk]);
  }
  __syncthreads();

  // 2-deep zE4 ring: stable phase across steps (after 8 pairs zA=E0, zB=E1)
  u4_t zA = zE4[0][tid], zB = zE4[1][tid];
  u4_t hvA, hvB;

#define CHUNK(k_, HC_, HN_, ZLO_, ZHI_) { \
    if ((k_) < 15) hv##HN_ = *(const u4_t*)(hcur + 16 * ((k_) + 1)); \
    sn = dot2acc(WN##k_[0], hv##HC_[0], sn); sn = dot2acc(WN##k_[1], hv##HC_[1], sn); \
    sn = dot2acc(WN##k_[2], hv##HC_[2], sn); sn = dot2acc(WN##k_[3], hv##HC_[3], sn); \
    sr = dot2acc(up_lo(RU##k_[0]), hv##HC_[0], sr); \
    sr = dot2acc(up_hi(RU##k_[0]), hv##HC_[1], sr); \
    sr = dot2acc(up_lo(RU##k_[1]), hv##HC_[2], sr); \
    sr = dot2acc(up_hi(RU##k_[1]), hv##HC_[3], sr); \
    sz = dot2acc(up_lo(ZLO_), hv##HC_[0], sz); \
    sz = dot2acc(up_hi(ZLO_), hv##HC_[1], sz); \
    sz = dot2acc(up_lo(ZHI_), hv##HC_[2], sz); \
    sz = dot2acc(up_hi(ZHI_), hv##HC_[3], sz); }

#define PAIR(j_, k0_, k1_, HC0_, HN0_, HC1_, HN1_, ZS_) { \
    u4_t zc_ = z##ZS_; \
    z##ZS_ = zE4[((j_) + 2) & 7][tid]; \
    CHUNK(k0_, HC0_, HN0_, zc_[0], zc_[1]) \
    CHUNK(k1_, HC1_, HN1_, zc_[2], zc_[3]) }

  for (int t = 0; t < TOUT; ++t) {
    const int cur = t & 1, nxt = cur ^ 1;

    // issue chunk-0 h read + gate/pred inputs FIRST
    const char* hcur = (const char*)&hh[cur][0] + 256 * sub;
    hvA = *(const u4_t*)(hcur);
    float gir = gi_buf[cur][g];
    float giz = gi_buf[cur][HDIM + g];
    float gin = gi_buf[cur][2 * HDIM + g];
    float pwv = pw_lds[cur][g];

    // prefetch step t+1 inputs (async, drains at this step's barrier)
    if (wave < 6) {
      gload_lds4(gi_b + (size_t)(t+1) * G3 + (2*wave)   * 64 + lane,
                 &gi_buf[nxt][(2*wave)   * 64]);
      gload_lds4(gi_b + (size_t)(t+1) * G3 + (2*wave+1) * 64 + lane,
                 &gi_buf[nxt][(2*wave+1) * 64]);
    }
    if (wave == 6) {
      int qn = q_b[t+1]; if (qn < 0) qn = 0;
      const float* pr = pred_w + (size_t)qn * HDIM;
      gload_lds4(pr + lane,       &pw_lds[nxt][0]);
      gload_lds4(pr + 64 + lane,  &pw_lds[nxt][64]);
      gload_lds4(pr + 128 + lane, &pw_lds[nxt][128]);
      gload_lds4(pr + 192 + lane, &pw_lds[nxt][192]);
    }
    float pbv = 0.f;
    if (tid == 8) { int qt = q_b[t]; if (qt < 0) qt = 0; pbv = pred_b[qt]; }

    // software-pipelined matvec: hh 2-deep, zE4 2-deep pair ring
    float sr = 0.f, sz = 0.f, sn = 0.f;
    PAIR(0, 0, 1, A,B, B,A, A)
    PAIR(1, 2, 3, A,B, B,A, B)
    PAIR(2, 4, 5, A,B, B,A, A)
    PAIR(3, 6, 7, A,B, B,A, B)
    PAIR(4, 8, 9, A,B, B,A, A)
    PAIR(5, 10,11, A,B, B,A, B)
    PAIR(6, 12,13, A,B, B,A, A)
    PAIR(7, 14,15, A,B, B,A, B)
    sr += __shfl_xor(sr, 1); sz += __shfl_xor(sz, 1); sn += __shfl_xor(sn, 1);

    // finisher for step t-1 (ppbuf published by last barrier), wave 0 only
    if (t > 0 && tid < 64) {
      f4_t pv = *(const f4_t*)&ppbuf[nxt][lane << 2];
      float v = (pv[0] + pv[1]) + (pv[2] + pv[3]);
      v += __shfl_xor(v, 1);  v += __shfl_xor(v, 2);
      v += __shfl_xor(v, 4);  v += __shfl_xor(v, 8);
      v += __shfl_xor(v, 16); v += __shfl_xor(v, 32);
      if (tid == 0)
        out[b * TOUT + t - 1] = __fdividef(1.f, 1.f + __expf(-(v + pb2[nxt])));
    }

    // gates (both lanes of the pair compute redundantly)
    float r_ = __fdividef(1.f, 1.f + __expf(-(gir + sr)));
    float z_ = __fdividef(1.f, 1.f + __expf(-(giz + sz)));
    float e2 = __expf(2.f * (gin + r_ * (sn + bhn)));
    float n_ = 1.f - __fdividef(2.f, e2 + 1.f);
    h_prev = (1.f - z_) * n_ + z_ * h_prev;

    if (sub == 0) {
      hh[nxt][g] = (_Float16)h_prev;
      ppbuf[cur][g] = h_prev * pwv;     // pred product; reduced next step
    }
    if (tid == 8) pb2[cur] = pbv;

    __syncthreads();   // the ONLY barrier: publishes hh[nxt], ppbuf, prefetches
  }

  // epilogue: finish step 198 (parity 0)
  if (tid < 64) {
    f4_t pv = *(const f4_t*)&ppbuf[0][lane << 2];
    float v = (pv[0] + pv[1]) + (pv[2] + pv[3]);
    v += __shfl_xor(v, 1);  v += __shfl_xor(v, 2);
    v += __shfl_xor(v, 4);  v += __shfl_xor(v, 8);
    v += __shfl_xor(v, 16); v += __shfl_xor(v, 32);
    if (tid == 0)
      out[b * TOUT + 198] = __fdividef(1.f, 1.f + __expf(-(v + pb2[0])));
  }
}

// ---------------------------------------------------------------------------
extern "C" void kernel_launch(void* const* d_in, const int* in_sizes, int n_in,
                              void* d_out, int out_size, void* d_ws, size_t ws_size,
                              hipStream_t stream) {
  const int*   questions = (const int*)d_in[1];
  const int*   answers   = (const int*)d_in[2];
  const float* q_emb     = (const float*)d_in[3];
  const float* a_emb     = (const float*)d_in[4];
  const float* w_ih      = (const float*)d_in[5];
  const float* w_hh      = (const float*)d_in[6];
  const float* b_ih      = (const float*)d_in[7];
  const float* b_hh      = (const float*)d_in[8];
  const float* pred_w    = (const float*)d_in[9];
  const float* pred_b    = (const float*)d_in[10];
  float* out = (float*)d_out;

  const size_t gi_bytes = (size_t)64 * T_SEQ * G3 * 4;     // 39.3 MB
  const size_t xh_bytes = (size_t)64 * T_SEQ * EDIM * 2;   // 6.55 MB
  const size_t wh_bytes = (size_t)G3 * EDIM * 2;           // 0.39 MB
  float* gi = (float*)d_ws;

  if (ws_size >= gi_bytes + xh_bytes + wh_bytes) {
    _Float16* xh    = (_Float16*)((char*)d_ws + gi_bytes);
    _Float16* wih_h = (_Float16*)((char*)d_ws + gi_bytes + xh_bytes);
    xbuild_kernel<<<100, 256, 0, stream>>>(questions, answers, q_emb, a_emb,
                                           w_ih, xh, wih_h);
    gi_gemm_fast_kernel<<<dim3(200, 6), 512, 0, stream>>>(xh, wih_h, b_ih, b_hh, gi);
  } else {
    gi_gemm_kernel<<<dim3(200, 6), 512, 0, stream>>>(
        questions, answers, q_emb, a_emb, w_ih, b_ih, b_hh, gi);
  }

  gru_scan_kernel<<<64, 512, 0, stream>>>(
      questions, w_hh, b_hh, pred_w, pred_b, gi, out);
}

// Round 14
// 393.552 us; speedup vs baseline: 2.0029x; 1.0476x over previous
//
#include <hip/hip_runtime.h>
#include <hip/hip_bf16.h>

#define T_SEQ 200
#define HDIM  256
#define EDIM  256
#define G3    768   // 3*H
#define TOUT  199   // T-1

typedef _Float16 h2_t __attribute__((ext_vector_type(2)));
typedef _Float16 f16x8_t __attribute__((ext_vector_type(8)));
typedef unsigned int u4_t __attribute__((ext_vector_type(4)));
typedef unsigned int u2_t __attribute__((ext_vector_type(2)));
typedef float f4_t __attribute__((ext_vector_type(4)));

static __device__ __forceinline__ float dot2acc(unsigned int w, unsigned int h, float c) {
  return __builtin_amdgcn_fdot2(__builtin_bit_cast(h2_t, w),
                                __builtin_bit_cast(h2_t, h), c, false);
}

static __device__ __forceinline__ unsigned int pk(float x, float y) {
  h2_t p; p[0] = (_Float16)x; p[1] = (_Float16)y;
  return __builtin_bit_cast(unsigned int, p);
}

// 4 floats -> 4 e5m2 bytes (top byte of f16, round-half-up; weights <=0.0625
// so no overflow). Numerics validated rounds 9-13.
static __device__ __forceinline__ unsigned int pk_e5m2x4(const float* p) {
  unsigned int r = 0;
#pragma unroll
  for (int j = 0; j < 4; ++j) {
    unsigned short b = __builtin_bit_cast(unsigned short, (_Float16)p[j]);
    r |= ((unsigned int)((unsigned short)(b + 0x80) >> 8)) << (8 * j);
  }
  return r;
}

// e5m2 bytes {b0,b1} of u -> h2 {b0<<8, b1<<8}: single v_perm_b32
static __device__ __forceinline__ unsigned int up_lo(unsigned int u) {
  return __builtin_amdgcn_perm(0u, u, 0x010C000Cu);
}
static __device__ __forceinline__ unsigned int up_hi(unsigned int u) {
  return __builtin_amdgcn_perm(0u, u, 0x030C020Cu);
}

// async global->LDS, 4 bytes per lane; lds base must be wave-uniform
static __device__ __forceinline__ void gload_lds4(const float* g, float* l) {
  __builtin_amdgcn_global_load_lds(
      (const __attribute__((address_space(1))) void*)g,
      (__attribute__((address_space(3))) void*)l, 4, 0, 0);
}

// ---------------------------------------------------------------------------
// xbuild (+wcvt fused): xh[m][e] = (f16)(q_emb[q[m]][e] + a_emb[a[m]][e]);
// also converts w_ih -> fp16.
// ---------------------------------------------------------------------------
__global__ __attribute__((amdgpu_flat_work_group_size(256, 256)))
void xbuild_kernel(const int* __restrict__ questions,
                   const int* __restrict__ answers,
                   const float* __restrict__ q_emb,
                   const float* __restrict__ a_emb,
                   const float* __restrict__ w_ih,
                   _Float16* __restrict__ xh,
                   _Float16* __restrict__ wih_h)
{
  const int tid = threadIdx.x;
  {
    int wi = (blockIdx.x * 256 + tid) * 8;
    if (wi < G3 * EDIM) {
      f4_t a = *(const f4_t*)(w_ih + wi);
      f4_t b = *(const f4_t*)(w_ih + wi + 4);
      f16x8_t o;
      o[0]=(_Float16)a[0]; o[1]=(_Float16)a[1]; o[2]=(_Float16)a[2]; o[3]=(_Float16)a[3];
      o[4]=(_Float16)b[0]; o[5]=(_Float16)b[1]; o[6]=(_Float16)b[2]; o[7]=(_Float16)b[3];
      *(f16x8_t*)(wih_h + wi) = o;
    }
  }
  const int m0 = blockIdx.x * 128;
  for (int i = 0; i < 128; ++i) {
    int m = m0 + i;
    int q = questions[m]; q = q < 0 ? 0 : q;
    int a = answers[m];   a = a < 0 ? 0 : a;
    xh[(size_t)m * EDIM + tid] =
        (_Float16)(q_emb[(size_t)q * EDIM + tid] + a_emb[(size_t)a * EDIM + tid]);
  }
}

// ---------------------------------------------------------------------------
// Kernel A fast (MFMA f16, preconverted operands): gi = xh @ wih_h^T + bias.
// Fragment pattern proven rounds 9-13.
// ---------------------------------------------------------------------------
__global__ __attribute__((amdgpu_flat_work_group_size(512, 512)))
void gi_gemm_fast_kernel(const _Float16* __restrict__ xh,
                         const _Float16* __restrict__ wih_h,
                         const float* __restrict__ b_ih,
                         const float* __restrict__ b_hh,
                         float* __restrict__ gi)
{
  const int lane = threadIdx.x & 63;
  const int wv   = threadIdx.x >> 6;
  const int lr   = lane & 15;
  const int kg   = lane >> 4;
  const int wm   = wv & 3;
  const int wn   = wv >> 2;

  const int m  = blockIdx.x * 64 + wm * 16 + lr;
  const int nb = blockIdx.y * 128 + wn * 64;

  const _Float16* arow = xh + (size_t)m * EDIM + 8 * kg;
  const _Float16* wrow = wih_h + (size_t)(nb + lr) * EDIM + 8 * kg;

  f4_t zero4 = {0.f, 0.f, 0.f, 0.f};
  f4_t acc0 = zero4, acc1 = zero4, acc2 = zero4, acc3 = zero4;

#pragma unroll
  for (int i = 0; i < 8; ++i) {
    f16x8_t af = *(const f16x8_t*)(arow + 32 * i);
#define BTF(nt) { \
    f16x8_t bf = *(const f16x8_t*)(wrow + (size_t)(nt) * 16 * EDIM + 32 * i); \
    acc##nt = __builtin_amdgcn_mfma_f32_16x16x32_f16(af, bf, acc##nt, 0, 0, 0); }
    BTF(0) BTF(1) BTF(2) BTF(3)
  }

  const int mrow0 = blockIdx.x * 64 + wm * 16 + kg * 4;
#define STF(nt) { \
    const int c_ = nb + (nt) * 16 + lr; \
    const float bias_ = b_ih[c_] + (c_ < 2 * HDIM ? b_hh[c_] : 0.f); \
    float* d_ = gi + (size_t)mrow0 * G3 + c_; \
    d_[0]      = acc##nt[0] + bias_; \
    d_[G3]     = acc##nt[1] + bias_; \
    d_[2 * G3] = acc##nt[2] + bias_; \
    d_[3 * G3] = acc##nt[3] + bias_; }
  STF(0) STF(1) STF(2) STF(3)
}

// ---------------------------------------------------------------------------
// Kernel A fallback (round-9 version, proven): gather + cvt inline.
// ---------------------------------------------------------------------------
__global__ __attribute__((amdgpu_flat_work_group_size(512, 512)))
__attribute__((amdgpu_waves_per_eu(2, 2)))
void gi_gemm_kernel(
    const int* __restrict__ questions,
    const int* __restrict__ answers,
    const float* __restrict__ q_emb,
    const float* __restrict__ a_emb,
    const float* __restrict__ w_ih,
    const float* __restrict__ b_ih,
    const float* __restrict__ b_hh,
    float* __restrict__ gi)
{
  const int lane = threadIdx.x & 63;
  const int wv   = threadIdx.x >> 6;
  const int lr   = lane & 15;
  const int kg   = lane >> 4;
  const int wm   = wv & 3;
  const int wn   = wv >> 2;

  const int m  = blockIdx.x * 64 + wm * 16 + lr;
  const int nb = blockIdx.y * 128 + wn * 64;

  int q = questions[m]; q = q < 0 ? 0 : q;
  int a = answers[m];   a = a < 0 ? 0 : a;
  const float* qrow = q_emb + (size_t)q * EDIM + 8 * kg;
  const float* arow = a_emb + (size_t)a * EDIM + 8 * kg;
  const float* wrow = w_ih + (size_t)(nb + lr) * EDIM + 8 * kg;

  f4_t zero4 = {0.f, 0.f, 0.f, 0.f};
  f4_t acc0 = zero4, acc1 = zero4, acc2 = zero4, acc3 = zero4;

#pragma unroll
  for (int i = 0; i < 8; ++i) {
    f4_t q0 = *(const f4_t*)(qrow + 32 * i);
    f4_t q1 = *(const f4_t*)(qrow + 32 * i + 4);
    f4_t a0 = *(const f4_t*)(arow + 32 * i);
    f4_t a1 = *(const f4_t*)(arow + 32 * i + 4);
    f16x8_t af;
    af[0] = (_Float16)(q0[0] + a0[0]); af[1] = (_Float16)(q0[1] + a0[1]);
    af[2] = (_Float16)(q0[2] + a0[2]); af[3] = (_Float16)(q0[3] + a0[3]);
    af[4] = (_Float16)(q1[0] + a1[0]); af[5] = (_Float16)(q1[1] + a1[1]);
    af[6] = (_Float16)(q1[2] + a1[2]); af[7] = (_Float16)(q1[3] + a1[3]);
#define BT(nt) { \
    f4_t b0 = *(const f4_t*)(wrow + (nt) * 16 * EDIM + 32 * i); \
    f4_t b1 = *(const f4_t*)(wrow + (nt) * 16 * EDIM + 32 * i + 4); \
    f16x8_t bf; \
    bf[0] = (_Float16)b0[0]; bf[1] = (_Float16)b0[1]; \
    bf[2] = (_Float16)b0[2]; bf[3] = (_Float16)b0[3]; \
    bf[4] = (_Float16)b1[0]; bf[5] = (_Float16)b1[1]; \
    bf[6] = (_Float16)b1[2]; bf[7] = (_Float16)b1[3]; \
    acc##nt = __builtin_amdgcn_mfma_f32_16x16x32_f16(af, bf, acc##nt, 0, 0, 0); }
    BT(0) BT(1) BT(2) BT(3)
  }

  const int mrow0 = blockIdx.x * 64 + wm * 16 + kg * 4;
#define ST(nt) { \
    const int c_ = nb + (nt) * 16 + lr; \
    const float bias_ = b_ih[c_] + (c_ < 2 * HDIM ? b_hh[c_] : 0.f); \
    float* d_ = gi + (size_t)mrow0 * G3 + c_; \
    d_[0]      = acc##nt[0] + bias_; \
    d_[G3]     = acc##nt[1] + bias_; \
    d_[2 * G3] = acc##nt[2] + bias_; \
    d_[3 * G3] = acc##nt[3] + bias_; }
  ST(0) ST(1) ST(2) ST(3)
}

// ---------------------------------------------------------------------------
// Kernel B: GRU scan, 64 blocks x 512 thr, ONE barrier per step.
// Round-14: VALU diet.
//  (1) W_z in LDS as FP16 u4 rows zF[16][512] (128 KB; occupancy already
//      1 block/CU so free). Removes 64 v_perm unpacks/thread/step; z dot2s
//      consume the ring value directly. 2-deep ring, reload (k+2)&15,
//      phase-stable (16 % 2 == 0).
//  (2) incremental prefetch/out pointers (pfA/pfB/outp += stride) instead of
//      per-step 64-bit recompute from t.
// r perms (64/step) must stay: r fp16 would need 64 VGPRs we don't have.
// ---------------------------------------------------------------------------
__global__ __attribute__((amdgpu_flat_work_group_size(512, 512)))
__attribute__((amdgpu_waves_per_eu(2, 2)))
void gru_scan_kernel(
    const int* __restrict__ questions,
    const float* __restrict__ w_hh,    // [768][256]
    const float* __restrict__ b_hh,    // [768]
    const float* __restrict__ pred_w,  // [Q+1][256]
    const float* __restrict__ pred_b,  // [Q+1]
    const float* __restrict__ gi,      // [B*T][768] (b_ih + b_hh_{r,z} folded)
    float* __restrict__ out)           // [B][199]
{
  const int b    = blockIdx.x;
  const int tid  = threadIdx.x;
  const int lane = tid & 63;
  const int wave = tid >> 6;
  const int g    = tid >> 1;   // hidden unit 0..255
  const int sub  = tid & 1;    // column half

  __shared__ __align__(16) u4_t zF[16][512];        // 128 KB: fp16 W_z rows
  __shared__ __align__(16) _Float16 hh[2][HDIM];    // fp16 h double-buffer
  __shared__ __align__(16) float ppbuf[2][HDIM];    // per-unit pred products
  __shared__ float gi_buf[2][G3];
  __shared__ float pw_lds[2][HDIM];
  __shared__ float pb2[2];                          // pred_b, per parity

  // ---- W_n -> 16 named u4 fp16 (64 VGPRs) ----
  const float* wn_p = w_hh + (size_t)(2 * HDIM + g) * HDIM + 128 * sub;
#define WLOAD(name, p_, r_) u4_t name; { \
    f4_t f0_ = *(const f4_t*)((p_) + 8 * (r_)); \
    f4_t f1_ = *(const f4_t*)((p_) + 8 * (r_) + 4); \
    name[0] = pk(f0_[0], f0_[1]); name[1] = pk(f0_[2], f0_[3]); \
    name[2] = pk(f1_[0], f1_[1]); name[3] = pk(f1_[2], f1_[3]); }
  WLOAD(WN0,wn_p,0)  WLOAD(WN1,wn_p,1)  WLOAD(WN2,wn_p,2)  WLOAD(WN3,wn_p,3)
  WLOAD(WN4,wn_p,4)  WLOAD(WN5,wn_p,5)  WLOAD(WN6,wn_p,6)  WLOAD(WN7,wn_p,7)
  WLOAD(WN8,wn_p,8)  WLOAD(WN9,wn_p,9)  WLOAD(WN10,wn_p,10) WLOAD(WN11,wn_p,11)
  WLOAD(WN12,wn_p,12) WLOAD(WN13,wn_p,13) WLOAD(WN14,wn_p,14) WLOAD(WN15,wn_p,15)

  // ---- W_r -> 16 named u2 e5m2 (32 VGPRs) ----
  const float* wr_p = w_hh + (size_t)g * HDIM + 128 * sub;
#define RLOAD(name, r_) u2_t name; { \
    name[0] = pk_e5m2x4(wr_p + 8 * (r_)); \
    name[1] = pk_e5m2x4(wr_p + 8 * (r_) + 4); }
  RLOAD(RU0,0)  RLOAD(RU1,1)  RLOAD(RU2,2)  RLOAD(RU3,3)
  RLOAD(RU4,4)  RLOAD(RU5,5)  RLOAD(RU6,6)  RLOAD(RU7,7)
  RLOAD(RU8,8)  RLOAD(RU9,9)  RLOAD(RU10,10) RLOAD(RU11,11)
  RLOAD(RU12,12) RLOAD(RU13,13) RLOAD(RU14,14) RLOAD(RU15,15)

  // ---- W_z -> LDS fp16, u4 per chunk (8 cols) ----
  {
    const float* wz_p = w_hh + (size_t)(HDIM + g) * HDIM + 128 * sub;
    for (int k = 0; k < 16; ++k) {
      u4_t v;
      v[0] = pk(wz_p[8*k+0], wz_p[8*k+1]);
      v[1] = pk(wz_p[8*k+2], wz_p[8*k+3]);
      v[2] = pk(wz_p[8*k+4], wz_p[8*k+5]);
      v[3] = pk(wz_p[8*k+6], wz_p[8*k+7]);
      zF[k][tid] = v;
    }
  }

  const float bhn = b_hh[2 * HDIM + g];
  float h_prev = 0.f;

  if (tid < 32) { u4_t z_ = {0u,0u,0u,0u}; *(u4_t*)((char*)&hh[0][0] + tid * 16) = z_; }

  const int*   q_b  = questions + b * T_SEQ;
  const float* gi_b = gi + (size_t)b * T_SEQ * G3;

  // prologue: stage gi[0], pw[0]
  if (wave < 6) {
    gload_lds4(gi_b + (2*wave)   * 64 + lane, &gi_buf[0][(2*wave)   * 64]);
    gload_lds4(gi_b + (2*wave+1) * 64 + lane, &gi_buf[0][(2*wave+1) * 64]);
  }
  if (wave == 6) {
    int q0 = q_b[0]; if (q0 < 0) q0 = 0;
    const float* pr = pred_w + (size_t)q0 * HDIM;
#pragma unroll
    for (int kk = 0; kk < 4; ++kk) gload_lds4(pr + 64*kk + lane, &pw_lds[0][64*kk]);
  }
  __syncthreads();

  // incremental prefetch pointers (start at row t=1)
  const float* pfA = gi_b + G3 + (2*wave)   * 64 + lane;
  const float* pfB = gi_b + G3 + (2*wave+1) * 64 + lane;
  float* outp = out + b * TOUT;

  // 2-deep zF ring: stable phase across steps (16 % 2 == 0)
  u4_t zA = zF[0][tid], zB = zF[1][tid];
  u4_t hvA, hvB;

#define CHUNK(k_, HC_, HN_, ZS_) { \
    if ((k_) < 15) hv##HN_ = *(const u4_t*)(hcur + 16 * ((k_) + 1)); \
    u4_t zc_ = z##ZS_; \
    z##ZS_ = zF[((k_) + 2) & 15][tid]; \
    sn = dot2acc(WN##k_[0], hv##HC_[0], sn); sn = dot2acc(WN##k_[1], hv##HC_[1], sn); \
    sn = dot2acc(WN##k_[2], hv##HC_[2], sn); sn = dot2acc(WN##k_[3], hv##HC_[3], sn); \
    sr = dot2acc(up_lo(RU##k_[0]), hv##HC_[0], sr); \
    sr = dot2acc(up_hi(RU##k_[0]), hv##HC_[1], sr); \
    sr = dot2acc(up_lo(RU##k_[1]), hv##HC_[2], sr); \
    sr = dot2acc(up_hi(RU##k_[1]), hv##HC_[3], sr); \
    sz = dot2acc(zc_[0], hv##HC_[0], sz); \
    sz = dot2acc(zc_[1], hv##HC_[1], sz); \
    sz = dot2acc(zc_[2], hv##HC_[2], sz); \
    sz = dot2acc(zc_[3], hv##HC_[3], sz); }

  for (int t = 0; t < TOUT; ++t) {
    const int cur = t & 1, nxt = cur ^ 1;

    // issue chunk-0 h read + gate/pred inputs FIRST
    const char* hcur = (const char*)&hh[cur][0] + 256 * sub;
    hvA = *(const u4_t*)(hcur);
    float gir = gi_buf[cur][g];
    float giz = gi_buf[cur][HDIM + g];
    float gin = gi_buf[cur][2 * HDIM + g];
    float pwv = pw_lds[cur][g];

    // prefetch step t+1 inputs (async, drains at this step's barrier)
    if (wave < 6) {
      gload_lds4(pfA, &gi_buf[nxt][(2*wave)   * 64]);
      gload_lds4(pfB, &gi_buf[nxt][(2*wave+1) * 64]);
      pfA += G3; pfB += G3;
    }
    if (wave == 6) {
      int qn = q_b[t+1]; if (qn < 0) qn = 0;
      const float* pr = pred_w + (size_t)qn * HDIM;
      gload_lds4(pr + lane,       &pw_lds[nxt][0]);
      gload_lds4(pr + 64 + lane,  &pw_lds[nxt][64]);
      gload_lds4(pr + 128 + lane, &pw_lds[nxt][128]);
      gload_lds4(pr + 192 + lane, &pw_lds[nxt][192]);
    }
    float pbv = 0.f;
    if (tid == 8) { int qt = q_b[t]; if (qt < 0) qt = 0; pbv = pred_b[qt]; }

    // software-pipelined matvec: hh 2-deep, zF 2-deep ring, no z perms
    float sr = 0.f, sz = 0.f, sn = 0.f;
    CHUNK(0,A,B,A)  CHUNK(1,B,A,B)  CHUNK(2,A,B,A)  CHUNK(3,B,A,B)
    CHUNK(4,A,B,A)  CHUNK(5,B,A,B)  CHUNK(6,A,B,A)  CHUNK(7,B,A,B)
    CHUNK(8,A,B,A)  CHUNK(9,B,A,B)  CHUNK(10,A,B,A) CHUNK(11,B,A,B)
    CHUNK(12,A,B,A) CHUNK(13,B,A,B) CHUNK(14,A,B,A) CHUNK(15,B,A,B)
    sr += __shfl_xor(sr, 1); sz += __shfl_xor(sz, 1); sn += __shfl_xor(sn, 1);

    // finisher for step t-1 (ppbuf published by last barrier), wave 0 only
    if (t > 0 && tid < 64) {
      f4_t pv = *(const f4_t*)&ppbuf[nxt][lane << 2];
      float v = (pv[0] + pv[1]) + (pv[2] + pv[3]);
      v += __shfl_xor(v, 1);  v += __shfl_xor(v, 2);
      v += __shfl_xor(v, 4);  v += __shfl_xor(v, 8);
      v += __shfl_xor(v, 16); v += __shfl_xor(v, 32);
      if (tid == 0)
        outp[t - 1] = __fdividef(1.f, 1.f + __expf(-(v + pb2[nxt])));
    }

    // gates (both lanes of the pair compute redundantly)
    float r_ = __fdividef(1.f, 1.f + __expf(-(gir + sr)));
    float z_ = __fdividef(1.f, 1.f + __expf(-(giz + sz)));
    float e2 = __expf(2.f * (gin + r_ * (sn + bhn)));
    float n_ = 1.f - __fdividef(2.f, e2 + 1.f);
    h_prev = (1.f - z_) * n_ + z_ * h_prev;

    if (sub == 0) {
      hh[nxt][g] = (_Float16)h_prev;
      ppbuf[cur][g] = h_prev * pwv;     // pred product; reduced next step
    }
    if (tid == 8) pb2[cur] = pbv;

    __syncthreads();   // the ONLY barrier: publishes hh[nxt], ppbuf, prefetches
  }

  // epilogue: finish step 198 (parity 0)
  if (tid < 64) {
    f4_t pv = *(const f4_t*)&ppbuf[0][lane << 2];
    float v = (pv[0] + pv[1]) + (pv[2] + pv[3]);
    v += __shfl_xor(v, 1);  v += __shfl_xor(v, 2);
    v += __shfl_xor(v, 4);  v += __shfl_xor(v, 8);
    v += __shfl_xor(v, 16); v += __shfl_xor(v, 32);
    if (tid == 0)
      out[b * TOUT + 198] = __fdividef(1.f, 1.f + __expf(-(v + pb2[0])));
  }
}

// ---------------------------------------------------------------------------
extern "C" void kernel_launch(void* const* d_in, const int* in_sizes, int n_in,
                              void* d_out, int out_size, void* d_ws, size_t ws_size,
                              hipStream_t stream) {
  const int*   questions = (const int*)d_in[1];
  const int*   answers   = (const int*)d_in[2];
  const float* q_emb     = (const float*)d_in[3];
  const float* a_emb     = (const float*)d_in[4];
  const float* w_ih      = (const float*)d_in[5];
  const float* w_hh      = (const float*)d_in[6];
  const float* b_ih      = (const float*)d_in[7];
  const float* b_hh      = (const float*)d_in[8];
  const float* pred_w    = (const float*)d_in[9];
  const float* pred_b    = (const float*)d_in[10];
  float* out = (float*)d_out;

  const size_t gi_bytes = (size_t)64 * T_SEQ * G3 * 4;     // 39.3 MB
  const size_t xh_bytes = (size_t)64 * T_SEQ * EDIM * 2;   // 6.55 MB
  const size_t wh_bytes = (size_t)G3 * EDIM * 2;           // 0.39 MB
  float* gi = (float*)d_ws;

  if (ws_size >= gi_bytes + xh_bytes + wh_bytes) {
    _Float16* xh    = (_Float16*)((char*)d_ws + gi_bytes);
    _Float16* wih_h = (_Float16*)((char*)d_ws + gi_bytes + xh_bytes);
    xbuild_kernel<<<100, 256, 0, stream>>>(questions, answers, q_emb, a_emb,
                                           w_ih, xh, wih_h);
    gi_gemm_fast_kernel<<<dim3(200, 6), 512, 0, stream>>>(xh, wih_h, b_ih, b_hh, gi);
  } else {
    gi_gemm_kernel<<<dim3(200, 6), 512, 0, stream>>>(
        questions, answers, q_emb, a_emb, w_ih, b_ih, b_hh, gi);
  }

  gru_scan_kernel<<<64, 512, 0, stream>>>(
      questions, w_hh, b_hh, pred_w, pred_b, gi, out);
}

// Round 15
// 380.016 us; speedup vs baseline: 2.0742x; 1.0356x over previous
//
#include <hip/hip_runtime.h>
#include <hip/hip_bf16.h>

#define T_SEQ 200
#define HDIM  256
#define EDIM  256
#define G3    768   // 3*H
#define TOUT  199   // T-1

typedef _Float16 h2_t __attribute__((ext_vector_type(2)));
typedef _Float16 f16x8_t __attribute__((ext_vector_type(8)));
typedef unsigned int u4_t __attribute__((ext_vector_type(4)));
typedef unsigned int u2_t __attribute__((ext_vector_type(2)));
typedef float f4_t __attribute__((ext_vector_type(4)));

static __device__ __forceinline__ float dot2acc(unsigned int w, unsigned int h, float c) {
  return __builtin_amdgcn_fdot2(__builtin_bit_cast(h2_t, w),
                                __builtin_bit_cast(h2_t, h), c, false);
}

static __device__ __forceinline__ unsigned int pk(float x, float y) {
  h2_t p; p[0] = (_Float16)x; p[1] = (_Float16)y;
  return __builtin_bit_cast(unsigned int, p);
}

// 4 floats -> 4 e5m2 bytes (top byte of f16, round-half-up; weights <=0.0625
// so no overflow). Numerics validated rounds 9-14.
static __device__ __forceinline__ unsigned int pk_e5m2x4(const float* p) {
  unsigned int r = 0;
#pragma unroll
  for (int j = 0; j < 4; ++j) {
    unsigned short b = __builtin_bit_cast(unsigned short, (_Float16)p[j]);
    r |= ((unsigned int)((unsigned short)(b + 0x80) >> 8)) << (8 * j);
  }
  return r;
}

// e5m2 bytes {b0,b1} of u -> h2 {b0<<8, b1<<8}: single v_perm_b32
static __device__ __forceinline__ unsigned int up_lo(unsigned int u) {
  return __builtin_amdgcn_perm(0u, u, 0x010C000Cu);
}
static __device__ __forceinline__ unsigned int up_hi(unsigned int u) {
  return __builtin_amdgcn_perm(0u, u, 0x030C020Cu);
}

// async global->LDS, 4 bytes per lane; LDS base is wave-uniform (HW adds lane*4)
static __device__ __forceinline__ void gload_lds4(const void* g, void* l) {
  __builtin_amdgcn_global_load_lds(
      (const __attribute__((address_space(1))) void*)g,
      (__attribute__((address_space(3))) void*)l, 4, 0, 0);
}

// ---------------------------------------------------------------------------
// xbuild (+wcvt fused): xh[m][e] = (f16)(q_emb[q[m]][e] + a_emb[a[m]][e]);
// blocks 0..95 also convert w_ih -> fp16. 400 blocks x 32 rows (r14: 100x128
// serial-depth was the chain bottleneck).
// ---------------------------------------------------------------------------
__global__ __attribute__((amdgpu_flat_work_group_size(256, 256)))
void xbuild_kernel(const int* __restrict__ questions,
                   const int* __restrict__ answers,
                   const float* __restrict__ q_emb,
                   const float* __restrict__ a_emb,
                   const float* __restrict__ w_ih,
                   _Float16* __restrict__ xh,
                   _Float16* __restrict__ wih_h)
{
  const int tid = threadIdx.x;
  {
    int wi = (blockIdx.x * 256 + tid) * 8;
    if (wi < G3 * EDIM) {
      f4_t a = *(const f4_t*)(w_ih + wi);
      f4_t b = *(const f4_t*)(w_ih + wi + 4);
      f16x8_t o;
      o[0]=(_Float16)a[0]; o[1]=(_Float16)a[1]; o[2]=(_Float16)a[2]; o[3]=(_Float16)a[3];
      o[4]=(_Float16)b[0]; o[5]=(_Float16)b[1]; o[6]=(_Float16)b[2]; o[7]=(_Float16)b[3];
      *(f16x8_t*)(wih_h + wi) = o;
    }
  }
  const int m0 = blockIdx.x * 32;
  for (int i = 0; i < 32; ++i) {
    int m = m0 + i;
    int q = questions[m]; q = q < 0 ? 0 : q;
    int a = answers[m];   a = a < 0 ? 0 : a;
    xh[(size_t)m * EDIM + tid] =
        (_Float16)(q_emb[(size_t)q * EDIM + tid] + a_emb[(size_t)a * EDIM + tid]);
  }
}

// ---------------------------------------------------------------------------
// Kernel A fast (MFMA f16): gi_h = (f16)(xh @ wih_h^T + bias).
// Fragment pattern proven rounds 9-14. f16 store halves write traffic.
// ---------------------------------------------------------------------------
__global__ __attribute__((amdgpu_flat_work_group_size(512, 512)))
void gi_gemm_fast_kernel(const _Float16* __restrict__ xh,
                         const _Float16* __restrict__ wih_h,
                         const float* __restrict__ b_ih,
                         const float* __restrict__ b_hh,
                         _Float16* __restrict__ gi_h)
{
  const int lane = threadIdx.x & 63;
  const int wv   = threadIdx.x >> 6;
  const int lr   = lane & 15;
  const int kg   = lane >> 4;
  const int wm   = wv & 3;
  const int wn   = wv >> 2;

  const int m  = blockIdx.x * 64 + wm * 16 + lr;
  const int nb = blockIdx.y * 128 + wn * 64;

  const _Float16* arow = xh + (size_t)m * EDIM + 8 * kg;
  const _Float16* wrow = wih_h + (size_t)(nb + lr) * EDIM + 8 * kg;

  f4_t zero4 = {0.f, 0.f, 0.f, 0.f};
  f4_t acc0 = zero4, acc1 = zero4, acc2 = zero4, acc3 = zero4;

#pragma unroll
  for (int i = 0; i < 8; ++i) {
    f16x8_t af = *(const f16x8_t*)(arow + 32 * i);
#define BTF(nt) { \
    f16x8_t bf = *(const f16x8_t*)(wrow + (size_t)(nt) * 16 * EDIM + 32 * i); \
    acc##nt = __builtin_amdgcn_mfma_f32_16x16x32_f16(af, bf, acc##nt, 0, 0, 0); }
    BTF(0) BTF(1) BTF(2) BTF(3)
  }

  const int mrow0 = blockIdx.x * 64 + wm * 16 + kg * 4;
#define STF(nt) { \
    const int c_ = nb + (nt) * 16 + lr; \
    const float bias_ = b_ih[c_] + (c_ < 2 * HDIM ? b_hh[c_] : 0.f); \
    _Float16* d_ = gi_h + (size_t)mrow0 * G3 + c_; \
    d_[0]      = (_Float16)(acc##nt[0] + bias_); \
    d_[G3]     = (_Float16)(acc##nt[1] + bias_); \
    d_[2 * G3] = (_Float16)(acc##nt[2] + bias_); \
    d_[3 * G3] = (_Float16)(acc##nt[3] + bias_); }
  STF(0) STF(1) STF(2) STF(3)
}

// ---------------------------------------------------------------------------
// Kernel A fallback (inline gather+cvt, proven r9): writes f16 gi.
// ---------------------------------------------------------------------------
__global__ __attribute__((amdgpu_flat_work_group_size(512, 512)))
__attribute__((amdgpu_waves_per_eu(2, 2)))
void gi_gemm_kernel(
    const int* __restrict__ questions,
    const int* __restrict__ answers,
    const float* __restrict__ q_emb,
    const float* __restrict__ a_emb,
    const float* __restrict__ w_ih,
    const float* __restrict__ b_ih,
    const float* __restrict__ b_hh,
    _Float16* __restrict__ gi_h)
{
  const int lane = threadIdx.x & 63;
  const int wv   = threadIdx.x >> 6;
  const int lr   = lane & 15;
  const int kg   = lane >> 4;
  const int wm   = wv & 3;
  const int wn   = wv >> 2;

  const int m  = blockIdx.x * 64 + wm * 16 + lr;
  const int nb = blockIdx.y * 128 + wn * 64;

  int q = questions[m]; q = q < 0 ? 0 : q;
  int a = answers[m];   a = a < 0 ? 0 : a;
  const float* qrow = q_emb + (size_t)q * EDIM + 8 * kg;
  const float* arow = a_emb + (size_t)a * EDIM + 8 * kg;
  const float* wrow = w_ih + (size_t)(nb + lr) * EDIM + 8 * kg;

  f4_t zero4 = {0.f, 0.f, 0.f, 0.f};
  f4_t acc0 = zero4, acc1 = zero4, acc2 = zero4, acc3 = zero4;

#pragma unroll
  for (int i = 0; i < 8; ++i) {
    f4_t q0 = *(const f4_t*)(qrow + 32 * i);
    f4_t q1 = *(const f4_t*)(qrow + 32 * i + 4);
    f4_t a0 = *(const f4_t*)(arow + 32 * i);
    f4_t a1 = *(const f4_t*)(arow + 32 * i + 4);
    f16x8_t af;
    af[0] = (_Float16)(q0[0] + a0[0]); af[1] = (_Float16)(q0[1] + a0[1]);
    af[2] = (_Float16)(q0[2] + a0[2]); af[3] = (_Float16)(q0[3] + a0[3]);
    af[4] = (_Float16)(q1[0] + a1[0]); af[5] = (_Float16)(q1[1] + a1[1]);
    af[6] = (_Float16)(q1[2] + a1[2]); af[7] = (_Float16)(q1[3] + a1[3]);
#define BT(nt) { \
    f4_t b0 = *(const f4_t*)(wrow + (nt) * 16 * EDIM + 32 * i); \
    f4_t b1 = *(const f4_t*)(wrow + (nt) * 16 * EDIM + 32 * i + 4); \
    f16x8_t bf; \
    bf[0] = (_Float16)b0[0]; bf[1] = (_Float16)b0[1]; \
    bf[2] = (_Float16)b0[2]; bf[3] = (_Float16)b0[3]; \
    bf[4] = (_Float16)b1[0]; bf[5] = (_Float16)b1[1]; \
    bf[6] = (_Float16)b1[2]; bf[7] = (_Float16)b1[3]; \
    acc##nt = __builtin_amdgcn_mfma_f32_16x16x32_f16(af, bf, acc##nt, 0, 0, 0); }
    BT(0) BT(1) BT(2) BT(3)
  }

  const int mrow0 = blockIdx.x * 64 + wm * 16 + kg * 4;
#define ST(nt) { \
    const int c_ = nb + (nt) * 16 + lr; \
    const float bias_ = b_ih[c_] + (c_ < 2 * HDIM ? b_hh[c_] : 0.f); \
    _Float16* d_ = gi_h + (size_t)mrow0 * G3 + c_; \
    d_[0]      = (_Float16)(acc##nt[0] + bias_); \
    d_[G3]     = (_Float16)(acc##nt[1] + bias_); \
    d_[2 * G3] = (_Float16)(acc##nt[2] + bias_); \
    d_[3 * G3] = (_Float16)(acc##nt[3] + bias_); }
  ST(0) ST(1) ST(2) ST(3)
}

// ---------------------------------------------------------------------------
// Kernel B: GRU scan, 64 blocks x 512 thr, ONE barrier per step (r14 base).
// Round-15: gi in FP16 — per-step prefetch 12 -> 6 gload_lds4, HBM gi stream
// 39 -> 19.6 MB; gate inputs via ds_read_u16 + cvt (+3 VALU, -6 mem instrs).
// ---------------------------------------------------------------------------
__global__ __attribute__((amdgpu_flat_work_group_size(512, 512)))
__attribute__((amdgpu_waves_per_eu(2, 2)))
void gru_scan_kernel(
    const int* __restrict__ questions,
    const float* __restrict__ w_hh,    // [768][256]
    const float* __restrict__ b_hh,    // [768]
    const float* __restrict__ pred_w,  // [Q+1][256]
    const float* __restrict__ pred_b,  // [Q+1]
    const _Float16* __restrict__ gi,   // [B*T][768] f16 (b_ih + b_hh_{r,z} folded)
    float* __restrict__ out)           // [B][199]
{
  const int b    = blockIdx.x;
  const int tid  = threadIdx.x;
  const int lane = tid & 63;
  const int wave = tid >> 6;
  const int g    = tid >> 1;   // hidden unit 0..255
  const int sub  = tid & 1;    // column half

  __shared__ __align__(16) u4_t zF[16][512];        // 128 KB: fp16 W_z rows
  __shared__ __align__(16) _Float16 hh[2][HDIM];    // fp16 h double-buffer
  __shared__ __align__(16) float ppbuf[2][HDIM];    // per-unit pred products
  __shared__ __align__(16) _Float16 gi_buf[2][G3];  // f16 gi rows (3 KB)
  __shared__ float pw_lds[2][HDIM];
  __shared__ float pb2[2];                          // pred_b, per parity

  // ---- W_n -> 16 named u4 fp16 (64 VGPRs) ----
  const float* wn_p = w_hh + (size_t)(2 * HDIM + g) * HDIM + 128 * sub;
#define WLOAD(name, p_, r_) u4_t name; { \
    f4_t f0_ = *(const f4_t*)((p_) + 8 * (r_)); \
    f4_t f1_ = *(const f4_t*)((p_) + 8 * (r_) + 4); \
    name[0] = pk(f0_[0], f0_[1]); name[1] = pk(f0_[2], f0_[3]); \
    name[2] = pk(f1_[0], f1_[1]); name[3] = pk(f1_[2], f1_[3]); }
  WLOAD(WN0,wn_p,0)  WLOAD(WN1,wn_p,1)  WLOAD(WN2,wn_p,2)  WLOAD(WN3,wn_p,3)
  WLOAD(WN4,wn_p,4)  WLOAD(WN5,wn_p,5)  WLOAD(WN6,wn_p,6)  WLOAD(WN7,wn_p,7)
  WLOAD(WN8,wn_p,8)  WLOAD(WN9,wn_p,9)  WLOAD(WN10,wn_p,10) WLOAD(WN11,wn_p,11)
  WLOAD(WN12,wn_p,12) WLOAD(WN13,wn_p,13) WLOAD(WN14,wn_p,14) WLOAD(WN15,wn_p,15)

  // ---- W_r -> 16 named u2 e5m2 (32 VGPRs) ----
  const float* wr_p = w_hh + (size_t)g * HDIM + 128 * sub;
#define RLOAD(name, r_) u2_t name; { \
    name[0] = pk_e5m2x4(wr_p + 8 * (r_)); \
    name[1] = pk_e5m2x4(wr_p + 8 * (r_) + 4); }
  RLOAD(RU0,0)  RLOAD(RU1,1)  RLOAD(RU2,2)  RLOAD(RU3,3)
  RLOAD(RU4,4)  RLOAD(RU5,5)  RLOAD(RU6,6)  RLOAD(RU7,7)
  RLOAD(RU8,8)  RLOAD(RU9,9)  RLOAD(RU10,10) RLOAD(RU11,11)
  RLOAD(RU12,12) RLOAD(RU13,13) RLOAD(RU14,14) RLOAD(RU15,15)

  // ---- W_z -> LDS fp16, u4 per chunk (8 cols) ----
  {
    const float* wz_p = w_hh + (size_t)(HDIM + g) * HDIM + 128 * sub;
    for (int k = 0; k < 16; ++k) {
      u4_t v;
      v[0] = pk(wz_p[8*k+0], wz_p[8*k+1]);
      v[1] = pk(wz_p[8*k+2], wz_p[8*k+3]);
      v[2] = pk(wz_p[8*k+4], wz_p[8*k+5]);
      v[3] = pk(wz_p[8*k+6], wz_p[8*k+7]);
      zF[k][tid] = v;
    }
  }

  const float bhn = b_hh[2 * HDIM + g];
  float h_prev = 0.f;

  if (tid < 32) { u4_t z_ = {0u,0u,0u,0u}; *(u4_t*)((char*)&hh[0][0] + tid * 16) = z_; }

  const int*  q_b  = questions + b * T_SEQ;
  const char* gi_b = (const char*)(gi + (size_t)b * T_SEQ * G3);  // 1536 B/row

  // prologue: stage gi[0] (6 x 256B), pw[0]
  if (wave < 6) {
    gload_lds4(gi_b + wave * 256 + lane * 4,
               (char*)&gi_buf[0][0] + wave * 256);
  }
  if (wave == 6) {
    int q0 = q_b[0]; if (q0 < 0) q0 = 0;
    const float* pr = pred_w + (size_t)q0 * HDIM;
#pragma unroll
    for (int kk = 0; kk < 4; ++kk)
      gload_lds4(pr + 64*kk + lane, &pw_lds[0][64*kk]);
  }
  __syncthreads();

  // incremental prefetch pointer (starts at row t=1)
  const char* pf = gi_b + 1536 + wave * 256 + lane * 4;
  float* outp = out + b * TOUT;

  // 2-deep zF ring: stable phase across steps (16 % 2 == 0)
  u4_t zA = zF[0][tid], zB = zF[1][tid];
  u4_t hvA, hvB;

#define CHUNK(k_, HC_, HN_, ZS_) { \
    if ((k_) < 15) hv##HN_ = *(const u4_t*)(hcur + 16 * ((k_) + 1)); \
    u4_t zc_ = z##ZS_; \
    z##ZS_ = zF[((k_) + 2) & 15][tid]; \
    sn = dot2acc(WN##k_[0], hv##HC_[0], sn); sn = dot2acc(WN##k_[1], hv##HC_[1], sn); \
    sn = dot2acc(WN##k_[2], hv##HC_[2], sn); sn = dot2acc(WN##k_[3], hv##HC_[3], sn); \
    sr = dot2acc(up_lo(RU##k_[0]), hv##HC_[0], sr); \
    sr = dot2acc(up_hi(RU##k_[0]), hv##HC_[1], sr); \
    sr = dot2acc(up_lo(RU##k_[1]), hv##HC_[2], sr); \
    sr = dot2acc(up_hi(RU##k_[1]), hv##HC_[3], sr); \
    sz = dot2acc(zc_[0], hv##HC_[0], sz); \
    sz = dot2acc(zc_[1], hv##HC_[1], sz); \
    sz = dot2acc(zc_[2], hv##HC_[2], sz); \
    sz = dot2acc(zc_[3], hv##HC_[3], sz); }

  for (int t = 0; t < TOUT; ++t) {
    const int cur = t & 1, nxt = cur ^ 1;

    // issue chunk-0 h read + gate/pred inputs FIRST
    const char* hcur = (const char*)&hh[cur][0] + 256 * sub;
    hvA = *(const u4_t*)(hcur);
    float gir = (float)gi_buf[cur][g];
    float giz = (float)gi_buf[cur][HDIM + g];
    float gin = (float)gi_buf[cur][2 * HDIM + g];
    float pwv = pw_lds[cur][g];

    // prefetch step t+1 inputs (async, drains at this step's barrier)
    if (wave < 6) {
      gload_lds4(pf, (char*)&gi_buf[nxt][0] + wave * 256);
      pf += 1536;
    }
    if (wave == 6) {
      int qn = q_b[t+1]; if (qn < 0) qn = 0;
      const float* pr = pred_w + (size_t)qn * HDIM;
      gload_lds4(pr + lane,       &pw_lds[nxt][0]);
      gload_lds4(pr + 64 + lane,  &pw_lds[nxt][64]);
      gload_lds4(pr + 128 + lane, &pw_lds[nxt][128]);
      gload_lds4(pr + 192 + lane, &pw_lds[nxt][192]);
    }
    float pbv = 0.f;
    if (tid == 8) { int qt = q_b[t]; if (qt < 0) qt = 0; pbv = pred_b[qt]; }

    // software-pipelined matvec: hh 2-deep, zF 2-deep ring, no z perms
    float sr = 0.f, sz = 0.f, sn = 0.f;
    CHUNK(0,A,B,A)  CHUNK(1,B,A,B)  CHUNK(2,A,B,A)  CHUNK(3,B,A,B)
    CHUNK(4,A,B,A)  CHUNK(5,B,A,B)  CHUNK(6,A,B,A)  CHUNK(7,B,A,B)
    CHUNK(8,A,B,A)  CHUNK(9,B,A,B)  CHUNK(10,A,B,A) CHUNK(11,B,A,B)
    CHUNK(12,A,B,A) CHUNK(13,B,A,B) CHUNK(14,A,B,A) CHUNK(15,B,A,B)
    sr += __shfl_xor(sr, 1); sz += __shfl_xor(sz, 1); sn += __shfl_xor(sn, 1);

    // finisher for step t-1 (ppbuf published by last barrier), wave 0 only
    if (t > 0 && tid < 64) {
      f4_t pv = *(const f4_t*)&ppbuf[nxt][lane << 2];
      float v = (pv[0] + pv[1]) + (pv[2] + pv[3]);
      v += __shfl_xor(v, 1);  v += __shfl_xor(v, 2);
      v += __shfl_xor(v, 4);  v += __shfl_xor(v, 8);
      v += __shfl_xor(v, 16); v += __shfl_xor(v, 32);
      if (tid == 0)
        outp[t - 1] = __fdividef(1.f, 1.f + __expf(-(v + pb2[nxt])));
    }

    // gates (both lanes of the pair compute redundantly)
    float r_ = __fdividef(1.f, 1.f + __expf(-(gir + sr)));
    float z_ = __fdividef(1.f, 1.f + __expf(-(giz + sz)));
    float e2 = __expf(2.f * (gin + r_ * (sn + bhn)));
    float n_ = 1.f - __fdividef(2.f, e2 + 1.f);
    h_prev = (1.f - z_) * n_ + z_ * h_prev;

    if (sub == 0) {
      hh[nxt][g] = (_Float16)h_prev;
      ppbuf[cur][g] = h_prev * pwv;     // pred product; reduced next step
    }
    if (tid == 8) pb2[cur] = pbv;

    __syncthreads();   // the ONLY barrier: publishes hh[nxt], ppbuf, prefetches
  }

  // epilogue: finish step 198 (parity 0)
  if (tid < 64) {
    f4_t pv = *(const f4_t*)&ppbuf[0][lane << 2];
    float v = (pv[0] + pv[1]) + (pv[2] + pv[3]);
    v += __shfl_xor(v, 1);  v += __shfl_xor(v, 2);
    v += __shfl_xor(v, 4);  v += __shfl_xor(v, 8);
    v += __shfl_xor(v, 16); v += __shfl_xor(v, 32);
    if (tid == 0)
      out[b * TOUT + 198] = __fdividef(1.f, 1.f + __expf(-(v + pb2[0])));
  }
}

// ---------------------------------------------------------------------------
extern "C" void kernel_launch(void* const* d_in, const int* in_sizes, int n_in,
                              void* d_out, int out_size, void* d_ws, size_t ws_size,
                              hipStream_t stream) {
  const int*   questions = (const int*)d_in[1];
  const int*   answers   = (const int*)d_in[2];
  const float* q_emb     = (const float*)d_in[3];
  const float* a_emb     = (const float*)d_in[4];
  const float* w_ih      = (const float*)d_in[5];
  const float* w_hh      = (const float*)d_in[6];
  const float* b_ih      = (const float*)d_in[7];
  const float* b_hh      = (const float*)d_in[8];
  const float* pred_w    = (const float*)d_in[9];
  const float* pred_b    = (const float*)d_in[10];
  float* out = (float*)d_out;

  const size_t gih_bytes = (size_t)64 * T_SEQ * G3 * 2;    // 19.66 MB
  const size_t xh_bytes  = (size_t)64 * T_SEQ * EDIM * 2;  // 6.55 MB
  const size_t wh_bytes  = (size_t)G3 * EDIM * 2;          // 0.39 MB
  _Float16* gi_h = (_Float16*)d_ws;

  if (ws_size >= gih_bytes + xh_bytes + wh_bytes) {
    _Float16* xh    = (_Float16*)((char*)d_ws + gih_bytes);
    _Float16* wih_h = (_Float16*)((char*)d_ws + gih_bytes + xh_bytes);
    xbuild_kernel<<<400, 256, 0, stream>>>(questions, answers, q_emb, a_emb,
                                           w_ih, xh, wih_h);
    gi_gemm_fast_kernel<<<dim3(200, 6), 512, 0, stream>>>(xh, wih_h, b_ih, b_hh, gi_h);
  } else {
    gi_gemm_kernel<<<dim3(200, 6), 512, 0, stream>>>(
        questions, answers, q_emb, a_emb, w_ih, b_ih, b_hh, gi_h);
  }

  gru_scan_kernel<<<64, 512, 0, stream>>>(
      questions, w_hh, b_hh, pred_w, pred_b, gi_h, out);
}

// Round 16
// 376.800 us; speedup vs baseline: 2.0919x; 1.0085x over previous
//
#include <hip/hip_runtime.h>
#include <hip/hip_bf16.h>

#define T_SEQ 200
#define HDIM  256
#define EDIM  256
#define G3    768   // 3*H
#define TOUT  199   // T-1

typedef _Float16 h2_t __attribute__((ext_vector_type(2)));
typedef _Float16 f16x8_t __attribute__((ext_vector_type(8)));
typedef unsigned int u4_t __attribute__((ext_vector_type(4)));
typedef unsigned int u2_t __attribute__((ext_vector_type(2)));
typedef float f4_t __attribute__((ext_vector_type(4)));

static __device__ __forceinline__ float dot2acc(unsigned int w, unsigned int h, float c) {
  return __builtin_amdgcn_fdot2(__builtin_bit_cast(h2_t, w),
                                __builtin_bit_cast(h2_t, h), c, false);
}

static __device__ __forceinline__ unsigned int pk(float x, float y) {
  h2_t p; p[0] = (_Float16)x; p[1] = (_Float16)y;
  return __builtin_bit_cast(unsigned int, p);
}

// 4 floats -> 4 e5m2 bytes (top byte of f16, round-half-up; weights <=0.0625
// so no overflow). Numerics validated rounds 9-15.
static __device__ __forceinline__ unsigned int pk_e5m2x4(const float* p) {
  unsigned int r = 0;
#pragma unroll
  for (int j = 0; j < 4; ++j) {
    unsigned short b = __builtin_bit_cast(unsigned short, (_Float16)p[j]);
    r |= ((unsigned int)((unsigned short)(b + 0x80) >> 8)) << (8 * j);
  }
  return r;
}

// e5m2 bytes {b0,b1} of u -> h2 {b0<<8, b1<<8}: single v_perm_b32
static __device__ __forceinline__ unsigned int up_lo(unsigned int u) {
  return __builtin_amdgcn_perm(0u, u, 0x010C000Cu);
}
static __device__ __forceinline__ unsigned int up_hi(unsigned int u) {
  return __builtin_amdgcn_perm(0u, u, 0x030C020Cu);
}

// async global->LDS; size literal 4 or 16 B/lane; LDS base wave-uniform
static __device__ __forceinline__ void gload_lds4(const void* g, void* l) {
  __builtin_amdgcn_global_load_lds(
      (const __attribute__((address_space(1))) void*)g,
      (__attribute__((address_space(3))) void*)l, 4, 0, 0);
}
static __device__ __forceinline__ void gload_lds16(const void* g, void* l) {
  __builtin_amdgcn_global_load_lds(
      (const __attribute__((address_space(1))) void*)g,
      (__attribute__((address_space(3))) void*)l, 16, 0, 0);
}

// ---------------------------------------------------------------------------
// xbuild (+wcvt fused): xh[m][e] = (f16)(q_emb[q[m]][e] + a_emb[a[m]][e]);
// blocks 0..95 also convert w_ih -> fp16. 400 blocks x 32 rows.
// ---------------------------------------------------------------------------
__global__ __attribute__((amdgpu_flat_work_group_size(256, 256)))
void xbuild_kernel(const int* __restrict__ questions,
                   const int* __restrict__ answers,
                   const float* __restrict__ q_emb,
                   const float* __restrict__ a_emb,
                   const float* __restrict__ w_ih,
                   _Float16* __restrict__ xh,
                   _Float16* __restrict__ wih_h)
{
  const int tid = threadIdx.x;
  {
    int wi = (blockIdx.x * 256 + tid) * 8;
    if (wi < G3 * EDIM) {
      f4_t a = *(const f4_t*)(w_ih + wi);
      f4_t b = *(const f4_t*)(w_ih + wi + 4);
      f16x8_t o;
      o[0]=(_Float16)a[0]; o[1]=(_Float16)a[1]; o[2]=(_Float16)a[2]; o[3]=(_Float16)a[3];
      o[4]=(_Float16)b[0]; o[5]=(_Float16)b[1]; o[6]=(_Float16)b[2]; o[7]=(_Float16)b[3];
      *(f16x8_t*)(wih_h + wi) = o;
    }
  }
  const int m0 = blockIdx.x * 32;
  for (int i = 0; i < 32; ++i) {
    int m = m0 + i;
    int q = questions[m]; q = q < 0 ? 0 : q;
    int a = answers[m];   a = a < 0 ? 0 : a;
    xh[(size_t)m * EDIM + tid] =
        (_Float16)(q_emb[(size_t)q * EDIM + tid] + a_emb[(size_t)a * EDIM + tid]);
  }
}

// ---------------------------------------------------------------------------
// Kernel A fast (MFMA f16): gi_h = (f16)(xh @ wih_h^T + bias).
// Fragment pattern proven rounds 9-15.
// ---------------------------------------------------------------------------
__global__ __attribute__((amdgpu_flat_work_group_size(512, 512)))
void gi_gemm_fast_kernel(const _Float16* __restrict__ xh,
                         const _Float16* __restrict__ wih_h,
                         const float* __restrict__ b_ih,
                         const float* __restrict__ b_hh,
                         _Float16* __restrict__ gi_h)
{
  const int lane = threadIdx.x & 63;
  const int wv   = threadIdx.x >> 6;
  const int lr   = lane & 15;
  const int kg   = lane >> 4;
  const int wm   = wv & 3;
  const int wn   = wv >> 2;

  const int m  = blockIdx.x * 64 + wm * 16 + lr;
  const int nb = blockIdx.y * 128 + wn * 64;

  const _Float16* arow = xh + (size_t)m * EDIM + 8 * kg;
  const _Float16* wrow = wih_h + (size_t)(nb + lr) * EDIM + 8 * kg;

  f4_t zero4 = {0.f, 0.f, 0.f, 0.f};
  f4_t acc0 = zero4, acc1 = zero4, acc2 = zero4, acc3 = zero4;

#pragma unroll
  for (int i = 0; i < 8; ++i) {
    f16x8_t af = *(const f16x8_t*)(arow + 32 * i);
#define BTF(nt) { \
    f16x8_t bf = *(const f16x8_t*)(wrow + (size_t)(nt) * 16 * EDIM + 32 * i); \
    acc##nt = __builtin_amdgcn_mfma_f32_16x16x32_f16(af, bf, acc##nt, 0, 0, 0); }
    BTF(0) BTF(1) BTF(2) BTF(3)
  }

  const int mrow0 = blockIdx.x * 64 + wm * 16 + kg * 4;
#define STF(nt) { \
    const int c_ = nb + (nt) * 16 + lr; \
    const float bias_ = b_ih[c_] + (c_ < 2 * HDIM ? b_hh[c_] : 0.f); \
    _Float16* d_ = gi_h + (size_t)mrow0 * G3 + c_; \
    d_[0]      = (_Float16)(acc##nt[0] + bias_); \
    d_[G3]     = (_Float16)(acc##nt[1] + bias_); \
    d_[2 * G3] = (_Float16)(acc##nt[2] + bias_); \
    d_[3 * G3] = (_Float16)(acc##nt[3] + bias_); }
  STF(0) STF(1) STF(2) STF(3)
}

// ---------------------------------------------------------------------------
// Kernel A fallback (inline gather+cvt, proven r9): writes f16 gi.
// ---------------------------------------------------------------------------
__global__ __attribute__((amdgpu_flat_work_group_size(512, 512)))
__attribute__((amdgpu_waves_per_eu(2, 2)))
void gi_gemm_kernel(
    const int* __restrict__ questions,
    const int* __restrict__ answers,
    const float* __restrict__ q_emb,
    const float* __restrict__ a_emb,
    const float* __restrict__ w_ih,
    const float* __restrict__ b_ih,
    const float* __restrict__ b_hh,
    _Float16* __restrict__ gi_h)
{
  const int lane = threadIdx.x & 63;
  const int wv   = threadIdx.x >> 6;
  const int lr   = lane & 15;
  const int kg   = lane >> 4;
  const int wm   = wv & 3;
  const int wn   = wv >> 2;

  const int m  = blockIdx.x * 64 + wm * 16 + lr;
  const int nb = blockIdx.y * 128 + wn * 64;

  int q = questions[m]; q = q < 0 ? 0 : q;
  int a = answers[m];   a = a < 0 ? 0 : a;
  const float* qrow = q_emb + (size_t)q * EDIM + 8 * kg;
  const float* arow = a_emb + (size_t)a * EDIM + 8 * kg;
  const float* wrow = w_ih + (size_t)(nb + lr) * EDIM + 8 * kg;

  f4_t zero4 = {0.f, 0.f, 0.f, 0.f};
  f4_t acc0 = zero4, acc1 = zero4, acc2 = zero4, acc3 = zero4;

#pragma unroll
  for (int i = 0; i < 8; ++i) {
    f4_t q0 = *(const f4_t*)(qrow + 32 * i);
    f4_t q1 = *(const f4_t*)(qrow + 32 * i + 4);
    f4_t a0 = *(const f4_t*)(arow + 32 * i);
    f4_t a1 = *(const f4_t*)(arow + 32 * i + 4);
    f16x8_t af;
    af[0] = (_Float16)(q0[0] + a0[0]); af[1] = (_Float16)(q0[1] + a0[1]);
    af[2] = (_Float16)(q0[2] + a0[2]); af[3] = (_Float16)(q0[3] + a0[3]);
    af[4] = (_Float16)(q1[0] + a1[0]); af[5] = (_Float16)(q1[1] + a1[1]);
    af[6] = (_Float16)(q1[2] + a1[2]); af[7] = (_Float16)(q1[3] + a1[3]);
#define BT(nt) { \
    f4_t b0 = *(const f4_t*)(wrow + (nt) * 16 * EDIM + 32 * i); \
    f4_t b1 = *(const f4_t*)(wrow + (nt) * 16 * EDIM + 32 * i + 4); \
    f16x8_t bf; \
    bf[0] = (_Float16)b0[0]; bf[1] = (_Float16)b0[1]; \
    bf[2] = (_Float16)b0[2]; bf[3] = (_Float16)b0[3]; \
    bf[4] = (_Float16)b1[0]; bf[5] = (_Float16)b1[1]; \
    bf[6] = (_Float16)b1[2]; bf[7] = (_Float16)b1[3]; \
    acc##nt = __builtin_amdgcn_mfma_f32_16x16x32_f16(af, bf, acc##nt, 0, 0, 0); }
    BT(0) BT(1) BT(2) BT(3)
  }

  const int mrow0 = blockIdx.x * 64 + wm * 16 + kg * 4;
#define ST(nt) { \
    const int c_ = nb + (nt) * 16 + lr; \
    const float bias_ = b_ih[c_] + (c_ < 2 * HDIM ? b_hh[c_] : 0.f); \
    _Float16* d_ = gi_h + (size_t)mrow0 * G3 + c_; \
    d_[0]      = (_Float16)(acc##nt[0] + bias_); \
    d_[G3]     = (_Float16)(acc##nt[1] + bias_); \
    d_[2 * G3] = (_Float16)(acc##nt[2] + bias_); \
    d_[3 * G3] = (_Float16)(acc##nt[3] + bias_); }
  ST(0) ST(1) ST(2) ST(3)
}

// ---------------------------------------------------------------------------
// Kernel B: GRU scan, 64 blocks x 512 thr, ONE barrier per step (r15 base).
// Round-16: VMEM-issue diet + wave role split.
//  (1) gi prefetch: two width-16 global_load_lds (waves 0-1, 1024B each)
//      instead of six 4B issues on waves 0-5. gi_buf rows padded to 2048B
//      (wave 1 covers bytes 1024..2047; 1536..2047 is pad / next-row spill,
//      harmless: source stays inside d_ws).
//  (2) pw prefetch: ONE width-16 issue (wave 6) covers the whole 1024B row.
//  (3) s_setprio(1) around the dot2 block — waves now role-diverse
//      (only waves 0,1,6 issue VMEM), the regime where setprio pays.
// ---------------------------------------------------------------------------
__global__ __attribute__((amdgpu_flat_work_group_size(512, 512)))
__attribute__((amdgpu_waves_per_eu(2, 2)))
void gru_scan_kernel(
    const int* __restrict__ questions,
    const float* __restrict__ w_hh,    // [768][256]
    const float* __restrict__ b_hh,    // [768]
    const float* __restrict__ pred_w,  // [Q+1][256]
    const float* __restrict__ pred_b,  // [Q+1]
    const _Float16* __restrict__ gi,   // [B*T][768] f16 (b_ih + b_hh_{r,z} folded)
    float* __restrict__ out)           // [B][199]
{
  const int b    = blockIdx.x;
  const int tid  = threadIdx.x;
  const int lane = tid & 63;
  const int wave = tid >> 6;
  const int g    = tid >> 1;   // hidden unit 0..255
  const int sub  = tid & 1;    // column half

  __shared__ __align__(16) u4_t zF[16][512];          // 128 KB: fp16 W_z rows
  __shared__ __align__(16) _Float16 hh[2][HDIM];      // fp16 h double-buffer
  __shared__ __align__(16) float ppbuf[2][HDIM];      // per-unit pred products
  __shared__ __align__(16) _Float16 gi_buf[2][1024];  // f16 gi rows (2KB padded)
  __shared__ __align__(16) float pw_lds[2][HDIM];
  __shared__ float pb2[2];                            // pred_b, per parity

  // ---- W_n -> 16 named u4 fp16 (64 VGPRs) ----
  const float* wn_p = w_hh + (size_t)(2 * HDIM + g) * HDIM + 128 * sub;
#define WLOAD(name, p_, r_) u4_t name; { \
    f4_t f0_ = *(const f4_t*)((p_) + 8 * (r_)); \
    f4_t f1_ = *(const f4_t*)((p_) + 8 * (r_) + 4); \
    name[0] = pk(f0_[0], f0_[1]); name[1] = pk(f0_[2], f0_[3]); \
    name[2] = pk(f1_[0], f1_[1]); name[3] = pk(f1_[2], f1_[3]); }
  WLOAD(WN0,wn_p,0)  WLOAD(WN1,wn_p,1)  WLOAD(WN2,wn_p,2)  WLOAD(WN3,wn_p,3)
  WLOAD(WN4,wn_p,4)  WLOAD(WN5,wn_p,5)  WLOAD(WN6,wn_p,6)  WLOAD(WN7,wn_p,7)
  WLOAD(WN8,wn_p,8)  WLOAD(WN9,wn_p,9)  WLOAD(WN10,wn_p,10) WLOAD(WN11,wn_p,11)
  WLOAD(WN12,wn_p,12) WLOAD(WN13,wn_p,13) WLOAD(WN14,wn_p,14) WLOAD(WN15,wn_p,15)

  // ---- W_r -> 16 named u2 e5m2 (32 VGPRs) ----
  const float* wr_p = w_hh + (size_t)g * HDIM + 128 * sub;
#define RLOAD(name, r_) u2_t name; { \
    name[0] = pk_e5m2x4(wr_p + 8 * (r_)); \
    name[1] = pk_e5m2x4(wr_p + 8 * (r_) + 4); }
  RLOAD(RU0,0)  RLOAD(RU1,1)  RLOAD(RU2,2)  RLOAD(RU3,3)
  RLOAD(RU4,4)  RLOAD(RU5,5)  RLOAD(RU6,6)  RLOAD(RU7,7)
  RLOAD(RU8,8)  RLOAD(RU9,9)  RLOAD(RU10,10) RLOAD(RU11,11)
  RLOAD(RU12,12) RLOAD(RU13,13) RLOAD(RU14,14) RLOAD(RU15,15)

  // ---- W_z -> LDS fp16, u4 per chunk (8 cols) ----
  {
    const float* wz_p = w_hh + (size_t)(HDIM + g) * HDIM + 128 * sub;
    for (int k = 0; k < 16; ++k) {
      u4_t v;
      v[0] = pk(wz_p[8*k+0], wz_p[8*k+1]);
      v[1] = pk(wz_p[8*k+2], wz_p[8*k+3]);
      v[2] = pk(wz_p[8*k+4], wz_p[8*k+5]);
      v[3] = pk(wz_p[8*k+6], wz_p[8*k+7]);
      zF[k][tid] = v;
    }
  }

  const float bhn = b_hh[2 * HDIM + g];
  float h_prev = 0.f;

  if (tid < 32) { u4_t z_ = {0u,0u,0u,0u}; *(u4_t*)((char*)&hh[0][0] + tid * 16) = z_; }

  const int*  q_b  = questions + b * T_SEQ;
  const char* gi_b = (const char*)(gi + (size_t)b * T_SEQ * G3);  // 1536 B/row

  // prologue: stage gi[0] (2 x 1024B wide loads), pw[0] (1 wide load)
  if (wave < 2) {
    gload_lds16(gi_b + wave * 1024 + lane * 16,
                (char*)&gi_buf[0][0] + wave * 1024);
  }
  if (wave == 6) {
    int q0 = q_b[0]; if (q0 < 0) q0 = 0;
    const float* pr = pred_w + (size_t)q0 * HDIM;
    gload_lds16((const char*)pr + lane * 16, &pw_lds[0][0]);
  }
  __syncthreads();

  // incremental prefetch pointer (starts at row t=1)
  const char* pf = gi_b + 1536 + wave * 1024 + lane * 16;
  float* outp = out + b * TOUT;

  // 2-deep zF ring: stable phase across steps (16 % 2 == 0)
  u4_t zA = zF[0][tid], zB = zF[1][tid];
  u4_t hvA, hvB;

#define CHUNK(k_, HC_, HN_, ZS_) { \
    if ((k_) < 15) hv##HN_ = *(const u4_t*)(hcur + 16 * ((k_) + 1)); \
    u4_t zc_ = z##ZS_; \
    z##ZS_ = zF[((k_) + 2) & 15][tid]; \
    sn = dot2acc(WN##k_[0], hv##HC_[0], sn); sn = dot2acc(WN##k_[1], hv##HC_[1], sn); \
    sn = dot2acc(WN##k_[2], hv##HC_[2], sn); sn = dot2acc(WN##k_[3], hv##HC_[3], sn); \
    sr = dot2acc(up_lo(RU##k_[0]), hv##HC_[0], sr); \
    sr = dot2acc(up_hi(RU##k_[0]), hv##HC_[1], sr); \
    sr = dot2acc(up_lo(RU##k_[1]), hv##HC_[2], sr); \
    sr = dot2acc(up_hi(RU##k_[1]), hv##HC_[3], sr); \
    sz = dot2acc(zc_[0], hv##HC_[0], sz); \
    sz = dot2acc(zc_[1], hv##HC_[1], sz); \
    sz = dot2acc(zc_[2], hv##HC_[2], sz); \
    sz = dot2acc(zc_[3], hv##HC_[3], sz); }

  for (int t = 0; t < TOUT; ++t) {
    const int cur = t & 1, nxt = cur ^ 1;

    // issue chunk-0 h read + gate/pred inputs FIRST
    const char* hcur = (const char*)&hh[cur][0] + 256 * sub;
    hvA = *(const u4_t*)(hcur);
    float gir = (float)gi_buf[cur][g];
    float giz = (float)gi_buf[cur][HDIM + g];
    float gin = (float)gi_buf[cur][2 * HDIM + g];
    float pwv = pw_lds[cur][g];

    // prefetch step t+1 inputs (async, drains at this step's barrier)
    if (wave < 2) {
      gload_lds16(pf, (char*)&gi_buf[nxt][0] + wave * 1024);
      pf += 1536;
    }
    if (wave == 6) {
      int qn = q_b[t+1]; if (qn < 0) qn = 0;
      const float* pr = pred_w + (size_t)qn * HDIM;
      gload_lds16((const char*)pr + lane * 16, &pw_lds[nxt][0]);
    }
    float pbv = 0.f;
    if (tid == 8) { int qt = q_b[t]; if (qt < 0) qt = 0; pbv = pred_b[qt]; }

    // software-pipelined matvec: hh 2-deep, zF 2-deep ring
    __builtin_amdgcn_s_setprio(1);
    float sr = 0.f, sz = 0.f, sn = 0.f;
    CHUNK(0,A,B,A)  CHUNK(1,B,A,B)  CHUNK(2,A,B,A)  CHUNK(3,B,A,B)
    CHUNK(4,A,B,A)  CHUNK(5,B,A,B)  CHUNK(6,A,B,A)  CHUNK(7,B,A,B)
    CHUNK(8,A,B,A)  CHUNK(9,B,A,B)  CHUNK(10,A,B,A) CHUNK(11,B,A,B)
    CHUNK(12,A,B,A) CHUNK(13,B,A,B) CHUNK(14,A,B,A) CHUNK(15,B,A,B)
    __builtin_amdgcn_s_setprio(0);
    sr += __shfl_xor(sr, 1); sz += __shfl_xor(sz, 1); sn += __shfl_xor(sn, 1);

    // finisher for step t-1 (ppbuf published by last barrier), wave 0 only
    if (t > 0 && tid < 64) {
      f4_t pv = *(const f4_t*)&ppbuf[nxt][lane << 2];
      float v = (pv[0] + pv[1]) + (pv[2] + pv[3]);
      v += __shfl_xor(v, 1);  v += __shfl_xor(v, 2);
      v += __shfl_xor(v, 4);  v += __shfl_xor(v, 8);
      v += __shfl_xor(v, 16); v += __shfl_xor(v, 32);
      if (tid == 0)
        outp[t - 1] = __fdividef(1.f, 1.f + __expf(-(v + pb2[nxt])));
    }

    // gates (both lanes of the pair compute redundantly)
    float r_ = __fdividef(1.f, 1.f + __expf(-(gir + sr)));
    float z_ = __fdividef(1.f, 1.f + __expf(-(giz + sz)));
    float e2 = __expf(2.f * (gin + r_ * (sn + bhn)));
    float n_ = 1.f - __fdividef(2.f, e2 + 1.f);
    h_prev = (1.f - z_) * n_ + z_ * h_prev;

    if (sub == 0) {
      hh[nxt][g] = (_Float16)h_prev;
      ppbuf[cur][g] = h_prev * pwv;     // pred product; reduced next step
    }
    if (tid == 8) pb2[cur] = pbv;

    __syncthreads();   // the ONLY barrier: publishes hh[nxt], ppbuf, prefetches
  }

  // epilogue: finish step 198 (parity 0)
  if (tid < 64) {
    f4_t pv = *(const f4_t*)&ppbuf[0][lane << 2];
    float v = (pv[0] + pv[1]) + (pv[2] + pv[3]);
    v += __shfl_xor(v, 1);  v += __shfl_xor(v, 2);
    v += __shfl_xor(v, 4);  v += __shfl_xor(v, 8);
    v += __shfl_xor(v, 16); v += __shfl_xor(v, 32);
    if (tid == 0)
      out[b * TOUT + 198] = __fdividef(1.f, 1.f + __expf(-(v + pb2[0])));
  }
}

// ---------------------------------------------------------------------------
extern "C" void kernel_launch(void* const* d_in, const int* in_sizes, int n_in,
                              void* d_out, int out_size, void* d_ws, size_t ws_size,
                              hipStream_t stream) {
  const int*   questions = (const int*)d_in[1];
  const int*   answers   = (const int*)d_in[2];
  const float* q_emb     = (const float*)d_in[3];
  const float* a_emb     = (const float*)d_in[4];
  const float* w_ih      = (const float*)d_in[5];
  const float* w_hh      = (const float*)d_in[6];
  const float* b_ih      = (const float*)d_in[7];
  const float* b_hh      = (const float*)d_in[8];
  const float* pred_w    = (const float*)d_in[9];
  const float* pred_b    = (const float*)d_in[10];
  float* out = (float*)d_out;

  const size_t gih_bytes = (size_t)64 * T_SEQ * G3 * 2;    // 19.66 MB
  const size_t xh_bytes  = (size_t)64 * T_SEQ * EDIM * 2;  // 6.55 MB
  const size_t wh_bytes  = (size_t)G3 * EDIM * 2;          // 0.39 MB
  _Float16* gi_h = (_Float16*)d_ws;

  if (ws_size >= gih_bytes + xh_bytes + wh_bytes + 2048) {
    _Float16* xh    = (_Float16*)((char*)d_ws + gih_bytes);
    _Float16* wih_h = (_Float16*)((char*)d_ws + gih_bytes + xh_bytes);
    xbuild_kernel<<<400, 256, 0, stream>>>(questions, answers, q_emb, a_emb,
                                           w_ih, xh, wih_h);
    gi_gemm_fast_kernel<<<dim3(200, 6), 512, 0, stream>>>(xh, wih_h, b_ih, b_hh, gi_h);
  } else {
    gi_gemm_kernel<<<dim3(200, 6), 512, 0, stream>>>(
        questions, answers, q_emb, a_emb, w_ih, b_ih, b_hh, gi_h);
  }

  gru_scan_kernel<<<64, 512, 0, stream>>>(
      questions, w_hh, b_hh, pred_w, pred_b, gi_h, out);
}